// Round 1
// 11414.598 us; speedup vs baseline: 1.2769x; 1.2769x over previous
//
#include <hip/hip_runtime.h>
#include <hip/hip_bf16.h>

typedef __hip_bfloat16 bf16;
typedef unsigned short u16;
typedef unsigned int u32;
typedef __attribute__((ext_vector_type(8))) short short8;
typedef __attribute__((ext_vector_type(4))) float f32x4;

#define NPART 30000
#define NEDGE 300000
#define HD 128
#define NLAYER 10
#define NFLOAT_ARRAYS 43
#define NMAT 66

// ---------------- dtype detect ----------------
__device__ __forceinline__ bool detect_bf16(const unsigned short* braw) {
    return braw[1] == 0x3F80u;
}

// ---------------- fp32<->bf16 helpers (RNE) ----------------
__device__ __forceinline__ u16 f2b(float f) {
    u32 u = __float_as_uint(f);
    u += 0x7FFFu + ((u >> 16) & 1u);
    return (u16)(u >> 16);
}
__device__ __forceinline__ float b2f(u16 u) {
    return __uint_as_float(((u32)u) << 16);
}
__device__ __forceinline__ u32 pack2(float a, float b) {
    return (u32)f2b(a) | ((u32)f2b(b) << 16);
}

// ---------------- convert all float arrays to canonical fp32 ----------------
struct ConvArgs {
    const void* src[NFLOAT_ARRAYS];
    int n[NFLOAT_ARRAYS];
    int off[NFLOAT_ARRAYS];
};

__global__ __launch_bounds__(256)
void k_convert(ConvArgs a, float* __restrict__ dst, const unsigned short* __restrict__ braw)
{
    const bool isb = detect_bf16(braw);
    const int aid = blockIdx.y;
    const int n = a.n[aid];
    float* o = dst + a.off[aid];
    const int stride = gridDim.x * 256;
    int i = blockIdx.x * 256 + threadIdx.x;
    if (isb) {
        const unsigned short* s = (const unsigned short*)a.src[aid];
        for (; i < n; i += stride) {
            const unsigned int u = ((unsigned int)s[i]) << 16;
            o[i] = __uint_as_float(u);
        }
    } else {
        const float* s = (const float*)a.src[aid];
        for (; i < n; i += stride) o[i] = s[i];
    }
}

// ---------------- weight pre-pack: f32 [K][128] -> bf16 fragment-linear ----------------
// dst layout: [mtile(8)][ks(K/32)][lane(64)][8 contiguous k] ushorts.
// A-frag for lane l of tile (mt,ks): hid = mt*16+(l&15), k = ks*32+(l>>4)*8 + j.
struct PackArgs {
    int src_off[NMAT];
    int dst_off[NMAT];
    int K[NMAT];
    int nks[NMAT];
};

__global__ __launch_bounds__(256)
void k_pack(const float* __restrict__ cw, u16* __restrict__ wpk, PackArgs pa)
{
    const int mid = blockIdx.y;
    const int nks = pa.nks[mid];
    const int total = nks * 4096;
    const int d = blockIdx.x * 256 + threadIdx.x;
    if (d >= total) return;
    const int j = d & 7, l = (d >> 3) & 63, t = d >> 9;
    const int ks = t % nks, mt = t / nks;
    const int hid = mt * 16 + (l & 15);
    const int k = ks * 32 + (l >> 4) * 8 + j;
    const float v = (k < pa.K[mid]) ? cw[pa.src_off[mid] + k * HD + hid] : 0.0f;
    wpk[pa.dst_off[mid] + d] = f2b(v);
}

// ---------------- MFMA GEMM tile: 64 rows x 128 hid, 4 waves ----------------
// wave (wm,wn): wm in {0,1} = hid half (64), wn in {0,1} = row half (32).
// Each wave: 4 M-tiles x 2 N-tiles of 16x16, K stepped by 32.
template<int NKS, int XROW>
__device__ __forceinline__ void gemm16(const u16* __restrict__ Wp,
                                       const float* __restrict__ Bias,
                                       const u16* __restrict__ x,
                                       f32x4 acc[4][2],
                                       const int wm, const int wn,
                                       const int l15, const int lg, const int lane)
{
#pragma unroll
    for (int mt = 0; mt < 4; mt++) {
        const f32x4 bv = *(const f32x4*)(Bias + wm * 64 + mt * 16 + lg * 4);
        acc[mt][0] = bv;
        acc[mt][1] = bv;
    }
    const u16* xr0 = x + (wn * 32 + l15) * XROW + lg * 8;
    const u16* xr1 = xr0 + 16 * XROW;
    const u16* wp = Wp + (wm * 4 * NKS) * 512 + lane * 8;
#pragma unroll
    for (int ks = 0; ks < NKS; ks++) {
        const short8 b0 = *(const short8*)(xr0 + ks * 32);
        const short8 b1 = *(const short8*)(xr1 + ks * 32);
#pragma unroll
        for (int mt = 0; mt < 4; mt++) {
            const short8 a = *(const short8*)(wp + (mt * NKS + ks) * 512);
            acc[mt][0] = __builtin_amdgcn_mfma_f32_16x16x32_bf16(a, b0, acc[mt][0], 0, 0, 0);
            acc[mt][1] = __builtin_amdgcn_mfma_f32_16x16x32_bf16(a, b1, acc[mt][1], 0, 0, 0);
        }
    }
}

// relu + pack 4 bf16 + 8B LDS store into h[row][136]
__device__ __forceinline__ void store_h(u16* __restrict__ h, const f32x4 acc[4][2],
                                        const int wm, const int wn, const int l15, const int lg)
{
#pragma unroll
    for (int nt = 0; nt < 2; nt++) {
        const int e = wn * 32 + nt * 16 + l15;
#pragma unroll
        for (int mt = 0; mt < 4; mt++) {
            const int hid = wm * 64 + mt * 16 + lg * 4;
            const f32x4 v = acc[mt][nt];
            const u32 lo = pack2(fmaxf(v[0], 0.0f), fmaxf(v[1], 0.0f));
            const u32 hi = pack2(fmaxf(v[2], 0.0f), fmaxf(v[3], 0.0f));
            *(uint2*)(h + e * 136 + hid) = make_uint2(lo, hi);
        }
    }
}

// full Linear-ReLU-Linear-ReLU-Linear-LayerNorm on a 64-row tile.
// xs: LDS [64][XROW] bf16 (K1 cols valid); h1/h2 may overlap xs (sync-separated).
template<int NKS1, int XROW>
__device__ __forceinline__ void mlp_mfma(const u16* __restrict__ xs,
    u16* __restrict__ h1, u16* __restrict__ h2,
    float (*red)[2][2][16][2],
    const u16* __restrict__ W1p, const float* __restrict__ B1,
    const u16* __restrict__ W2p, const float* __restrict__ B2,
    const u16* __restrict__ W3p, const float* __restrict__ B3,
    const float* __restrict__ g, const float* __restrict__ be,
    float outv[4][2][4],
    const int wm, const int wn, const int l15, const int lg, const int lane)
{
    f32x4 acc[4][2];
    gemm16<NKS1, XROW>(W1p, B1, xs, acc, wm, wn, l15, lg, lane);
    __syncthreads();                      // all waves done reading xs
    store_h(h1, acc, wm, wn, l15, lg);    // h1 may overlay xs
    __syncthreads();
    gemm16<4, 136>(W2p, B2, h1, acc, wm, wn, l15, lg, lane);
    store_h(h2, acc, wm, wn, l15, lg);    // h2 disjoint from h1 -> no sync needed before
    __syncthreads();
    gemm16<4, 136>(W3p, B3, h2, acc, wm, wn, l15, lg, lane);
    // ---- layernorm over 128 features per row ----
    float ps[2], pss[2];
#pragma unroll
    for (int nt = 0; nt < 2; nt++) {
        float s = 0.0f, ss = 0.0f;
#pragma unroll
        for (int mt = 0; mt < 4; mt++) {
#pragma unroll
            for (int r = 0; r < 4; r++) {
                const float v = acc[mt][nt][r];
                s += v; ss += v * v;
            }
        }
        s += __shfl_xor(s, 16); ss += __shfl_xor(ss, 16);
        s += __shfl_xor(s, 32); ss += __shfl_xor(ss, 32);
        ps[nt] = s; pss[nt] = ss;
    }
    if (lane < 16) {
#pragma unroll
        for (int nt = 0; nt < 2; nt++) {
            red[wm][wn][nt][l15][0] = ps[nt];
            red[wm][wn][nt][l15][1] = pss[nt];
        }
    }
    __syncthreads();
#pragma unroll
    for (int nt = 0; nt < 2; nt++) {
        const float S  = red[0][wn][nt][l15][0] + red[1][wn][nt][l15][0];
        const float SS = red[0][wn][nt][l15][1] + red[1][wn][nt][l15][1];
        const float mu  = S * (1.0f / 128.0f);
        const float var = SS * (1.0f / 128.0f) - mu * mu;
        const float inv = rsqrtf(var + 1e-5f);
#pragma unroll
        for (int mt = 0; mt < 4; mt++) {
            const int hid = wm * 64 + mt * 16 + lg * 4;
            const f32x4 gv  = *(const f32x4*)(g + hid);
            const f32x4 bev = *(const f32x4*)(be + hid);
#pragma unroll
            for (int r = 0; r < 4; r++)
                outv[mt][nt][r] = (acc[mt][nt][r] - mu) * inv * gv[r] + bev[r];
        }
    }
}

// ---------------- node encoder (K=30 padded to 32) ----------------
__device__ __forceinline__ float nfeat(int i, int k,
    const float* __restrict__ vel, const float* __restrict__ pos,
    const float* __restrict__ bounds, const int* __restrict__ ptype,
    const float* __restrict__ emb)
{
    if (k < 10) return vel[i * 10 + k];
    if (k < 14) {
        const int q = k - 10;
        float sub;
        if (q < 2) sub = pos[i * 2 + q] - bounds[q * 2 + 0];
        else       sub = bounds[(q - 2) * 2 + 1] - pos[i * 2 + (q - 2)];
        const float dv = sub * 20.0f;
        return fminf(fmaxf(dv, -1.0f), 1.0f);
    }
    if (k < 30) return emb[ptype[i] * 16 + (k - 14)];
    return 0.0f;
}

__global__ __launch_bounds__(256)
void k_node_enc_m(const float* __restrict__ vel, const float* __restrict__ pos,
                  const float* __restrict__ bounds, const int* __restrict__ ptype,
                  const float* __restrict__ emb,
                  const u16* __restrict__ W1p, const float* __restrict__ B1,
                  const u16* __restrict__ W2p, const float* __restrict__ B2,
                  const u16* __restrict__ W3p, const float* __restrict__ B3,
                  const float* __restrict__ g, const float* __restrict__ be,
                  float* __restrict__ nodes)
{
    __shared__ __align__(16) u16 lds[17408];   // h1+h2; xs (64*40) overlays front
    __shared__ float red[2][2][2][16][2];
    const int tid = threadIdx.x;
    const int i0 = blockIdx.x * 64;
    for (int idx = tid; idx < 1024; idx += 256) {
        const int m = idx >> 4, kk = idx & 15;
        const int i = i0 + m;
        float f0 = 0.0f, f1 = 0.0f;
        if (i < NPART) {
            f0 = nfeat(i, kk * 2 + 0, vel, pos, bounds, ptype, emb);
            f1 = nfeat(i, kk * 2 + 1, vel, pos, bounds, ptype, emb);
        }
        *(u32*)(lds + m * 40 + kk * 2) = pack2(f0, f1);
    }
    __syncthreads();
    const int lane = tid & 63, wv = tid >> 6;
    const int wm = wv >> 1, wn = wv & 1, l15 = lane & 15, lg = lane >> 4;
    float outv[4][2][4];
    mlp_mfma<1, 40>(lds, lds, lds + 8704, red, W1p, B1, W2p, B2, W3p, B3, g, be,
                    outv, wm, wn, l15, lg, lane);
#pragma unroll
    for (int nt = 0; nt < 2; nt++) {
        const int i = i0 + wn * 32 + nt * 16 + l15;
        if (i < NPART) {
#pragma unroll
            for (int mt = 0; mt < 4; mt++) {
                const int hid = wm * 64 + mt * 16 + lg * 4;
                *(float4*)(nodes + (size_t)i * HD + hid) =
                    make_float4(outv[mt][nt][0], outv[mt][nt][1], outv[mt][nt][2], outv[mt][nt][3]);
            }
        }
    }
}

// ---------------- edge encoder (K=3 padded to 32) ----------------
__global__ __launch_bounds__(256)
void k_edge_enc_m(const float* __restrict__ pos, const int* __restrict__ snd,
                  const int* __restrict__ rcv,
                  const u16* __restrict__ W1p, const float* __restrict__ B1,
                  const u16* __restrict__ W2p, const float* __restrict__ B2,
                  const u16* __restrict__ W3p, const float* __restrict__ B3,
                  const float* __restrict__ g, const float* __restrict__ be,
                  float* __restrict__ edges)
{
    __shared__ __align__(16) u16 lds[17408];
    __shared__ float red[2][2][2][16][2];
    const int tid = threadIdx.x;
    const int e0 = blockIdx.x * 64;
    for (int idx = tid; idx < 1024; idx += 256) {
        const int m = idx >> 4, kk = idx & 15;
        const int e = min(e0 + m, NEDGE - 1);
        u32 w = 0;
        if (kk < 2) {
            const int s = snd[e], r = rcv[e];
            const float dx = (pos[s * 2 + 0] - pos[r * 2 + 0]) * 20.0f;
            const float dy = (pos[s * 2 + 1] - pos[r * 2 + 1]) * 20.0f;
            if (kk == 0) w = pack2(dx, dy);
            else         w = pack2(sqrtf(dx * dx + dy * dy), 0.0f);
        }
        *(u32*)(lds + m * 40 + kk * 2) = w;
    }
    __syncthreads();
    const int lane = tid & 63, wv = tid >> 6;
    const int wm = wv >> 1, wn = wv & 1, l15 = lane & 15, lg = lane >> 4;
    float outv[4][2][4];
    mlp_mfma<1, 40>(lds, lds, lds + 8704, red, W1p, B1, W2p, B2, W3p, B3, g, be,
                    outv, wm, wn, l15, lg, lane);
#pragma unroll
    for (int nt = 0; nt < 2; nt++) {
        const int e = e0 + wn * 32 + nt * 16 + l15;
        if (e < NEDGE) {
#pragma unroll
            for (int mt = 0; mt < 4; mt++) {
                const int hid = wm * 64 + mt * 16 + lg * 4;
                *(float4*)(edges + (size_t)e * HD + hid) =
                    make_float4(outv[mt][nt][0], outv[mt][nt][1], outv[mt][nt][2], outv[mt][nt][3]);
            }
        }
    }
}

// ---------------- per-layer edge update (K=384) + scatter into agg ----------------
__global__ __launch_bounds__(256)
void k_edge_layer_m(const float* __restrict__ nodes, float* __restrict__ edges,
                    float* __restrict__ agg,
                    const int* __restrict__ snd, const int* __restrict__ rcv,
                    const u16* __restrict__ W1p, const float* __restrict__ B1,
                    const u16* __restrict__ W2p, const float* __restrict__ B2,
                    const u16* __restrict__ W3p, const float* __restrict__ B3,
                    const float* __restrict__ g, const float* __restrict__ be)
{
    __shared__ __align__(16) u16 lds[25088];   // xs 64x392 = 50176B; h1/h2 overlay
    __shared__ float red[2][2][2][16][2];
    const int tid = threadIdx.x;
    const int e0 = blockIdx.x * 64;
    // gather [edge | node_snd | node_rcv] -> bf16 X
    for (int idx = tid; idx < 3072; idx += 256) {
        const int m = idx / 48;
        const int r2 = idx - m * 48;
        const int s = r2 >> 4, q = r2 & 15;
        const int e = min(e0 + m, NEDGE - 1);
        const float* src;
        if (s == 0)      src = edges + (size_t)e * HD;
        else if (s == 1) src = nodes + (size_t)snd[e] * HD;
        else             src = nodes + (size_t)rcv[e] * HD;
        const float4 a = *(const float4*)(src + q * 8);
        const float4 b = *(const float4*)(src + q * 8 + 4);
        *(uint4*)(lds + m * 392 + s * 128 + q * 8) =
            make_uint4(pack2(a.x, a.y), pack2(a.z, a.w), pack2(b.x, b.y), pack2(b.z, b.w));
    }
    __syncthreads();
    const int lane = tid & 63, wv = tid >> 6;
    const int wm = wv >> 1, wn = wv & 1, l15 = lane & 15, lg = lane >> 4;
    float outv[4][2][4];
    mlp_mfma<12, 392>(lds, lds, lds + 8704, red, W1p, B1, W2p, B2, W3p, B3, g, be,
                      outv, wm, wn, l15, lg, lane);
    // residual + store + scatter-add (f32 states, 4 contiguous hids per lane)
#pragma unroll
    for (int nt = 0; nt < 2; nt++) {
        const int e = e0 + wn * 32 + nt * 16 + l15;
        if (e < NEDGE) {
            const int rr = rcv[e];
            float* ag = agg + (size_t)rr * HD;
            float* ep = edges + (size_t)e * HD;
#pragma unroll
            for (int mt = 0; mt < 4; mt++) {
                const int hid = wm * 64 + mt * 16 + lg * 4;
                const float4 old = *(const float4*)(ep + hid);
                float4 nv;
                nv.x = old.x + outv[mt][nt][0];
                nv.y = old.y + outv[mt][nt][1];
                nv.z = old.z + outv[mt][nt][2];
                nv.w = old.w + outv[mt][nt][3];
                *(float4*)(ep + hid) = nv;
                atomicAdd(ag + hid + 0, nv.x);
                atomicAdd(ag + hid + 1, nv.y);
                atomicAdd(ag + hid + 2, nv.z);
                atomicAdd(ag + hid + 3, nv.w);
            }
        }
    }
}

// ---------------- per-layer node update (K=256) ----------------
__global__ __launch_bounds__(256)
void k_node_layer_m(float* __restrict__ nodes, const float* __restrict__ agg,
                    const u16* __restrict__ W1p, const float* __restrict__ B1,
                    const u16* __restrict__ W2p, const float* __restrict__ B2,
                    const u16* __restrict__ W3p, const float* __restrict__ B3,
                    const float* __restrict__ g, const float* __restrict__ be)
{
    __shared__ __align__(16) u16 lds[17408];   // xs 64x264 = 33792B <= 34816B (h1+h2)
    __shared__ float red[2][2][2][16][2];
    const int tid = threadIdx.x;
    const int i0 = blockIdx.x * 64;
    for (int idx = tid; idx < 2048; idx += 256) {
        const int m = idx >> 5, r2 = idx & 31;
        const int s = r2 >> 4, q = r2 & 15;
        const int i = min(i0 + m, NPART - 1);
        const float* src = (s == 0) ? (nodes + (size_t)i * HD) : (agg + (size_t)i * HD);
        const float4 a = *(const float4*)(src + q * 8);
        const float4 b = *(const float4*)(src + q * 8 + 4);
        *(uint4*)(lds + m * 264 + s * 128 + q * 8) =
            make_uint4(pack2(a.x, a.y), pack2(a.z, a.w), pack2(b.x, b.y), pack2(b.z, b.w));
    }
    __syncthreads();
    const int lane = tid & 63, wv = tid >> 6;
    const int wm = wv >> 1, wn = wv & 1, l15 = lane & 15, lg = lane >> 4;
    float outv[4][2][4];
    mlp_mfma<8, 264>(lds, lds, lds + 8704, red, W1p, B1, W2p, B2, W3p, B3, g, be,
                     outv, wm, wn, l15, lg, lane);
#pragma unroll
    for (int nt = 0; nt < 2; nt++) {
        const int i = i0 + wn * 32 + nt * 16 + l15;
        if (i < NPART) {
            float* np = nodes + (size_t)i * HD;
#pragma unroll
            for (int mt = 0; mt < 4; mt++) {
                const int hid = wm * 64 + mt * 16 + lg * 4;
                const float4 old = *(const float4*)(np + hid);
                *(float4*)(np + hid) = make_float4(old.x + outv[mt][nt][0],
                                                   old.y + outv[mt][nt][1],
                                                   old.z + outv[mt][nt][2],
                                                   old.w + outv[mt][nt][3]);
            }
        }
    }
}

// ---------------- fp32 gemv for decoder (unchanged path) ----------------
template<int K, int S>
__device__ __forceinline__ void gemv(const float* __restrict__ in,
                                     const float* __restrict__ W,
                                     const float* __restrict__ B,
                                     float acc[8])
{
    const int j = threadIdx.x;
    const float bb = B[j];
#pragma unroll
    for (int m = 0; m < 8; m++) acc[m] = bb;
    constexpr int K4 = (K / 4) * 4;
    for (int k = 0; k < K4; k += 4) {
        const float w0 = W[(k + 0) * HD + j];
        const float w1 = W[(k + 1) * HD + j];
        const float w2 = W[(k + 2) * HD + j];
        const float w3 = W[(k + 3) * HD + j];
#pragma unroll
        for (int m = 0; m < 8; m++) {
            const float4 x = *(const float4*)(in + m * S + k);
            float a = acc[m];
            a = fmaf(x.x, w0, a);
            a = fmaf(x.y, w1, a);
            a = fmaf(x.z, w2, a);
            a = fmaf(x.w, w3, a);
            acc[m] = a;
        }
    }
#pragma unroll
    for (int k = K4; k < K; k++) {
        const float w = W[k * HD + j];
#pragma unroll
        for (int m = 0; m < 8; m++) acc[m] = fmaf(in[m * S + k], w, acc[m]);
    }
}

// ---------------- decoder + Euler integration (dual output dtype) ----------------
__global__ __launch_bounds__(128)
void k_decoder(const float* __restrict__ nodes,
               const float* W1, const float* B1, const float* W2, const float* B2,
               const float* W3, const float* B3,
               const float* __restrict__ vel, const float* __restrict__ pos,
               const float* __restrict__ tgt, const int* __restrict__ nonk,
               const unsigned short* __restrict__ braw, void* __restrict__ d_out)
{
    __shared__ __align__(16) float xs[8 * HD];
    __shared__ __align__(16) float h1[8 * HD];
    __shared__ __align__(16) float h2[8 * HD];
    const int j = threadIdx.x;
    const int i0 = blockIdx.x * 8;
    float acc[8];
#pragma unroll
    for (int m = 0; m < 8; m++) xs[m * HD + j] = nodes[(i0 + m) * HD + j];
    __syncthreads();
    gemv<HD, HD>(xs, W1, B1, acc);
#pragma unroll
    for (int m = 0; m < 8; m++) h1[m * HD + j] = fmaxf(acc[m], 0.0f);
    __syncthreads();
    gemv<HD, HD>(h1, W2, B2, acc);
#pragma unroll
    for (int m = 0; m < 8; m++) h2[m * HD + j] = fmaxf(acc[m], 0.0f);
    __syncthreads();
    if (j < 16) {
        const int m = j >> 1, d = j & 1, i = i0 + m;
        float a = B3[d];
        for (int k = 0; k < HD; k++) a = fmaf(h2[m * HD + k], W3[k * 2 + d], a);
        float pp = pos[i * 2 + d] + vel[i * 10 + 8 + d] + a;
        if (nonk[i] == 0) pp = tgt[i * 2 + d];
        if (detect_bf16(braw)) {
            bf16* o = (bf16*)d_out;
            o[i * 2 + d] = __float2bfloat16(a);
            o[2 * NPART + i * 2 + d] = __float2bfloat16(pp);
        } else {
            float* o = (float*)d_out;
            o[i * 2 + d] = a;
            o[2 * NPART + i * 2 + d] = pp;
        }
    }
}

extern "C" void kernel_launch(void* const* d_in, const int* in_sizes, int n_in,
                              void* d_out, int out_size, void* d_ws, size_t ws_size,
                              hipStream_t stream)
{
    const int* ptype = (const int*)d_in[4];
    const int* nonk  = (const int*)d_in[5];
    const int* snd   = (const int*)d_in[6];
    const int* rcv   = (const int*)d_in[7];
    const unsigned short* braw = (const unsigned short*)d_in[2];

    int fmap[NFLOAT_ARRAYS];
    {
        int c = 0;
        fmap[c++] = 0; fmap[c++] = 1; fmap[c++] = 2; fmap[c++] = 3; fmap[c++] = 8;
        for (int i = 9; i <= 46; i++) fmap[c++] = i;
    }
    ConvArgs ca;
    const float* fp[47];
    float* cw = (float*)d_ws;
    int off = 0;
    for (int i = 0; i < NFLOAT_ARRAYS; i++) {
        ca.src[i] = d_in[fmap[i]];
        ca.n[i]   = in_sizes[fmap[i]];
        ca.off[i] = off;
        fp[fmap[i]] = cw + off;
        off += in_sizes[fmap[i]];
    }
    // workspace: f32 states + packed bf16 weights
    float* nodes = cw + ((off + 3) & ~3);
    float* agg   = nodes + (size_t)NPART * HD;
    float* edges = agg   + (size_t)NPART * HD;
    u16*   wpk   = (u16*)(edges + (size_t)NEDGE * HD);

    // build pack table (order: ne x3, ee x3, ge x30, gn x30)
    PackArgs pa;
    int dst = 0, c = 0;
    int pk[NMAT];
    auto addm = [&](long srcoff, int K) {
        const int nk = (K + 31) / 32;
        pa.src_off[c] = (int)srcoff;
        pa.K[c] = K;
        pa.nks[c] = nk;
        pa.dst_off[c] = dst;
        pk[c] = dst;
        dst += nk * 4096;
        c++;
    };
    addm(fp[9]  - cw, 30);  addm(fp[11] - cw, 128); addm(fp[13] - cw, 128);
    addm(fp[17] - cw, 3);   addm(fp[19] - cw, 128); addm(fp[21] - cw, 128);
    for (int l = 0; l < NLAYER; l++) {
        addm(fp[25] - cw + (long)l * 384 * HD, 384);
        addm(fp[27] - cw + (long)l * HD * HD, 128);
        addm(fp[29] - cw + (long)l * HD * HD, 128);
    }
    for (int l = 0; l < NLAYER; l++) {
        addm(fp[33] - cw + (long)l * 256 * HD, 256);
        addm(fp[35] - cw + (long)l * HD * HD, 128);
        addm(fp[37] - cw + (long)l * HD * HD, 128);
    }

    k_convert<<<dim3(64, NFLOAT_ARRAYS), 256, 0, stream>>>(ca, cw, braw);
    k_pack<<<dim3(192, NMAT), 256, 0, stream>>>(cw, wpk, pa);

    const int NB = (NPART + 63) / 64;   // 469
    const int EB = (NEDGE + 63) / 64;   // 4688

    k_node_enc_m<<<NB, 256, 0, stream>>>(fp[0], fp[1], fp[2], ptype, fp[8],
        wpk + pk[0], fp[10], wpk + pk[1], fp[12], wpk + pk[2], fp[14],
        fp[15], fp[16], nodes);
    k_edge_enc_m<<<EB, 256, 0, stream>>>(fp[1], snd, rcv,
        wpk + pk[3], fp[18], wpk + pk[4], fp[20], wpk + pk[5], fp[22],
        fp[23], fp[24], edges);

    for (int l = 0; l < NLAYER; l++) {
        hipMemsetAsync(agg, 0, (size_t)NPART * HD * sizeof(float), stream);
        k_edge_layer_m<<<EB, 256, 0, stream>>>(nodes, edges, agg, snd, rcv,
            wpk + pk[6 + 3 * l],  fp[26] + (size_t)l * HD,
            wpk + pk[7 + 3 * l],  fp[28] + (size_t)l * HD,
            wpk + pk[8 + 3 * l],  fp[30] + (size_t)l * HD,
            fp[31] + (size_t)l * HD, fp[32] + (size_t)l * HD);
        k_node_layer_m<<<NB, 256, 0, stream>>>(nodes, agg,
            wpk + pk[36 + 3 * l], fp[34] + (size_t)l * HD,
            wpk + pk[37 + 3 * l], fp[36] + (size_t)l * HD,
            wpk + pk[38 + 3 * l], fp[38] + (size_t)l * HD,
            fp[39] + (size_t)l * HD, fp[40] + (size_t)l * HD);
    }

    k_decoder<<<NPART / 8, 128, 0, stream>>>(nodes,
        fp[41], fp[42], fp[43], fp[44], fp[45], fp[46],
        fp[0], fp[1], fp[3], nonk, braw, d_out);
}

// Round 2
// 3722.171 us; speedup vs baseline: 3.9159x; 3.0667x over previous
//
#include <hip/hip_runtime.h>
#include <hip/hip_bf16.h>

typedef __hip_bfloat16 bf16;
typedef unsigned short u16;
typedef unsigned int u32;
typedef __attribute__((ext_vector_type(8))) short short8;
typedef __attribute__((ext_vector_type(4))) float f32x4;

#define NPART 30000
#define NEDGE 300000
#define HD 128
#define NLAYER 10
#define NFLOAT_ARRAYS 43
#define NMAT 66

// ---------------- dtype detect ----------------
__device__ __forceinline__ bool detect_bf16(const unsigned short* braw) {
    return braw[1] == 0x3F80u;
}

// ---------------- fp32<->bf16 helpers (RNE) ----------------
__device__ __forceinline__ u16 f2b(float f) {
    u32 u = __float_as_uint(f);
    u += 0x7FFFu + ((u >> 16) & 1u);
    return (u16)(u >> 16);
}
__device__ __forceinline__ u32 pack2(float a, float b) {
    return (u32)f2b(a) | ((u32)f2b(b) << 16);
}

// ---------------- convert all float arrays to canonical fp32 ----------------
struct ConvArgs {
    const void* src[NFLOAT_ARRAYS];
    int n[NFLOAT_ARRAYS];
    int off[NFLOAT_ARRAYS];
};

__global__ __launch_bounds__(256)
void k_convert(ConvArgs a, float* __restrict__ dst, const unsigned short* __restrict__ braw)
{
    const bool isb = detect_bf16(braw);
    const int aid = blockIdx.y;
    const int n = a.n[aid];
    float* o = dst + a.off[aid];
    const int stride = gridDim.x * 256;
    int i = blockIdx.x * 256 + threadIdx.x;
    if (isb) {
        const unsigned short* s = (const unsigned short*)a.src[aid];
        for (; i < n; i += stride) {
            const unsigned int u = ((unsigned int)s[i]) << 16;
            o[i] = __uint_as_float(u);
        }
    } else {
        const float* s = (const float*)a.src[aid];
        for (; i < n; i += stride) o[i] = s[i];
    }
}

// ---------------- counting sort of edges by receiver ----------------
__global__ __launch_bounds__(256)
void k_hist(const int* __restrict__ rcv, int* __restrict__ counts)
{
    const int e = blockIdx.x * 256 + threadIdx.x;
    if (e < NEDGE) atomicAdd(&counts[rcv[e]], 1);
}

__global__ __launch_bounds__(1024)
void k_scan(const int* __restrict__ counts, int* __restrict__ row_ptr, int* __restrict__ cursor)
{
    __shared__ int part[1024];
    const int t = threadIdx.x;
    const int base = t * 32;
    int local[32];
    int s = 0;
#pragma unroll
    for (int k = 0; k < 32; k++) {
        const int idx = base + k;
        const int v = (idx < NPART) ? counts[idx] : 0;
        local[k] = s;
        s += v;
    }
    part[t] = s;
    __syncthreads();
    for (int off = 1; off < 1024; off <<= 1) {
        const int v = (t >= off) ? part[t - off] : 0;
        __syncthreads();
        part[t] += v;
        __syncthreads();
    }
    const int excl = (t == 0) ? 0 : part[t - 1];
#pragma unroll
    for (int k = 0; k < 32; k++) {
        const int idx = base + k;
        if (idx < NPART) {
            const int rp = excl + local[k];
            row_ptr[idx] = rp;
            cursor[idx] = rp;
        }
    }
    if (t == 0) row_ptr[NPART] = NEDGE;
}

__global__ __launch_bounds__(256)
void k_scatter(const int* __restrict__ snd, const int* __restrict__ rcv,
               int* __restrict__ cursor, int* __restrict__ snd_s, int* __restrict__ rcv_s)
{
    const int e = blockIdx.x * 256 + threadIdx.x;
    if (e < NEDGE) {
        const int r = rcv[e];
        const int p = atomicAdd(&cursor[r], 1);
        snd_s[p] = snd[e];
        rcv_s[p] = r;
    }
}

// ---------------- weight pre-pack: f32 [K][128] -> bf16 fragment-linear ----------------
// dst layout: [mtile(8)][ks(K/32)][lane(64)][8 contiguous k] ushorts.
struct PackArgs {
    int src_off[NMAT];
    int dst_off[NMAT];
    int K[NMAT];
    int nks[NMAT];
};

__global__ __launch_bounds__(256)
void k_pack(const float* __restrict__ cw, u16* __restrict__ wpk, PackArgs pa)
{
    const int mid = blockIdx.y;
    const int nks = pa.nks[mid];
    const int total = nks * 4096;
    const int d = blockIdx.x * 256 + threadIdx.x;
    if (d >= total) return;
    const int j = d & 7, l = (d >> 3) & 63, t = d >> 9;
    const int ks = t % nks, mt = t / nks;
    const int hid = mt * 16 + (l & 15);
    const int k = ks * 32 + (l >> 4) * 8 + j;
    const float v = (k < pa.K[mid]) ? cw[pa.src_off[mid] + k * HD + hid] : 0.0f;
    wpk[pa.dst_off[mid] + d] = f2b(v);
}

// ---------------- MFMA GEMM tile: 64 rows x 128 hid, 4 waves ----------------
template<int NKS, int XROW>
__device__ __forceinline__ void gemm16(const u16* __restrict__ Wp,
                                       const float* __restrict__ Bias,
                                       const u16* __restrict__ x,
                                       f32x4 acc[4][2],
                                       const int wm, const int wn,
                                       const int l15, const int lg, const int lane)
{
#pragma unroll
    for (int mt = 0; mt < 4; mt++) {
        const f32x4 bv = *(const f32x4*)(Bias + wm * 64 + mt * 16 + lg * 4);
        acc[mt][0] = bv;
        acc[mt][1] = bv;
    }
    const u16* xr0 = x + (wn * 32 + l15) * XROW + lg * 8;
    const u16* xr1 = xr0 + 16 * XROW;
    const u16* wp = Wp + (wm * 4 * NKS) * 512 + lane * 8;
#pragma unroll
    for (int ks = 0; ks < NKS; ks++) {
        const short8 b0 = *(const short8*)(xr0 + ks * 32);
        const short8 b1 = *(const short8*)(xr1 + ks * 32);
#pragma unroll
        for (int mt = 0; mt < 4; mt++) {
            const short8 a = *(const short8*)(wp + (mt * NKS + ks) * 512);
            acc[mt][0] = __builtin_amdgcn_mfma_f32_16x16x32_bf16(a, b0, acc[mt][0], 0, 0, 0);
            acc[mt][1] = __builtin_amdgcn_mfma_f32_16x16x32_bf16(a, b1, acc[mt][1], 0, 0, 0);
        }
    }
}

// relu + pack 4 bf16 + 8B LDS store into h[row][136]
__device__ __forceinline__ void store_h(u16* __restrict__ h, const f32x4 acc[4][2],
                                        const int wm, const int wn, const int l15, const int lg)
{
#pragma unroll
    for (int nt = 0; nt < 2; nt++) {
        const int e = wn * 32 + nt * 16 + l15;
#pragma unroll
        for (int mt = 0; mt < 4; mt++) {
            const int hid = wm * 64 + mt * 16 + lg * 4;
            const f32x4 v = acc[mt][nt];
            const u32 lo = pack2(fmaxf(v[0], 0.0f), fmaxf(v[1], 0.0f));
            const u32 hi = pack2(fmaxf(v[2], 0.0f), fmaxf(v[3], 0.0f));
            *(uint2*)(h + e * 136 + hid) = make_uint2(lo, hi);
        }
    }
}

template<int NKS1, int XROW>
__device__ __forceinline__ void mlp_mfma(const u16* __restrict__ xs,
    u16* __restrict__ h1, u16* __restrict__ h2,
    float (*red)[2][2][16][2],
    const u16* __restrict__ W1p, const float* __restrict__ B1,
    const u16* __restrict__ W2p, const float* __restrict__ B2,
    const u16* __restrict__ W3p, const float* __restrict__ B3,
    const float* __restrict__ g, const float* __restrict__ be,
    float outv[4][2][4],
    const int wm, const int wn, const int l15, const int lg, const int lane)
{
    f32x4 acc[4][2];
    gemm16<NKS1, XROW>(W1p, B1, xs, acc, wm, wn, l15, lg, lane);
    __syncthreads();                      // all waves done reading xs
    store_h(h1, acc, wm, wn, l15, lg);    // h1 may overlay xs
    __syncthreads();
    gemm16<4, 136>(W2p, B2, h1, acc, wm, wn, l15, lg, lane);
    store_h(h2, acc, wm, wn, l15, lg);    // h2 disjoint from h1
    __syncthreads();
    gemm16<4, 136>(W3p, B3, h2, acc, wm, wn, l15, lg, lane);
    // ---- layernorm over 128 features per row ----
    float ps[2], pss[2];
#pragma unroll
    for (int nt = 0; nt < 2; nt++) {
        float s = 0.0f, ss = 0.0f;
#pragma unroll
        for (int mt = 0; mt < 4; mt++) {
#pragma unroll
            for (int r = 0; r < 4; r++) {
                const float v = acc[mt][nt][r];
                s += v; ss += v * v;
            }
        }
        s += __shfl_xor(s, 16); ss += __shfl_xor(ss, 16);
        s += __shfl_xor(s, 32); ss += __shfl_xor(ss, 32);
        ps[nt] = s; pss[nt] = ss;
    }
    if (lane < 16) {
#pragma unroll
        for (int nt = 0; nt < 2; nt++) {
            red[wm][wn][nt][l15][0] = ps[nt];
            red[wm][wn][nt][l15][1] = pss[nt];
        }
    }
    __syncthreads();
#pragma unroll
    for (int nt = 0; nt < 2; nt++) {
        const float S  = red[0][wn][nt][l15][0] + red[1][wn][nt][l15][0];
        const float SS = red[0][wn][nt][l15][1] + red[1][wn][nt][l15][1];
        const float mu  = S * (1.0f / 128.0f);
        const float var = SS * (1.0f / 128.0f) - mu * mu;
        const float inv = rsqrtf(var + 1e-5f);
#pragma unroll
        for (int mt = 0; mt < 4; mt++) {
            const int hid = wm * 64 + mt * 16 + lg * 4;
            const f32x4 gv  = *(const f32x4*)(g + hid);
            const f32x4 bev = *(const f32x4*)(be + hid);
#pragma unroll
            for (int r = 0; r < 4; r++)
                outv[mt][nt][r] = (acc[mt][nt][r] - mu) * inv * gv[r] + bev[r];
        }
    }
}

// ---------------- node encoder (K=30 padded to 32) ----------------
__device__ __forceinline__ float nfeat(int i, int k,
    const float* __restrict__ vel, const float* __restrict__ pos,
    const float* __restrict__ bounds, const int* __restrict__ ptype,
    const float* __restrict__ emb)
{
    if (k < 10) return vel[i * 10 + k];
    if (k < 14) {
        const int q = k - 10;
        float sub;
        if (q < 2) sub = pos[i * 2 + q] - bounds[q * 2 + 0];
        else       sub = bounds[(q - 2) * 2 + 1] - pos[i * 2 + (q - 2)];
        const float dv = sub * 20.0f;
        return fminf(fmaxf(dv, -1.0f), 1.0f);
    }
    if (k < 30) return emb[ptype[i] * 16 + (k - 14)];
    return 0.0f;
}

__global__ __launch_bounds__(256)
void k_node_enc_m(const float* __restrict__ vel, const float* __restrict__ pos,
                  const float* __restrict__ bounds, const int* __restrict__ ptype,
                  const float* __restrict__ emb,
                  const u16* __restrict__ W1p, const float* __restrict__ B1,
                  const u16* __restrict__ W2p, const float* __restrict__ B2,
                  const u16* __restrict__ W3p, const float* __restrict__ B3,
                  const float* __restrict__ g, const float* __restrict__ be,
                  float* __restrict__ nodes, u16* __restrict__ nodes_bf)
{
    __shared__ __align__(16) u16 lds[17408];
    __shared__ float red[2][2][2][16][2];
    const int tid = threadIdx.x;
    const int i0 = blockIdx.x * 64;
    for (int idx = tid; idx < 1024; idx += 256) {
        const int m = idx >> 4, kk = idx & 15;
        const int i = i0 + m;
        float f0 = 0.0f, f1 = 0.0f;
        if (i < NPART) {
            f0 = nfeat(i, kk * 2 + 0, vel, pos, bounds, ptype, emb);
            f1 = nfeat(i, kk * 2 + 1, vel, pos, bounds, ptype, emb);
        }
        *(u32*)(lds + m * 40 + kk * 2) = pack2(f0, f1);
    }
    __syncthreads();
    const int lane = tid & 63, wv = tid >> 6;
    const int wm = wv >> 1, wn = wv & 1, l15 = lane & 15, lg = lane >> 4;
    float outv[4][2][4];
    mlp_mfma<1, 40>(lds, lds, lds + 8704, red, W1p, B1, W2p, B2, W3p, B3, g, be,
                    outv, wm, wn, l15, lg, lane);
#pragma unroll
    for (int nt = 0; nt < 2; nt++) {
        const int i = i0 + wn * 32 + nt * 16 + l15;
        if (i < NPART) {
#pragma unroll
            for (int mt = 0; mt < 4; mt++) {
                const int hid = wm * 64 + mt * 16 + lg * 4;
                const float4 v = make_float4(outv[mt][nt][0], outv[mt][nt][1],
                                             outv[mt][nt][2], outv[mt][nt][3]);
                *(float4*)(nodes + (size_t)i * HD + hid) = v;
                *(uint2*)(nodes_bf + (size_t)i * HD + hid) =
                    make_uint2(pack2(v.x, v.y), pack2(v.z, v.w));
            }
        }
    }
}

// ---------------- edge encoder (K=3 padded to 32), sorted edge order ----------------
__global__ __launch_bounds__(256)
void k_edge_enc_m(const float* __restrict__ pos, const int* __restrict__ snd_s,
                  const int* __restrict__ rcv_s,
                  const u16* __restrict__ W1p, const float* __restrict__ B1,
                  const u16* __restrict__ W2p, const float* __restrict__ B2,
                  const u16* __restrict__ W3p, const float* __restrict__ B3,
                  const float* __restrict__ g, const float* __restrict__ be,
                  float* __restrict__ edges)
{
    __shared__ __align__(16) u16 lds[17408];
    __shared__ float red[2][2][2][16][2];
    const int tid = threadIdx.x;
    const int e0 = blockIdx.x * 64;
    for (int idx = tid; idx < 1024; idx += 256) {
        const int m = idx >> 4, kk = idx & 15;
        const int e = min(e0 + m, NEDGE - 1);
        u32 w = 0;
        if (kk < 2) {
            const int s = snd_s[e], r = rcv_s[e];
            const float dx = (pos[s * 2 + 0] - pos[r * 2 + 0]) * 20.0f;
            const float dy = (pos[s * 2 + 1] - pos[r * 2 + 1]) * 20.0f;
            if (kk == 0) w = pack2(dx, dy);
            else         w = pack2(sqrtf(dx * dx + dy * dy), 0.0f);
        }
        *(u32*)(lds + m * 40 + kk * 2) = w;
    }
    __syncthreads();
    const int lane = tid & 63, wv = tid >> 6;
    const int wm = wv >> 1, wn = wv & 1, l15 = lane & 15, lg = lane >> 4;
    float outv[4][2][4];
    mlp_mfma<1, 40>(lds, lds, lds + 8704, red, W1p, B1, W2p, B2, W3p, B3, g, be,
                    outv, wm, wn, l15, lg, lane);
#pragma unroll
    for (int nt = 0; nt < 2; nt++) {
        const int e = e0 + wn * 32 + nt * 16 + l15;
        if (e < NEDGE) {
#pragma unroll
            for (int mt = 0; mt < 4; mt++) {
                const int hid = wm * 64 + mt * 16 + lg * 4;
                *(float4*)(edges + (size_t)e * HD + hid) =
                    make_float4(outv[mt][nt][0], outv[mt][nt][1], outv[mt][nt][2], outv[mt][nt][3]);
            }
        }
    }
}

// ---------------- per-layer edge update (K=384), no scatter ----------------
__global__ __launch_bounds__(256)
void k_edge_layer_m(const u16* __restrict__ nodes_bf, float* __restrict__ edges,
                    const int* __restrict__ snd_s, const int* __restrict__ rcv_s,
                    const u16* __restrict__ W1p, const float* __restrict__ B1,
                    const u16* __restrict__ W2p, const float* __restrict__ B2,
                    const u16* __restrict__ W3p, const float* __restrict__ B3,
                    const float* __restrict__ g, const float* __restrict__ be)
{
    __shared__ __align__(16) u16 lds[25088];   // xs 64x392; h1/h2 overlay front
    __shared__ float red[2][2][2][16][2];
    const int tid = threadIdx.x;
    const int e0 = blockIdx.x * 64;
    // gather [edge(f32->bf16) | node_snd(bf16) | node_rcv(bf16)] -> LDS
    for (int idx = tid; idx < 3072; idx += 256) {
        const int m = idx / 48;
        const int r2 = idx - m * 48;
        const int s = r2 >> 4, q = r2 & 15;
        const int e = min(e0 + m, NEDGE - 1);
        uint4 w;
        if (s == 0) {
            const float* src = edges + (size_t)e * HD + q * 8;
            const float4 a = *(const float4*)(src);
            const float4 b = *(const float4*)(src + 4);
            w = make_uint4(pack2(a.x, a.y), pack2(a.z, a.w), pack2(b.x, b.y), pack2(b.z, b.w));
        } else {
            const int n = (s == 1) ? snd_s[e] : rcv_s[e];
            w = *(const uint4*)(nodes_bf + (size_t)n * HD + q * 8);
        }
        *(uint4*)(lds + m * 392 + s * 128 + q * 8) = w;
    }
    __syncthreads();
    const int lane = tid & 63, wv = tid >> 6;
    const int wm = wv >> 1, wn = wv & 1, l15 = lane & 15, lg = lane >> 4;
    float outv[4][2][4];
    mlp_mfma<12, 392>(lds, lds, lds + 8704, red, W1p, B1, W2p, B2, W3p, B3, g, be,
                      outv, wm, wn, l15, lg, lane);
    // residual + store (f32 state, sequential)
#pragma unroll
    for (int nt = 0; nt < 2; nt++) {
        const int e = e0 + wn * 32 + nt * 16 + l15;
        if (e < NEDGE) {
            float* ep = edges + (size_t)e * HD;
#pragma unroll
            for (int mt = 0; mt < 4; mt++) {
                const int hid = wm * 64 + mt * 16 + lg * 4;
                const float4 old = *(const float4*)(ep + hid);
                *(float4*)(ep + hid) = make_float4(old.x + outv[mt][nt][0],
                                                   old.y + outv[mt][nt][1],
                                                   old.z + outv[mt][nt][2],
                                                   old.w + outv[mt][nt][3]);
            }
        }
    }
}

// ---------------- per-layer node update (K=256) with fused CSR segment-sum ----------------
__global__ __launch_bounds__(256)
void k_node_layer_m(float* __restrict__ nodes, u16* __restrict__ nodes_bf,
                    const float* __restrict__ edges, const int* __restrict__ row_ptr,
                    const u16* __restrict__ W1p, const float* __restrict__ B1,
                    const u16* __restrict__ W2p, const float* __restrict__ B2,
                    const u16* __restrict__ W3p, const float* __restrict__ B3,
                    const float* __restrict__ g, const float* __restrict__ be)
{
    __shared__ __align__(16) u16 lds[17408];   // xs 64x264; h1/h2 overlay
    __shared__ float red[2][2][2][16][2];
    const int tid = threadIdx.x;
    const int i0 = blockIdx.x * 64;
    for (int idx = tid; idx < 2048; idx += 256) {
        const int m = idx >> 5, r2 = idx & 31;
        const int s = r2 >> 4, q = r2 & 15;
        const int i = min(i0 + m, NPART - 1);
        uint4 w;
        if (s == 0) {
            const float* src = nodes + (size_t)i * HD + q * 8;
            const float4 a = *(const float4*)(src);
            const float4 b = *(const float4*)(src + 4);
            w = make_uint4(pack2(a.x, a.y), pack2(a.z, a.w), pack2(b.x, b.y), pack2(b.z, b.w));
        } else {
            // agg[i][q*8 .. q*8+7] = sum over CSR run of updated edges (f32)
            const int p0 = row_ptr[i], p1 = row_ptr[i + 1];
            float s0 = 0, s1 = 0, s2 = 0, s3 = 0, s4 = 0, s5 = 0, s6 = 0, s7 = 0;
            for (int p = p0; p < p1; p++) {
                const float* er = edges + (size_t)p * HD + q * 8;
                const float4 a = *(const float4*)(er);
                const float4 b = *(const float4*)(er + 4);
                s0 += a.x; s1 += a.y; s2 += a.z; s3 += a.w;
                s4 += b.x; s5 += b.y; s6 += b.z; s7 += b.w;
            }
            w = make_uint4(pack2(s0, s1), pack2(s2, s3), pack2(s4, s5), pack2(s6, s7));
        }
        *(uint4*)(lds + m * 264 + s * 128 + q * 8) = w;
    }
    __syncthreads();
    const int lane = tid & 63, wv = tid >> 6;
    const int wm = wv >> 1, wn = wv & 1, l15 = lane & 15, lg = lane >> 4;
    float outv[4][2][4];
    mlp_mfma<8, 264>(lds, lds, lds + 8704, red, W1p, B1, W2p, B2, W3p, B3, g, be,
                     outv, wm, wn, l15, lg, lane);
#pragma unroll
    for (int nt = 0; nt < 2; nt++) {
        const int i = i0 + wn * 32 + nt * 16 + l15;
        if (i < NPART) {
            float* np = nodes + (size_t)i * HD;
#pragma unroll
            for (int mt = 0; mt < 4; mt++) {
                const int hid = wm * 64 + mt * 16 + lg * 4;
                const float4 old = *(const float4*)(np + hid);
                const float4 nv = make_float4(old.x + outv[mt][nt][0],
                                              old.y + outv[mt][nt][1],
                                              old.z + outv[mt][nt][2],
                                              old.w + outv[mt][nt][3]);
                *(float4*)(np + hid) = nv;
                *(uint2*)(nodes_bf + (size_t)i * HD + hid) =
                    make_uint2(pack2(nv.x, nv.y), pack2(nv.z, nv.w));
            }
        }
    }
}

// ---------------- fp32 gemv for decoder ----------------
template<int K, int S>
__device__ __forceinline__ void gemv(const float* __restrict__ in,
                                     const float* __restrict__ W,
                                     const float* __restrict__ B,
                                     float acc[8])
{
    const int j = threadIdx.x;
    const float bb = B[j];
#pragma unroll
    for (int m = 0; m < 8; m++) acc[m] = bb;
    constexpr int K4 = (K / 4) * 4;
    for (int k = 0; k < K4; k += 4) {
        const float w0 = W[(k + 0) * HD + j];
        const float w1 = W[(k + 1) * HD + j];
        const float w2 = W[(k + 2) * HD + j];
        const float w3 = W[(k + 3) * HD + j];
#pragma unroll
        for (int m = 0; m < 8; m++) {
            const float4 x = *(const float4*)(in + m * S + k);
            float a = acc[m];
            a = fmaf(x.x, w0, a);
            a = fmaf(x.y, w1, a);
            a = fmaf(x.z, w2, a);
            a = fmaf(x.w, w3, a);
            acc[m] = a;
        }
    }
#pragma unroll
    for (int k = K4; k < K; k++) {
        const float w = W[k * HD + j];
#pragma unroll
        for (int m = 0; m < 8; m++) acc[m] = fmaf(in[m * S + k], w, acc[m]);
    }
}

// ---------------- decoder + Euler integration (dual output dtype) ----------------
__global__ __launch_bounds__(128)
void k_decoder(const float* __restrict__ nodes,
               const float* W1, const float* B1, const float* W2, const float* B2,
               const float* W3, const float* B3,
               const float* __restrict__ vel, const float* __restrict__ pos,
               const float* __restrict__ tgt, const int* __restrict__ nonk,
               const unsigned short* __restrict__ braw, void* __restrict__ d_out)
{
    __shared__ __align__(16) float xs[8 * HD];
    __shared__ __align__(16) float h1[8 * HD];
    __shared__ __align__(16) float h2[8 * HD];
    const int j = threadIdx.x;
    const int i0 = blockIdx.x * 8;
    float acc[8];
#pragma unroll
    for (int m = 0; m < 8; m++) xs[m * HD + j] = nodes[(i0 + m) * HD + j];
    __syncthreads();
    gemv<HD, HD>(xs, W1, B1, acc);
#pragma unroll
    for (int m = 0; m < 8; m++) h1[m * HD + j] = fmaxf(acc[m], 0.0f);
    __syncthreads();
    gemv<HD, HD>(h1, W2, B2, acc);
#pragma unroll
    for (int m = 0; m < 8; m++) h2[m * HD + j] = fmaxf(acc[m], 0.0f);
    __syncthreads();
    if (j < 16) {
        const int m = j >> 1, d = j & 1, i = i0 + m;
        float a = B3[d];
        for (int k = 0; k < HD; k++) a = fmaf(h2[m * HD + k], W3[k * 2 + d], a);
        float pp = pos[i * 2 + d] + vel[i * 10 + 8 + d] + a;
        if (nonk[i] == 0) pp = tgt[i * 2 + d];
        if (detect_bf16(braw)) {
            bf16* o = (bf16*)d_out;
            o[i * 2 + d] = __float2bfloat16(a);
            o[2 * NPART + i * 2 + d] = __float2bfloat16(pp);
        } else {
            float* o = (float*)d_out;
            o[i * 2 + d] = a;
            o[2 * NPART + i * 2 + d] = pp;
        }
    }
}

extern "C" void kernel_launch(void* const* d_in, const int* in_sizes, int n_in,
                              void* d_out, int out_size, void* d_ws, size_t ws_size,
                              hipStream_t stream)
{
    const int* ptype = (const int*)d_in[4];
    const int* nonk  = (const int*)d_in[5];
    const int* snd   = (const int*)d_in[6];
    const int* rcv   = (const int*)d_in[7];
    const unsigned short* braw = (const unsigned short*)d_in[2];

    int fmap[NFLOAT_ARRAYS];
    {
        int c = 0;
        fmap[c++] = 0; fmap[c++] = 1; fmap[c++] = 2; fmap[c++] = 3; fmap[c++] = 8;
        for (int i = 9; i <= 46; i++) fmap[c++] = i;
    }
    ConvArgs ca;
    const float* fp[47];
    float* cw = (float*)d_ws;
    int off = 0;
    for (int i = 0; i < NFLOAT_ARRAYS; i++) {
        ca.src[i] = d_in[fmap[i]];
        ca.n[i]   = in_sizes[fmap[i]];
        ca.off[i] = off;
        fp[fmap[i]] = cw + off;
        off += in_sizes[fmap[i]];
    }
    // workspace: f32 states + bf16 node mirror + packed weights + sort scratch
    float* nodes = cw + ((off + 3) & ~3);
    float* edges = nodes + (size_t)NPART * HD;
    u16* nodes_bf = (u16*)(edges + (size_t)NEDGE * HD);
    u16* wpk = nodes_bf + (size_t)NPART * HD;

    // build pack table (order: ne x3, ee x3, ge x30, gn x30)
    PackArgs pa;
    int dst = 0, c = 0;
    int pk[NMAT];
    auto addm = [&](long srcoff, int K) {
        const int nk = (K + 31) / 32;
        pa.src_off[c] = (int)srcoff;
        pa.K[c] = K;
        pa.nks[c] = nk;
        pa.dst_off[c] = dst;
        pk[c] = dst;
        dst += nk * 4096;
        c++;
    };
    addm(fp[9]  - cw, 30);  addm(fp[11] - cw, 128); addm(fp[13] - cw, 128);
    addm(fp[17] - cw, 3);   addm(fp[19] - cw, 128); addm(fp[21] - cw, 128);
    for (int l = 0; l < NLAYER; l++) {
        addm(fp[25] - cw + (long)l * 384 * HD, 384);
        addm(fp[27] - cw + (long)l * HD * HD, 128);
        addm(fp[29] - cw + (long)l * HD * HD, 128);
    }
    for (int l = 0; l < NLAYER; l++) {
        addm(fp[33] - cw + (long)l * 256 * HD, 256);
        addm(fp[35] - cw + (long)l * HD * HD, 128);
        addm(fp[37] - cw + (long)l * HD * HD, 128);
    }

    int* ip = (int*)(wpk + ((dst + 7) & ~7));
    int* row_ptr = ip;            ip += NPART + 8;
    int* cursor  = ip;            ip += NPART;
    int* counts  = ip;            ip += NPART;
    int* snd_s   = ip;            ip += NEDGE;
    int* rcv_s   = ip;

    const int EBL = (NEDGE + 255) / 256;

    k_convert<<<dim3(64, NFLOAT_ARRAYS), 256, 0, stream>>>(ca, cw, braw);
    // counting sort of edges by receiver (independent of convert)
    hipMemsetAsync(counts, 0, (size_t)NPART * sizeof(int), stream);
    k_hist<<<EBL, 256, 0, stream>>>(rcv, counts);
    k_scan<<<1, 1024, 0, stream>>>(counts, row_ptr, cursor);
    k_scatter<<<EBL, 256, 0, stream>>>(snd, rcv, cursor, snd_s, rcv_s);
    k_pack<<<dim3(192, NMAT), 256, 0, stream>>>(cw, wpk, pa);

    const int NB = (NPART + 63) / 64;   // 469
    const int EB = (NEDGE + 63) / 64;   // 4688

    k_node_enc_m<<<NB, 256, 0, stream>>>(fp[0], fp[1], fp[2], ptype, fp[8],
        wpk + pk[0], fp[10], wpk + pk[1], fp[12], wpk + pk[2], fp[14],
        fp[15], fp[16], nodes, nodes_bf);
    k_edge_enc_m<<<EB, 256, 0, stream>>>(fp[1], snd_s, rcv_s,
        wpk + pk[3], fp[18], wpk + pk[4], fp[20], wpk + pk[5], fp[22],
        fp[23], fp[24], edges);

    for (int l = 0; l < NLAYER; l++) {
        k_edge_layer_m<<<EB, 256, 0, stream>>>(nodes_bf, edges, snd_s, rcv_s,
            wpk + pk[6 + 3 * l],  fp[26] + (size_t)l * HD,
            wpk + pk[7 + 3 * l],  fp[28] + (size_t)l * HD,
            wpk + pk[8 + 3 * l],  fp[30] + (size_t)l * HD,
            fp[31] + (size_t)l * HD, fp[32] + (size_t)l * HD);
        k_node_layer_m<<<NB, 256, 0, stream>>>(nodes, nodes_bf, edges, row_ptr,
            wpk + pk[36 + 3 * l], fp[34] + (size_t)l * HD,
            wpk + pk[37 + 3 * l], fp[36] + (size_t)l * HD,
            wpk + pk[38 + 3 * l], fp[38] + (size_t)l * HD,
            fp[39] + (size_t)l * HD, fp[40] + (size_t)l * HD);
    }

    k_decoder<<<NPART / 8, 128, 0, stream>>>(nodes,
        fp[41], fp[42], fp[43], fp[44], fp[45], fp[46],
        fp[0], fp[1], fp[3], nonk, braw, d_out);
}

// Round 3
// 2594.379 us; speedup vs baseline: 5.6182x; 1.4347x over previous
//
#include <hip/hip_runtime.h>
#include <hip/hip_bf16.h>

typedef __hip_bfloat16 bf16;
typedef unsigned short u16;
typedef unsigned int u32;
typedef __attribute__((ext_vector_type(8))) short short8;
typedef __attribute__((ext_vector_type(4))) float f32x4;

#define NPART 30000
#define NEDGE 300000
#define HD 128
#define NLAYER 10
#define NFLOAT_ARRAYS 43
#define NMAT 66

// ---------------- dtype detect ----------------
__device__ __forceinline__ bool detect_bf16(const unsigned short* braw) {
    return braw[1] == 0x3F80u;
}

// ---------------- fp32<->bf16 helpers (RNE) ----------------
__device__ __forceinline__ u16 f2b(float f) {
    u32 u = __float_as_uint(f);
    u += 0x7FFFu + ((u >> 16) & 1u);
    return (u16)(u >> 16);
}
__device__ __forceinline__ u32 pack2(float a, float b) {
    return (u32)f2b(a) | ((u32)f2b(b) << 16);
}

// ---------------- convert all float arrays to canonical fp32 ----------------
struct ConvArgs {
    const void* src[NFLOAT_ARRAYS];
    int n[NFLOAT_ARRAYS];
    int off[NFLOAT_ARRAYS];
};

__global__ __launch_bounds__(256)
void k_convert(ConvArgs a, float* __restrict__ dst, const unsigned short* __restrict__ braw)
{
    const bool isb = detect_bf16(braw);
    const int aid = blockIdx.y;
    const int n = a.n[aid];
    float* o = dst + a.off[aid];
    const int stride = gridDim.x * 256;
    int i = blockIdx.x * 256 + threadIdx.x;
    if (isb) {
        const unsigned short* s = (const unsigned short*)a.src[aid];
        for (; i < n; i += stride) {
            const unsigned int u = ((unsigned int)s[i]) << 16;
            o[i] = __uint_as_float(u);
        }
    } else {
        const float* s = (const float*)a.src[aid];
        for (; i < n; i += stride) o[i] = s[i];
    }
}

// ---------------- counting sort of edges by receiver ----------------
__global__ __launch_bounds__(256)
void k_hist(const int* __restrict__ rcv, int* __restrict__ counts)
{
    const int e = blockIdx.x * 256 + threadIdx.x;
    if (e < NEDGE) atomicAdd(&counts[rcv[e]], 1);
}

__global__ __launch_bounds__(1024)
void k_scan(const int* __restrict__ counts, int* __restrict__ row_ptr, int* __restrict__ cursor)
{
    __shared__ int part[1024];
    const int t = threadIdx.x;
    const int base = t * 32;
    int local[32];
    int s = 0;
#pragma unroll
    for (int k = 0; k < 32; k++) {
        const int idx = base + k;
        const int v = (idx < NPART) ? counts[idx] : 0;
        local[k] = s;
        s += v;
    }
    part[t] = s;
    __syncthreads();
    for (int off = 1; off < 1024; off <<= 1) {
        const int v = (t >= off) ? part[t - off] : 0;
        __syncthreads();
        part[t] += v;
        __syncthreads();
    }
    const int excl = (t == 0) ? 0 : part[t - 1];
#pragma unroll
    for (int k = 0; k < 32; k++) {
        const int idx = base + k;
        if (idx < NPART) {
            const int rp = excl + local[k];
            row_ptr[idx] = rp;
            cursor[idx] = rp;
        }
    }
    if (t == 0) row_ptr[NPART] = NEDGE;
}

__global__ __launch_bounds__(256)
void k_scatter(const int* __restrict__ snd, const int* __restrict__ rcv,
               int* __restrict__ cursor, int* __restrict__ snd_s, int* __restrict__ rcv_s)
{
    const int e = blockIdx.x * 256 + threadIdx.x;
    if (e < NEDGE) {
        const int r = rcv[e];
        const int p = atomicAdd(&cursor[r], 1);
        snd_s[p] = snd[e];
        rcv_s[p] = r;
    }
}

// ---------------- weight pre-pack: f32 [K][128] -> bf16 fragment-linear ----------------
// dst layout: [mtile(8)][ks(K/32)][lane(64)][8 contiguous k] ushorts.
struct PackArgs {
    int src_off[NMAT];
    int dst_off[NMAT];
    int K[NMAT];
    int nks[NMAT];
};

__global__ __launch_bounds__(256)
void k_pack(const float* __restrict__ cw, u16* __restrict__ wpk, PackArgs pa)
{
    const int mid = blockIdx.y;
    const int nks = pa.nks[mid];
    const int total = nks * 4096;
    const int d = blockIdx.x * 256 + threadIdx.x;
    if (d >= total) return;
    const int j = d & 7, l = (d >> 3) & 63, t = d >> 9;
    const int ks = t % nks, mt = t / nks;
    const int hid = mt * 16 + (l & 15);
    const int k = ks * 32 + (l >> 4) * 8 + j;
    const float v = (k < pa.K[mid]) ? cw[pa.src_off[mid] + k * HD + hid] : 0.0f;
    wpk[pa.dst_off[mid] + d] = f2b(v);
}

// ================= 4-wave (256-thr) MFMA MLP: encoders + node layer =================
template<int NKS, int XROW>
__device__ __forceinline__ void gemm16(const u16* __restrict__ Wp,
                                       const float* __restrict__ Bias,
                                       const u16* __restrict__ x,
                                       f32x4 acc[4][2],
                                       const int wm, const int wn,
                                       const int l15, const int lg, const int lane)
{
#pragma unroll
    for (int mt = 0; mt < 4; mt++) {
        const f32x4 bv = *(const f32x4*)(Bias + wm * 64 + mt * 16 + lg * 4);
        acc[mt][0] = bv;
        acc[mt][1] = bv;
    }
    const u16* xr0 = x + (wn * 32 + l15) * XROW + lg * 8;
    const u16* xr1 = xr0 + 16 * XROW;
    const u16* wp = Wp + (wm * 4 * NKS) * 512 + lane * 8;
#pragma unroll
    for (int ks = 0; ks < NKS; ks++) {
        const short8 b0 = *(const short8*)(xr0 + ks * 32);
        const short8 b1 = *(const short8*)(xr1 + ks * 32);
#pragma unroll
        for (int mt = 0; mt < 4; mt++) {
            const short8 a = *(const short8*)(wp + (mt * NKS + ks) * 512);
            acc[mt][0] = __builtin_amdgcn_mfma_f32_16x16x32_bf16(a, b0, acc[mt][0], 0, 0, 0);
            acc[mt][1] = __builtin_amdgcn_mfma_f32_16x16x32_bf16(a, b1, acc[mt][1], 0, 0, 0);
        }
    }
}

__device__ __forceinline__ void store_h(u16* __restrict__ h, const f32x4 acc[4][2],
                                        const int wm, const int wn, const int l15, const int lg)
{
#pragma unroll
    for (int nt = 0; nt < 2; nt++) {
        const int e = wn * 32 + nt * 16 + l15;
#pragma unroll
        for (int mt = 0; mt < 4; mt++) {
            const int hid = wm * 64 + mt * 16 + lg * 4;
            const f32x4 v = acc[mt][nt];
            const u32 lo = pack2(fmaxf(v[0], 0.0f), fmaxf(v[1], 0.0f));
            const u32 hi = pack2(fmaxf(v[2], 0.0f), fmaxf(v[3], 0.0f));
            *(uint2*)(h + e * 136 + hid) = make_uint2(lo, hi);
        }
    }
}

template<int NKS1, int XROW>
__device__ __forceinline__ void mlp_mfma(const u16* __restrict__ xs,
    u16* __restrict__ h1, u16* __restrict__ h2,
    float (*red)[2][2][16][2],
    const u16* __restrict__ W1p, const float* __restrict__ B1,
    const u16* __restrict__ W2p, const float* __restrict__ B2,
    const u16* __restrict__ W3p, const float* __restrict__ B3,
    const float* __restrict__ g, const float* __restrict__ be,
    float outv[4][2][4],
    const int wm, const int wn, const int l15, const int lg, const int lane)
{
    f32x4 acc[4][2];
    gemm16<NKS1, XROW>(W1p, B1, xs, acc, wm, wn, l15, lg, lane);
    __syncthreads();
    store_h(h1, acc, wm, wn, l15, lg);
    __syncthreads();
    gemm16<4, 136>(W2p, B2, h1, acc, wm, wn, l15, lg, lane);
    store_h(h2, acc, wm, wn, l15, lg);
    __syncthreads();
    gemm16<4, 136>(W3p, B3, h2, acc, wm, wn, l15, lg, lane);
    float ps[2], pss[2];
#pragma unroll
    for (int nt = 0; nt < 2; nt++) {
        float s = 0.0f, ss = 0.0f;
#pragma unroll
        for (int mt = 0; mt < 4; mt++) {
#pragma unroll
            for (int r = 0; r < 4; r++) {
                const float v = acc[mt][nt][r];
                s += v; ss += v * v;
            }
        }
        s += __shfl_xor(s, 16); ss += __shfl_xor(ss, 16);
        s += __shfl_xor(s, 32); ss += __shfl_xor(ss, 32);
        ps[nt] = s; pss[nt] = ss;
    }
    if (lane < 16) {
#pragma unroll
        for (int nt = 0; nt < 2; nt++) {
            red[wm][wn][nt][l15][0] = ps[nt];
            red[wm][wn][nt][l15][1] = pss[nt];
        }
    }
    __syncthreads();
#pragma unroll
    for (int nt = 0; nt < 2; nt++) {
        const float S  = red[0][wn][nt][l15][0] + red[1][wn][nt][l15][0];
        const float SS = red[0][wn][nt][l15][1] + red[1][wn][nt][l15][1];
        const float mu  = S * (1.0f / 128.0f);
        const float var = SS * (1.0f / 128.0f) - mu * mu;
        const float inv = rsqrtf(var + 1e-5f);
#pragma unroll
    for (int mt = 0; mt < 4; mt++) {
            const int hid = wm * 64 + mt * 16 + lg * 4;
            const f32x4 gv  = *(const f32x4*)(g + hid);
            const f32x4 bev = *(const f32x4*)(be + hid);
#pragma unroll
            for (int r = 0; r < 4; r++)
                outv[mt][nt][r] = (acc[mt][nt][r] - mu) * inv * gv[r] + bev[r];
        }
    }
}

// ---------------- node encoder (K=30 padded to 32) ----------------
__device__ __forceinline__ float nfeat(int i, int k,
    const float* __restrict__ vel, const float* __restrict__ pos,
    const float* __restrict__ bounds, const int* __restrict__ ptype,
    const float* __restrict__ emb)
{
    if (k < 10) return vel[i * 10 + k];
    if (k < 14) {
        const int q = k - 10;
        float sub;
        if (q < 2) sub = pos[i * 2 + q] - bounds[q * 2 + 0];
        else       sub = bounds[(q - 2) * 2 + 1] - pos[i * 2 + (q - 2)];
        const float dv = sub * 20.0f;
        return fminf(fmaxf(dv, -1.0f), 1.0f);
    }
    if (k < 30) return emb[ptype[i] * 16 + (k - 14)];
    return 0.0f;
}

__global__ __launch_bounds__(256)
void k_node_enc_m(const float* __restrict__ vel, const float* __restrict__ pos,
                  const float* __restrict__ bounds, const int* __restrict__ ptype,
                  const float* __restrict__ emb,
                  const u16* __restrict__ W1p, const float* __restrict__ B1,
                  const u16* __restrict__ W2p, const float* __restrict__ B2,
                  const u16* __restrict__ W3p, const float* __restrict__ B3,
                  const float* __restrict__ g, const float* __restrict__ be,
                  float* __restrict__ nodes, u16* __restrict__ nodes_bf)
{
    __shared__ __align__(16) u16 lds[17408];
    __shared__ float red[2][2][2][16][2];
    const int tid = threadIdx.x;
    const int i0 = blockIdx.x * 64;
    for (int idx = tid; idx < 1024; idx += 256) {
        const int m = idx >> 4, kk = idx & 15;
        const int i = i0 + m;
        float f0 = 0.0f, f1 = 0.0f;
        if (i < NPART) {
            f0 = nfeat(i, kk * 2 + 0, vel, pos, bounds, ptype, emb);
            f1 = nfeat(i, kk * 2 + 1, vel, pos, bounds, ptype, emb);
        }
        *(u32*)(lds + m * 40 + kk * 2) = pack2(f0, f1);
    }
    __syncthreads();
    const int lane = tid & 63, wv = tid >> 6;
    const int wm = wv >> 1, wn = wv & 1, l15 = lane & 15, lg = lane >> 4;
    float outv[4][2][4];
    mlp_mfma<1, 40>(lds, lds, lds + 8704, red, W1p, B1, W2p, B2, W3p, B3, g, be,
                    outv, wm, wn, l15, lg, lane);
#pragma unroll
    for (int nt = 0; nt < 2; nt++) {
        const int i = i0 + wn * 32 + nt * 16 + l15;
        if (i < NPART) {
#pragma unroll
            for (int mt = 0; mt < 4; mt++) {
                const int hid = wm * 64 + mt * 16 + lg * 4;
                const float4 v = make_float4(outv[mt][nt][0], outv[mt][nt][1],
                                             outv[mt][nt][2], outv[mt][nt][3]);
                *(float4*)(nodes + (size_t)i * HD + hid) = v;
                *(uint2*)(nodes_bf + (size_t)i * HD + hid) =
                    make_uint2(pack2(v.x, v.y), pack2(v.z, v.w));
            }
        }
    }
}

// ---------------- edge encoder (K=3 padded to 32), sorted edge order ----------------
__global__ __launch_bounds__(256)
void k_edge_enc_m(const float* __restrict__ pos, const int* __restrict__ snd_s,
                  const int* __restrict__ rcv_s,
                  const u16* __restrict__ W1p, const float* __restrict__ B1,
                  const u16* __restrict__ W2p, const float* __restrict__ B2,
                  const u16* __restrict__ W3p, const float* __restrict__ B3,
                  const float* __restrict__ g, const float* __restrict__ be,
                  float* __restrict__ edges)
{
    __shared__ __align__(16) u16 lds[17408];
    __shared__ float red[2][2][2][16][2];
    const int tid = threadIdx.x;
    const int e0 = blockIdx.x * 64;
    for (int idx = tid; idx < 1024; idx += 256) {
        const int m = idx >> 4, kk = idx & 15;
        const int e = min(e0 + m, NEDGE - 1);
        u32 w = 0;
        if (kk < 2) {
            const int s = snd_s[e], r = rcv_s[e];
            const float dx = (pos[s * 2 + 0] - pos[r * 2 + 0]) * 20.0f;
            const float dy = (pos[s * 2 + 1] - pos[r * 2 + 1]) * 20.0f;
            if (kk == 0) w = pack2(dx, dy);
            else         w = pack2(sqrtf(dx * dx + dy * dy), 0.0f);
        }
        *(u32*)(lds + m * 40 + kk * 2) = w;
    }
    __syncthreads();
    const int lane = tid & 63, wv = tid >> 6;
    const int wm = wv >> 1, wn = wv & 1, l15 = lane & 15, lg = lane >> 4;
    float outv[4][2][4];
    mlp_mfma<1, 40>(lds, lds, lds + 8704, red, W1p, B1, W2p, B2, W3p, B3, g, be,
                    outv, wm, wn, l15, lg, lane);
#pragma unroll
    for (int nt = 0; nt < 2; nt++) {
        const int e = e0 + wn * 32 + nt * 16 + l15;
        if (e < NEDGE) {
#pragma unroll
            for (int mt = 0; mt < 4; mt++) {
                const int hid = wm * 64 + mt * 16 + lg * 4;
                *(float4*)(edges + (size_t)e * HD + hid) =
                    make_float4(outv[mt][nt][0], outv[mt][nt][1], outv[mt][nt][2], outv[mt][nt][3]);
            }
        }
    }
}

// ================= 8-wave (512-thr) pipelined edge layer =================
// wave wv: wm = wv>>1 in 0..3 (32 hid), wn = wv&1 (32 edge rows).
__device__ __forceinline__ void egemm_seg(const u16* __restrict__ Wp,
                                          const u16* __restrict__ x,
                                          f32x4 acc[2][2], const int ks0,
                                          const int wm, const int wn,
                                          const int l15, const int lg, const int lane)
{
    const u16* xr0 = x + (wn * 32 + l15) * 136 + lg * 8;
    const u16* xr1 = xr0 + 16 * 136;
#pragma unroll
    for (int ks = 0; ks < 4; ks++) {
        const short8 b0 = *(const short8*)(xr0 + ks * 32);
        const short8 b1 = *(const short8*)(xr1 + ks * 32);
#pragma unroll
        for (int mt = 0; mt < 2; mt++) {
            const short8 a = *(const short8*)(Wp + (((wm * 2 + mt) * 12 + ks0 + ks) * 64 + lane) * 8);
            acc[mt][0] = __builtin_amdgcn_mfma_f32_16x16x32_bf16(a, b0, acc[mt][0], 0, 0, 0);
            acc[mt][1] = __builtin_amdgcn_mfma_f32_16x16x32_bf16(a, b1, acc[mt][1], 0, 0, 0);
        }
    }
}

__device__ __forceinline__ void egemm_h(const u16* __restrict__ Wp,
                                        const float* __restrict__ Bias,
                                        const u16* __restrict__ x,
                                        f32x4 acc[2][2],
                                        const int wm, const int wn,
                                        const int l15, const int lg, const int lane)
{
#pragma unroll
    for (int mt = 0; mt < 2; mt++) {
        const f32x4 bv = *(const f32x4*)(Bias + wm * 32 + mt * 16 + lg * 4);
        acc[mt][0] = bv;
        acc[mt][1] = bv;
    }
    const u16* xr0 = x + (wn * 32 + l15) * 136 + lg * 8;
    const u16* xr1 = xr0 + 16 * 136;
#pragma unroll
    for (int ks = 0; ks < 4; ks++) {
        const short8 b0 = *(const short8*)(xr0 + ks * 32);
        const short8 b1 = *(const short8*)(xr1 + ks * 32);
#pragma unroll
        for (int mt = 0; mt < 2; mt++) {
            const short8 a = *(const short8*)(Wp + (((wm * 2 + mt) * 4 + ks) * 64 + lane) * 8);
            acc[mt][0] = __builtin_amdgcn_mfma_f32_16x16x32_bf16(a, b0, acc[mt][0], 0, 0, 0);
            acc[mt][1] = __builtin_amdgcn_mfma_f32_16x16x32_bf16(a, b1, acc[mt][1], 0, 0, 0);
        }
    }
}

__device__ __forceinline__ void estore_h(u16* __restrict__ h, const f32x4 acc[2][2],
                                         const int wm, const int wn, const int l15, const int lg)
{
#pragma unroll
    for (int nt = 0; nt < 2; nt++) {
        const int e = wn * 32 + nt * 16 + l15;
#pragma unroll
        for (int mt = 0; mt < 2; mt++) {
            const int hid = wm * 32 + mt * 16 + lg * 4;
            const f32x4 v = acc[mt][nt];
            const u32 lo = pack2(fmaxf(v[0], 0.0f), fmaxf(v[1], 0.0f));
            const u32 hi = pack2(fmaxf(v[2], 0.0f), fmaxf(v[3], 0.0f));
            *(uint2*)(h + e * 136 + hid) = make_uint2(lo, hi);
        }
    }
}

__global__ __launch_bounds__(512)
void k_edge_layer_m(const u16* __restrict__ nodes_bf, float* __restrict__ edges,
                    const int* __restrict__ snd_s, const int* __restrict__ rcv_s,
                    const u16* __restrict__ W1p, const float* __restrict__ B1,
                    const u16* __restrict__ W2p, const float* __restrict__ B2,
                    const u16* __restrict__ W3p, const float* __restrict__ B3,
                    const float* __restrict__ g, const float* __restrict__ be)
{
    __shared__ __align__(16) u16 sb0[64 * 136];
    __shared__ __align__(16) u16 sb1[64 * 136];
    __shared__ float red[4][2][2][16][2];
    const int tid = threadIdx.x;
    const int e0 = blockIdx.x * 64;
    const int lane = tid & 63, wv = tid >> 6;
    const int wm = wv >> 1, wn = wv & 1, l15 = lane & 15, lg = lane >> 4;

    // stage seg0 (own edge rows, f32 -> bf16) into sb0
#pragma unroll
    for (int t = 0; t < 2; t++) {
        const int idx = tid + t * 512;
        const int m = idx >> 4, q = idx & 15;
        const int e = min(e0 + m, NEDGE - 1);
        const float* src = edges + (size_t)e * HD + q * 8;
        const float4 a = *(const float4*)(src);
        const float4 b = *(const float4*)(src + 4);
        *(uint4*)(sb0 + m * 136 + q * 8) = make_uint4(pack2(a.x, a.y), pack2(a.z, a.w),
                                                      pack2(b.x, b.y), pack2(b.z, b.w));
    }
    // issue seg1 (sender rows, bf16) loads -> regs
    uint4 st[2];
#pragma unroll
    for (int t = 0; t < 2; t++) {
        const int idx = tid + t * 512;
        const int m = idx >> 4, q = idx & 15;
        const int e = min(e0 + m, NEDGE - 1);
        st[t] = *(const uint4*)(nodes_bf + (size_t)snd_s[e] * HD + q * 8);
    }
    __syncthreads();

    f32x4 acc[2][2];
#pragma unroll
    for (int mt = 0; mt < 2; mt++) {
        const f32x4 bv = *(const f32x4*)(B1 + wm * 32 + mt * 16 + lg * 4);
        acc[mt][0] = bv;
        acc[mt][1] = bv;
    }
    __builtin_amdgcn_s_setprio(1);
    egemm_seg(W1p, sb0, acc, 0, wm, wn, l15, lg, lane);
    __builtin_amdgcn_s_setprio(0);
    // write seg1 -> sb1, issue seg2 (receiver rows) loads
#pragma unroll
    for (int t = 0; t < 2; t++) {
        const int idx = tid + t * 512;
        const int m = idx >> 4, q = idx & 15;
        *(uint4*)(sb1 + m * 136 + q * 8) = st[t];
    }
#pragma unroll
    for (int t = 0; t < 2; t++) {
        const int idx = tid + t * 512;
        const int m = idx >> 4, q = idx & 15;
        const int e = min(e0 + m, NEDGE - 1);
        st[t] = *(const uint4*)(nodes_bf + (size_t)rcv_s[e] * HD + q * 8);
    }
    __syncthreads();

    __builtin_amdgcn_s_setprio(1);
    egemm_seg(W1p, sb1, acc, 4, wm, wn, l15, lg, lane);
    __builtin_amdgcn_s_setprio(0);
#pragma unroll
    for (int t = 0; t < 2; t++) {
        const int idx = tid + t * 512;
        const int m = idx >> 4, q = idx & 15;
        *(uint4*)(sb0 + m * 136 + q * 8) = st[t];
    }
    __syncthreads();

    __builtin_amdgcn_s_setprio(1);
    egemm_seg(W1p, sb0, acc, 8, wm, wn, l15, lg, lane);
    __builtin_amdgcn_s_setprio(0);
    estore_h(sb1, acc, wm, wn, l15, lg);   // sb1 free (last read before prev barrier)
    __syncthreads();

    __builtin_amdgcn_s_setprio(1);
    egemm_h(W2p, B2, sb1, acc, wm, wn, l15, lg, lane);
    __builtin_amdgcn_s_setprio(0);
    estore_h(sb0, acc, wm, wn, l15, lg);   // sb0 free
    __syncthreads();

    __builtin_amdgcn_s_setprio(1);
    egemm_h(W3p, B3, sb0, acc, wm, wn, l15, lg, lane);
    __builtin_amdgcn_s_setprio(0);

    // ---- layernorm ----
    float ps[2], pss[2];
#pragma unroll
    for (int nt = 0; nt < 2; nt++) {
        float s = 0.0f, ss = 0.0f;
#pragma unroll
        for (int mt = 0; mt < 2; mt++) {
#pragma unroll
            for (int r = 0; r < 4; r++) {
                const float v = acc[mt][nt][r];
                s += v; ss += v * v;
            }
        }
        s += __shfl_xor(s, 16); ss += __shfl_xor(ss, 16);
        s += __shfl_xor(s, 32); ss += __shfl_xor(ss, 32);
        ps[nt] = s; pss[nt] = ss;
    }
    if (lane < 16) {
#pragma unroll
        for (int nt = 0; nt < 2; nt++) {
            red[wm][wn][nt][l15][0] = ps[nt];
            red[wm][wn][nt][l15][1] = pss[nt];
        }
    }
    __syncthreads();
#pragma unroll
    for (int nt = 0; nt < 2; nt++) {
        const float S  = red[0][wn][nt][l15][0] + red[1][wn][nt][l15][0]
                       + red[2][wn][nt][l15][0] + red[3][wn][nt][l15][0];
        const float SS = red[0][wn][nt][l15][1] + red[1][wn][nt][l15][1]
                       + red[2][wn][nt][l15][1] + red[3][wn][nt][l15][1];
        const float mu  = S * (1.0f / 128.0f);
        const float var = SS * (1.0f / 128.0f) - mu * mu;
        const float inv = rsqrtf(var + 1e-5f);
        const int e = e0 + wn * 32 + nt * 16 + l15;
        if (e < NEDGE) {
            float* ep = edges + (size_t)e * HD;
#pragma unroll
            for (int mt = 0; mt < 2; mt++) {
                const int hid = wm * 32 + mt * 16 + lg * 4;
                const f32x4 gv  = *(const f32x4*)(g + hid);
                const f32x4 bev = *(const f32x4*)(be + hid);
                const float4 old = *(const float4*)(ep + hid);
                float4 nv;
                nv.x = old.x + (acc[mt][nt][0] - mu) * inv * gv[0] + bev[0];
                nv.y = old.y + (acc[mt][nt][1] - mu) * inv * gv[1] + bev[1];
                nv.z = old.z + (acc[mt][nt][2] - mu) * inv * gv[2] + bev[2];
                nv.w = old.w + (acc[mt][nt][3] - mu) * inv * gv[3] + bev[3];
                *(float4*)(ep + hid) = nv;
            }
        }
    }
}

// ---------------- per-layer node update (K=256) with fused CSR segment-sum ----------------
__global__ __launch_bounds__(256)
void k_node_layer_m(float* __restrict__ nodes, u16* __restrict__ nodes_bf,
                    const float* __restrict__ edges, const int* __restrict__ row_ptr,
                    const u16* __restrict__ W1p, const float* __restrict__ B1,
                    const u16* __restrict__ W2p, const float* __restrict__ B2,
                    const u16* __restrict__ W3p, const float* __restrict__ B3,
                    const float* __restrict__ g, const float* __restrict__ be)
{
    __shared__ __align__(16) u16 lds[17408];
    __shared__ float red[2][2][2][16][2];
    const int tid = threadIdx.x;
    const int i0 = blockIdx.x * 64;
    // seg A: node rows f32->bf16
    for (int idx = tid; idx < 1024; idx += 256) {
        const int m = idx >> 4, q = idx & 15;
        const int i = min(i0 + m, NPART - 1);
        const float* src = nodes + (size_t)i * HD + q * 8;
        const float4 a = *(const float4*)(src);
        const float4 b = *(const float4*)(src + 4);
        *(uint4*)(lds + m * 264 + q * 8) =
            make_uint4(pack2(a.x, a.y), pack2(a.z, a.w), pack2(b.x, b.y), pack2(b.z, b.w));
    }
    // seg B: CSR segment sum, all threads (32 threads x 4 floats per row)
    for (int idx = tid; idx < 2048; idx += 256) {
        const int m = idx >> 5, qq = idx & 31;
        const int i = min(i0 + m, NPART - 1);
        const int p0 = row_ptr[i], p1 = row_ptr[i + 1];
        float s0 = 0, s1 = 0, s2 = 0, s3 = 0;
        for (int p = p0; p < p1; p++) {
            const float4 a = *(const float4*)(edges + (size_t)p * HD + qq * 4);
            s0 += a.x; s1 += a.y; s2 += a.z; s3 += a.w;
        }
        *(uint2*)(lds + m * 264 + 128 + qq * 4) = make_uint2(pack2(s0, s1), pack2(s2, s3));
    }
    __syncthreads();
    const int lane = tid & 63, wv = tid >> 6;
    const int wm = wv >> 1, wn = wv & 1, l15 = lane & 15, lg = lane >> 4;
    float outv[4][2][4];
    mlp_mfma<8, 264>(lds, lds, lds + 8704, red, W1p, B1, W2p, B2, W3p, B3, g, be,
                     outv, wm, wn, l15, lg, lane);
#pragma unroll
    for (int nt = 0; nt < 2; nt++) {
        const int i = i0 + wn * 32 + nt * 16 + l15;
        if (i < NPART) {
            float* np = nodes + (size_t)i * HD;
#pragma unroll
            for (int mt = 0; mt < 4; mt++) {
                const int hid = wm * 64 + mt * 16 + lg * 4;
                const float4 old = *(const float4*)(np + hid);
                const float4 nv = make_float4(old.x + outv[mt][nt][0],
                                              old.y + outv[mt][nt][1],
                                              old.z + outv[mt][nt][2],
                                              old.w + outv[mt][nt][3]);
                *(float4*)(np + hid) = nv;
                *(uint2*)(nodes_bf + (size_t)i * HD + hid) =
                    make_uint2(pack2(nv.x, nv.y), pack2(nv.z, nv.w));
            }
        }
    }
}

// ---------------- fp32 gemv for decoder ----------------
template<int K, int S>
__device__ __forceinline__ void gemv(const float* __restrict__ in,
                                     const float* __restrict__ W,
                                     const float* __restrict__ B,
                                     float acc[8])
{
    const int j = threadIdx.x;
    const float bb = B[j];
#pragma unroll
    for (int m = 0; m < 8; m++) acc[m] = bb;
    constexpr int K4 = (K / 4) * 4;
    for (int k = 0; k < K4; k += 4) {
        const float w0 = W[(k + 0) * HD + j];
        const float w1 = W[(k + 1) * HD + j];
        const float w2 = W[(k + 2) * HD + j];
        const float w3 = W[(k + 3) * HD + j];
#pragma unroll
        for (int m = 0; m < 8; m++) {
            const float4 x = *(const float4*)(in + m * S + k);
            float a = acc[m];
            a = fmaf(x.x, w0, a);
            a = fmaf(x.y, w1, a);
            a = fmaf(x.z, w2, a);
            a = fmaf(x.w, w3, a);
            acc[m] = a;
        }
    }
#pragma unroll
    for (int k = K4; k < K; k++) {
        const float w = W[k * HD + j];
#pragma unroll
        for (int m = 0; m < 8; m++) acc[m] = fmaf(in[m * S + k], w, acc[m]);
    }
}

// ---------------- decoder + Euler integration (dual output dtype) ----------------
__global__ __launch_bounds__(128)
void k_decoder(const float* __restrict__ nodes,
               const float* W1, const float* B1, const float* W2, const float* B2,
               const float* W3, const float* B3,
               const float* __restrict__ vel, const float* __restrict__ pos,
               const float* __restrict__ tgt, const int* __restrict__ nonk,
               const unsigned short* __restrict__ braw, void* __restrict__ d_out)
{
    __shared__ __align__(16) float xs[8 * HD];
    __shared__ __align__(16) float h1[8 * HD];
    __shared__ __align__(16) float h2[8 * HD];
    const int j = threadIdx.x;
    const int i0 = blockIdx.x * 8;
    float acc[8];
#pragma unroll
    for (int m = 0; m < 8; m++) xs[m * HD + j] = nodes[(i0 + m) * HD + j];
    __syncthreads();
    gemv<HD, HD>(xs, W1, B1, acc);
#pragma unroll
    for (int m = 0; m < 8; m++) h1[m * HD + j] = fmaxf(acc[m], 0.0f);
    __syncthreads();
    gemv<HD, HD>(h1, W2, B2, acc);
#pragma unroll
    for (int m = 0; m < 8; m++) h2[m * HD + j] = fmaxf(acc[m], 0.0f);
    __syncthreads();
    if (j < 16) {
        const int m = j >> 1, d = j & 1, i = i0 + m;
        float a = B3[d];
        for (int k = 0; k < HD; k++) a = fmaf(h2[m * HD + k], W3[k * 2 + d], a);
        float pp = pos[i * 2 + d] + vel[i * 10 + 8 + d] + a;
        if (nonk[i] == 0) pp = tgt[i * 2 + d];
        if (detect_bf16(braw)) {
            bf16* o = (bf16*)d_out;
            o[i * 2 + d] = __float2bfloat16(a);
            o[2 * NPART + i * 2 + d] = __float2bfloat16(pp);
        } else {
            float* o = (float*)d_out;
            o[i * 2 + d] = a;
            o[2 * NPART + i * 2 + d] = pp;
        }
    }
}

extern "C" void kernel_launch(void* const* d_in, const int* in_sizes, int n_in,
                              void* d_out, int out_size, void* d_ws, size_t ws_size,
                              hipStream_t stream)
{
    const int* ptype = (const int*)d_in[4];
    const int* nonk  = (const int*)d_in[5];
    const int* snd   = (const int*)d_in[6];
    const int* rcv   = (const int*)d_in[7];
    const unsigned short* braw = (const unsigned short*)d_in[2];

    int fmap[NFLOAT_ARRAYS];
    {
        int c = 0;
        fmap[c++] = 0; fmap[c++] = 1; fmap[c++] = 2; fmap[c++] = 3; fmap[c++] = 8;
        for (int i = 9; i <= 46; i++) fmap[c++] = i;
    }
    ConvArgs ca;
    const float* fp[47];
    float* cw = (float*)d_ws;
    int off = 0;
    for (int i = 0; i < NFLOAT_ARRAYS; i++) {
        ca.src[i] = d_in[fmap[i]];
        ca.n[i]   = in_sizes[fmap[i]];
        ca.off[i] = off;
        fp[fmap[i]] = cw + off;
        off += in_sizes[fmap[i]];
    }
    // workspace: f32 states + bf16 node mirror + packed weights + sort scratch
    float* nodes = cw + ((off + 3) & ~3);
    float* edges = nodes + (size_t)NPART * HD;
    u16* nodes_bf = (u16*)(edges + (size_t)NEDGE * HD);
    u16* wpk = nodes_bf + (size_t)NPART * HD;

    // build pack table (order: ne x3, ee x3, ge x30, gn x30)
    PackArgs pa;
    int dst = 0, c = 0;
    int pk[NMAT];
    auto addm = [&](long srcoff, int K) {
        const int nk = (K + 31) / 32;
        pa.src_off[c] = (int)srcoff;
        pa.K[c] = K;
        pa.nks[c] = nk;
        pa.dst_off[c] = dst;
        pk[c] = dst;
        dst += nk * 4096;
        c++;
    };
    addm(fp[9]  - cw, 30);  addm(fp[11] - cw, 128); addm(fp[13] - cw, 128);
    addm(fp[17] - cw, 3);   addm(fp[19] - cw, 128); addm(fp[21] - cw, 128);
    for (int l = 0; l < NLAYER; l++) {
        addm(fp[25] - cw + (long)l * 384 * HD, 384);
        addm(fp[27] - cw + (long)l * HD * HD, 128);
        addm(fp[29] - cw + (long)l * HD * HD, 128);
    }
    for (int l = 0; l < NLAYER; l++) {
        addm(fp[33] - cw + (long)l * 256 * HD, 256);
        addm(fp[35] - cw + (long)l * HD * HD, 128);
        addm(fp[37] - cw + (long)l * HD * HD, 128);
    }

    int* ip = (int*)(wpk + ((dst + 7) & ~7));
    int* row_ptr = ip;            ip += NPART + 8;
    int* cursor  = ip;            ip += NPART;
    int* counts  = ip;            ip += NPART;
    int* snd_s   = ip;            ip += NEDGE;
    int* rcv_s   = ip;

    const int EBL = (NEDGE + 255) / 256;

    k_convert<<<dim3(64, NFLOAT_ARRAYS), 256, 0, stream>>>(ca, cw, braw);
    hipMemsetAsync(counts, 0, (size_t)NPART * sizeof(int), stream);
    k_hist<<<EBL, 256, 0, stream>>>(rcv, counts);
    k_scan<<<1, 1024, 0, stream>>>(counts, row_ptr, cursor);
    k_scatter<<<EBL, 256, 0, stream>>>(snd, rcv, cursor, snd_s, rcv_s);
    k_pack<<<dim3(192, NMAT), 256, 0, stream>>>(cw, wpk, pa);

    const int NB = (NPART + 63) / 64;   // 469
    const int EB = (NEDGE + 63) / 64;   // 4688

    k_node_enc_m<<<NB, 256, 0, stream>>>(fp[0], fp[1], fp[2], ptype, fp[8],
        wpk + pk[0], fp[10], wpk + pk[1], fp[12], wpk + pk[2], fp[14],
        fp[15], fp[16], nodes, nodes_bf);
    k_edge_enc_m<<<EB, 256, 0, stream>>>(fp[1], snd_s, rcv_s,
        wpk + pk[3], fp[18], wpk + pk[4], fp[20], wpk + pk[5], fp[22],
        fp[23], fp[24], edges);

    for (int l = 0; l < NLAYER; l++) {
        k_edge_layer_m<<<EB, 512, 0, stream>>>(nodes_bf, edges, snd_s, rcv_s,
            wpk + pk[6 + 3 * l],  fp[26] + (size_t)l * HD,
            wpk + pk[7 + 3 * l],  fp[28] + (size_t)l * HD,
            wpk + pk[8 + 3 * l],  fp[30] + (size_t)l * HD,
            fp[31] + (size_t)l * HD, fp[32] + (size_t)l * HD);
        k_node_layer_m<<<NB, 256, 0, stream>>>(nodes, nodes_bf, edges, row_ptr,
            wpk + pk[36 + 3 * l], fp[34] + (size_t)l * HD,
            wpk + pk[37 + 3 * l], fp[36] + (size_t)l * HD,
            wpk + pk[38 + 3 * l], fp[38] + (size_t)l * HD,
            fp[39] + (size_t)l * HD, fp[40] + (size_t)l * HD);
    }

    k_decoder<<<NPART / 8, 128, 0, stream>>>(nodes,
        fp[41], fp[42], fp[43], fp[44], fp[45], fp[46],
        fp[0], fp[1], fp[3], nonk, braw, d_out);
}

// Round 4
// 2546.658 us; speedup vs baseline: 5.7235x; 1.0187x over previous
//
#include <hip/hip_runtime.h>
#include <hip/hip_bf16.h>

typedef __hip_bfloat16 bf16;
typedef unsigned short u16;
typedef unsigned int u32;
typedef __attribute__((ext_vector_type(8))) short short8;
typedef __attribute__((ext_vector_type(4))) float f32x4;

#define NPART 30000
#define NEDGE 300000
#define HD 128
#define NLAYER 10
#define NFLOAT_ARRAYS 43
#define NMAT 66

// ---------------- dtype detect ----------------
__device__ __forceinline__ bool detect_bf16(const unsigned short* braw) {
    return braw[1] == 0x3F80u;
}

// ---------------- fp32<->bf16 helpers (RNE) ----------------
__device__ __forceinline__ u16 f2b(float f) {
    u32 u = __float_as_uint(f);
    u += 0x7FFFu + ((u >> 16) & 1u);
    return (u16)(u >> 16);
}
__device__ __forceinline__ u32 pack2(float a, float b) {
    return (u32)f2b(a) | ((u32)f2b(b) << 16);
}

// ---------------- convert all float arrays to canonical fp32 ----------------
struct ConvArgs {
    const void* src[NFLOAT_ARRAYS];
    int n[NFLOAT_ARRAYS];
    int off[NFLOAT_ARRAYS];
};

__global__ __launch_bounds__(256)
void k_convert(ConvArgs a, float* __restrict__ dst, const unsigned short* __restrict__ braw)
{
    const bool isb = detect_bf16(braw);
    const int aid = blockIdx.y;
    const int n = a.n[aid];
    float* o = dst + a.off[aid];
    const int stride = gridDim.x * 256;
    int i = blockIdx.x * 256 + threadIdx.x;
    if (isb) {
        const unsigned short* s = (const unsigned short*)a.src[aid];
        for (; i < n; i += stride) {
            const unsigned int u = ((unsigned int)s[i]) << 16;
            o[i] = __uint_as_float(u);
        }
    } else {
        const float* s = (const float*)a.src[aid];
        for (; i < n; i += stride) o[i] = s[i];
    }
}

// ---------------- counting sort of edges by receiver ----------------
__global__ __launch_bounds__(256)
void k_hist(const int* __restrict__ rcv, int* __restrict__ counts)
{
    const int e = blockIdx.x * 256 + threadIdx.x;
    if (e < NEDGE) atomicAdd(&counts[rcv[e]], 1);
}

__global__ __launch_bounds__(1024)
void k_scan(const int* __restrict__ counts, int* __restrict__ row_ptr, int* __restrict__ cursor)
{
    __shared__ int part[1024];
    const int t = threadIdx.x;
    const int base = t * 32;
    int local[32];
    int s = 0;
#pragma unroll
    for (int k = 0; k < 32; k++) {
        const int idx = base + k;
        const int v = (idx < NPART) ? counts[idx] : 0;
        local[k] = s;
        s += v;
    }
    part[t] = s;
    __syncthreads();
    for (int off = 1; off < 1024; off <<= 1) {
        const int v = (t >= off) ? part[t - off] : 0;
        __syncthreads();
        part[t] += v;
        __syncthreads();
    }
    const int excl = (t == 0) ? 0 : part[t - 1];
#pragma unroll
    for (int k = 0; k < 32; k++) {
        const int idx = base + k;
        if (idx < NPART) {
            const int rp = excl + local[k];
            row_ptr[idx] = rp;
            cursor[idx] = rp;
        }
    }
    if (t == 0) row_ptr[NPART] = NEDGE;
}

__global__ __launch_bounds__(256)
void k_scatter(const int* __restrict__ snd, const int* __restrict__ rcv,
               int* __restrict__ cursor, int* __restrict__ snd_s, int* __restrict__ rcv_s)
{
    const int e = blockIdx.x * 256 + threadIdx.x;
    if (e < NEDGE) {
        const int r = rcv[e];
        const int p = atomicAdd(&cursor[r], 1);
        snd_s[p] = snd[e];
        rcv_s[p] = r;
    }
}

// ---------------- weight pre-pack: f32 [K][128] -> bf16 fragment-linear ----------------
struct PackArgs {
    int src_off[NMAT];
    int dst_off[NMAT];
    int K[NMAT];
    int nks[NMAT];
};

__global__ __launch_bounds__(256)
void k_pack(const float* __restrict__ cw, u16* __restrict__ wpk, PackArgs pa)
{
    const int mid = blockIdx.y;
    const int nks = pa.nks[mid];
    const int total = nks * 4096;
    const int d = blockIdx.x * 256 + threadIdx.x;
    if (d >= total) return;
    const int j = d & 7, l = (d >> 3) & 63, t = d >> 9;
    const int ks = t % nks, mt = t / nks;
    const int hid = mt * 16 + (l & 15);
    const int k = ks * 32 + (l >> 4) * 8 + j;
    const float v = (k < pa.K[mid]) ? cw[pa.src_off[mid] + k * HD + hid] : 0.0f;
    wpk[pa.dst_off[mid] + d] = f2b(v);
}

// ================= 4-wave (256-thr) MFMA MLP: encoders + node layer =================
template<int NKS, int XROW>
__device__ __forceinline__ void gemm16(const u16* __restrict__ Wp,
                                       const float* __restrict__ Bias,
                                       const u16* __restrict__ x,
                                       f32x4 acc[4][2],
                                       const int wm, const int wn,
                                       const int l15, const int lg, const int lane)
{
#pragma unroll
    for (int mt = 0; mt < 4; mt++) {
        const f32x4 bv = *(const f32x4*)(Bias + wm * 64 + mt * 16 + lg * 4);
        acc[mt][0] = bv;
        acc[mt][1] = bv;
    }
    const u16* xr0 = x + (wn * 32 + l15) * XROW + lg * 8;
    const u16* xr1 = xr0 + 16 * XROW;
    const u16* wp = Wp + (wm * 4 * NKS) * 512 + lane * 8;
#pragma unroll
    for (int ks = 0; ks < NKS; ks++) {
        const short8 b0 = *(const short8*)(xr0 + ks * 32);
        const short8 b1 = *(const short8*)(xr1 + ks * 32);
#pragma unroll
        for (int mt = 0; mt < 4; mt++) {
            const short8 a = *(const short8*)(wp + (mt * NKS + ks) * 512);
            acc[mt][0] = __builtin_amdgcn_mfma_f32_16x16x32_bf16(a, b0, acc[mt][0], 0, 0, 0);
            acc[mt][1] = __builtin_amdgcn_mfma_f32_16x16x32_bf16(a, b1, acc[mt][1], 0, 0, 0);
        }
    }
}

__device__ __forceinline__ void store_h(u16* __restrict__ h, const f32x4 acc[4][2],
                                        const int wm, const int wn, const int l15, const int lg)
{
#pragma unroll
    for (int nt = 0; nt < 2; nt++) {
        const int e = wn * 32 + nt * 16 + l15;
#pragma unroll
        for (int mt = 0; mt < 4; mt++) {
            const int hid = wm * 64 + mt * 16 + lg * 4;
            const f32x4 v = acc[mt][nt];
            const u32 lo = pack2(fmaxf(v[0], 0.0f), fmaxf(v[1], 0.0f));
            const u32 hi = pack2(fmaxf(v[2], 0.0f), fmaxf(v[3], 0.0f));
            *(uint2*)(h + e * 136 + hid) = make_uint2(lo, hi);
        }
    }
}

template<int NKS1, int XROW>
__device__ __forceinline__ void mlp_mfma(const u16* __restrict__ xs,
    u16* __restrict__ h1, u16* __restrict__ h2,
    float (*red)[2][2][16][2],
    const u16* __restrict__ W1p, const float* __restrict__ B1,
    const u16* __restrict__ W2p, const float* __restrict__ B2,
    const u16* __restrict__ W3p, const float* __restrict__ B3,
    const float* __restrict__ g, const float* __restrict__ be,
    float outv[4][2][4],
    const int wm, const int wn, const int l15, const int lg, const int lane)
{
    f32x4 acc[4][2];
    gemm16<NKS1, XROW>(W1p, B1, xs, acc, wm, wn, l15, lg, lane);
    __syncthreads();
    store_h(h1, acc, wm, wn, l15, lg);
    __syncthreads();
    gemm16<4, 136>(W2p, B2, h1, acc, wm, wn, l15, lg, lane);
    store_h(h2, acc, wm, wn, l15, lg);
    __syncthreads();
    gemm16<4, 136>(W3p, B3, h2, acc, wm, wn, l15, lg, lane);
    float ps[2], pss[2];
#pragma unroll
    for (int nt = 0; nt < 2; nt++) {
        float s = 0.0f, ss = 0.0f;
#pragma unroll
        for (int mt = 0; mt < 4; mt++) {
#pragma unroll
            for (int r = 0; r < 4; r++) {
                const float v = acc[mt][nt][r];
                s += v; ss += v * v;
            }
        }
        s += __shfl_xor(s, 16); ss += __shfl_xor(ss, 16);
        s += __shfl_xor(s, 32); ss += __shfl_xor(ss, 32);
        ps[nt] = s; pss[nt] = ss;
    }
    if (lane < 16) {
#pragma unroll
        for (int nt = 0; nt < 2; nt++) {
            red[wm][wn][nt][l15][0] = ps[nt];
            red[wm][wn][nt][l15][1] = pss[nt];
        }
    }
    __syncthreads();
#pragma unroll
    for (int nt = 0; nt < 2; nt++) {
        const float S  = red[0][wn][nt][l15][0] + red[1][wn][nt][l15][0];
        const float SS = red[0][wn][nt][l15][1] + red[1][wn][nt][l15][1];
        const float mu  = S * (1.0f / 128.0f);
        const float var = SS * (1.0f / 128.0f) - mu * mu;
        const float inv = rsqrtf(var + 1e-5f);
#pragma unroll
        for (int mt = 0; mt < 4; mt++) {
            const int hid = wm * 64 + mt * 16 + lg * 4;
            const f32x4 gv  = *(const f32x4*)(g + hid);
            const f32x4 bev = *(const f32x4*)(be + hid);
#pragma unroll
            for (int r = 0; r < 4; r++)
                outv[mt][nt][r] = (acc[mt][nt][r] - mu) * inv * gv[r] + bev[r];
        }
    }
}

// ---------------- node encoder (K=30 padded to 32) ----------------
__device__ __forceinline__ float nfeat(int i, int k,
    const float* __restrict__ vel, const float* __restrict__ pos,
    const float* __restrict__ bounds, const int* __restrict__ ptype,
    const float* __restrict__ emb)
{
    if (k < 10) return vel[i * 10 + k];
    if (k < 14) {
        const int q = k - 10;
        float sub;
        if (q < 2) sub = pos[i * 2 + q] - bounds[q * 2 + 0];
        else       sub = bounds[(q - 2) * 2 + 1] - pos[i * 2 + (q - 2)];
        const float dv = sub * 20.0f;
        return fminf(fmaxf(dv, -1.0f), 1.0f);
    }
    if (k < 30) return emb[ptype[i] * 16 + (k - 14)];
    return 0.0f;
}

__global__ __launch_bounds__(256)
void k_node_enc_m(const float* __restrict__ vel, const float* __restrict__ pos,
                  const float* __restrict__ bounds, const int* __restrict__ ptype,
                  const float* __restrict__ emb,
                  const u16* __restrict__ W1p, const float* __restrict__ B1,
                  const u16* __restrict__ W2p, const float* __restrict__ B2,
                  const u16* __restrict__ W3p, const float* __restrict__ B3,
                  const float* __restrict__ g, const float* __restrict__ be,
                  float* __restrict__ nodes, u16* __restrict__ nodes_bf)
{
    __shared__ __align__(16) u16 lds[17408];
    __shared__ float red[2][2][2][16][2];
    const int tid = threadIdx.x;
    const int i0 = blockIdx.x * 64;
    for (int idx = tid; idx < 1024; idx += 256) {
        const int m = idx >> 4, kk = idx & 15;
        const int i = i0 + m;
        float f0 = 0.0f, f1 = 0.0f;
        if (i < NPART) {
            f0 = nfeat(i, kk * 2 + 0, vel, pos, bounds, ptype, emb);
            f1 = nfeat(i, kk * 2 + 1, vel, pos, bounds, ptype, emb);
        }
        *(u32*)(lds + m * 40 + kk * 2) = pack2(f0, f1);
    }
    __syncthreads();
    const int lane = tid & 63, wv = tid >> 6;
    const int wm = wv >> 1, wn = wv & 1, l15 = lane & 15, lg = lane >> 4;
    float outv[4][2][4];
    mlp_mfma<1, 40>(lds, lds, lds + 8704, red, W1p, B1, W2p, B2, W3p, B3, g, be,
                    outv, wm, wn, l15, lg, lane);
#pragma unroll
    for (int nt = 0; nt < 2; nt++) {
        const int i = i0 + wn * 32 + nt * 16 + l15;
        if (i < NPART) {
#pragma unroll
            for (int mt = 0; mt < 4; mt++) {
                const int hid = wm * 64 + mt * 16 + lg * 4;
                const float4 v = make_float4(outv[mt][nt][0], outv[mt][nt][1],
                                             outv[mt][nt][2], outv[mt][nt][3]);
                *(float4*)(nodes + (size_t)i * HD + hid) = v;
                *(uint2*)(nodes_bf + (size_t)i * HD + hid) =
                    make_uint2(pack2(v.x, v.y), pack2(v.z, v.w));
            }
        }
    }
}

// ---------------- edge encoder (K=3 padded to 32), sorted edge order ----------------
__global__ __launch_bounds__(256)
void k_edge_enc_m(const float* __restrict__ pos, const int* __restrict__ snd_s,
                  const int* __restrict__ rcv_s,
                  const u16* __restrict__ W1p, const float* __restrict__ B1,
                  const u16* __restrict__ W2p, const float* __restrict__ B2,
                  const u16* __restrict__ W3p, const float* __restrict__ B3,
                  const float* __restrict__ g, const float* __restrict__ be,
                  float* __restrict__ edges)
{
    __shared__ __align__(16) u16 lds[17408];
    __shared__ float red[2][2][2][16][2];
    const int tid = threadIdx.x;
    const int e0 = blockIdx.x * 64;
    for (int idx = tid; idx < 1024; idx += 256) {
        const int m = idx >> 4, kk = idx & 15;
        const int e = min(e0 + m, NEDGE - 1);
        u32 w = 0;
        if (kk < 2) {
            const int s = snd_s[e], r = rcv_s[e];
            const float dx = (pos[s * 2 + 0] - pos[r * 2 + 0]) * 20.0f;
            const float dy = (pos[s * 2 + 1] - pos[r * 2 + 1]) * 20.0f;
            if (kk == 0) w = pack2(dx, dy);
            else         w = pack2(sqrtf(dx * dx + dy * dy), 0.0f);
        }
        *(u32*)(lds + m * 40 + kk * 2) = w;
    }
    __syncthreads();
    const int lane = tid & 63, wv = tid >> 6;
    const int wm = wv >> 1, wn = wv & 1, l15 = lane & 15, lg = lane >> 4;
    float outv[4][2][4];
    mlp_mfma<1, 40>(lds, lds, lds + 8704, red, W1p, B1, W2p, B2, W3p, B3, g, be,
                    outv, wm, wn, l15, lg, lane);
#pragma unroll
    for (int nt = 0; nt < 2; nt++) {
        const int e = e0 + wn * 32 + nt * 16 + l15;
        if (e < NEDGE) {
#pragma unroll
            for (int mt = 0; mt < 4; mt++) {
                const int hid = wm * 64 + mt * 16 + lg * 4;
                *(float4*)(edges + (size_t)e * HD + hid) =
                    make_float4(outv[mt][nt][0], outv[mt][nt][1], outv[mt][nt][2], outv[mt][nt][3]);
            }
        }
    }
}

// ================= 8-wave (512-thr) pipelined edge layer + fused agg =================
__device__ __forceinline__ void egemm_seg(const u16* __restrict__ Wp,
                                          const u16* __restrict__ x,
                                          f32x4 acc[2][2], const int ks0,
                                          const int wm, const int wn,
                                          const int l15, const int lg, const int lane)
{
    const u16* xr0 = x + (wn * 32 + l15) * 136 + lg * 8;
    const u16* xr1 = xr0 + 16 * 136;
#pragma unroll
    for (int ks = 0; ks < 4; ks++) {
        const short8 b0 = *(const short8*)(xr0 + ks * 32);
        const short8 b1 = *(const short8*)(xr1 + ks * 32);
#pragma unroll
        for (int mt = 0; mt < 2; mt++) {
            const short8 a = *(const short8*)(Wp + (((wm * 2 + mt) * 12 + ks0 + ks) * 64 + lane) * 8);
            acc[mt][0] = __builtin_amdgcn_mfma_f32_16x16x32_bf16(a, b0, acc[mt][0], 0, 0, 0);
            acc[mt][1] = __builtin_amdgcn_mfma_f32_16x16x32_bf16(a, b1, acc[mt][1], 0, 0, 0);
        }
    }
}

__device__ __forceinline__ void egemm_h(const u16* __restrict__ Wp,
                                        const float* __restrict__ Bias,
                                        const u16* __restrict__ x,
                                        f32x4 acc[2][2],
                                        const int wm, const int wn,
                                        const int l15, const int lg, const int lane)
{
#pragma unroll
    for (int mt = 0; mt < 2; mt++) {
        const f32x4 bv = *(const f32x4*)(Bias + wm * 32 + mt * 16 + lg * 4);
        acc[mt][0] = bv;
        acc[mt][1] = bv;
    }
    const u16* xr0 = x + (wn * 32 + l15) * 136 + lg * 8;
    const u16* xr1 = xr0 + 16 * 136;
#pragma unroll
    for (int ks = 0; ks < 4; ks++) {
        const short8 b0 = *(const short8*)(xr0 + ks * 32);
        const short8 b1 = *(const short8*)(xr1 + ks * 32);
#pragma unroll
        for (int mt = 0; mt < 2; mt++) {
            const short8 a = *(const short8*)(Wp + (((wm * 2 + mt) * 4 + ks) * 64 + lane) * 8);
            acc[mt][0] = __builtin_amdgcn_mfma_f32_16x16x32_bf16(a, b0, acc[mt][0], 0, 0, 0);
            acc[mt][1] = __builtin_amdgcn_mfma_f32_16x16x32_bf16(a, b1, acc[mt][1], 0, 0, 0);
        }
    }
}

__device__ __forceinline__ void estore_h(u16* __restrict__ h, const f32x4 acc[2][2],
                                         const int wm, const int wn, const int l15, const int lg)
{
#pragma unroll
    for (int nt = 0; nt < 2; nt++) {
        const int e = wn * 32 + nt * 16 + l15;
#pragma unroll
        for (int mt = 0; mt < 2; mt++) {
            const int hid = wm * 32 + mt * 16 + lg * 4;
            const f32x4 v = acc[mt][nt];
            const u32 lo = pack2(fmaxf(v[0], 0.0f), fmaxf(v[1], 0.0f));
            const u32 hi = pack2(fmaxf(v[2], 0.0f), fmaxf(v[3], 0.0f));
            *(uint2*)(h + e * 136 + hid) = make_uint2(lo, hi);
        }
    }
}

__global__ __launch_bounds__(512)
void k_edge_layer_m(const u16* __restrict__ nodes_bf, float* __restrict__ edges,
                    float* __restrict__ agg,
                    const int* __restrict__ snd_s, const int* __restrict__ rcv_s,
                    const u16* __restrict__ W1p, const float* __restrict__ B1,
                    const u16* __restrict__ W2p, const float* __restrict__ B2,
                    const u16* __restrict__ W3p, const float* __restrict__ B3,
                    const float* __restrict__ g, const float* __restrict__ be)
{
    __shared__ __align__(16) u16 sb[2 * 8704];    // two bf16 bufs; epilogue f32 view
    __shared__ float red[4][2][2][16][2];
    __shared__ int rblk[66];                      // [0..63]=receivers, 64=prev, 65=next
    u16* buf0 = sb;
    u16* buf1 = sb + 8704;
    float* fout = (float*)sb;                     // 64 rows x stride 132 f32 = 33792B

    const int tid = threadIdx.x;
    const int e0 = blockIdx.x * 64;
    const int lane = tid & 63, wv = tid >> 6;
    const int wm = wv >> 1, wn = wv & 1, l15 = lane & 15, lg = lane >> 4;

    // receiver block info
    if (tid < 64)       rblk[tid] = (e0 + tid < NEDGE) ? rcv_s[e0 + tid] : -1;
    else if (tid == 64) rblk[64] = (e0 > 0) ? rcv_s[e0 - 1] : -2;
    else if (tid == 65) rblk[65] = (e0 + 64 < NEDGE) ? rcv_s[e0 + 64] : -2;

    // stage seg0 (own edge rows, f32 -> bf16) into buf0; keep f32 old in regs
    float4 olda[2], oldb[2];
#pragma unroll
    for (int t = 0; t < 2; t++) {
        const int idx = tid + t * 512;
        const int m = idx >> 4, q = idx & 15;
        const int e = min(e0 + m, NEDGE - 1);
        const float* src = edges + (size_t)e * HD + q * 8;
        olda[t] = *(const float4*)(src);
        oldb[t] = *(const float4*)(src + 4);
        *(uint4*)(buf0 + m * 136 + q * 8) =
            make_uint4(pack2(olda[t].x, olda[t].y), pack2(olda[t].z, olda[t].w),
                       pack2(oldb[t].x, oldb[t].y), pack2(oldb[t].z, oldb[t].w));
    }
    // issue seg1 (sender rows, bf16) loads -> regs
    uint4 st[2];
#pragma unroll
    for (int t = 0; t < 2; t++) {
        const int idx = tid + t * 512;
        const int m = idx >> 4, q = idx & 15;
        const int e = min(e0 + m, NEDGE - 1);
        st[t] = *(const uint4*)(nodes_bf + (size_t)snd_s[e] * HD + q * 8);
    }
    __syncthreads();

    f32x4 acc[2][2];
#pragma unroll
    for (int mt = 0; mt < 2; mt++) {
        const f32x4 bv = *(const f32x4*)(B1 + wm * 32 + mt * 16 + lg * 4);
        acc[mt][0] = bv;
        acc[mt][1] = bv;
    }
    __builtin_amdgcn_s_setprio(1);
    egemm_seg(W1p, buf0, acc, 0, wm, wn, l15, lg, lane);
    __builtin_amdgcn_s_setprio(0);
    // write seg1 -> buf1, issue seg2 (receiver rows) loads
#pragma unroll
    for (int t = 0; t < 2; t++) {
        const int idx = tid + t * 512;
        const int m = idx >> 4, q = idx & 15;
        *(uint4*)(buf1 + m * 136 + q * 8) = st[t];
    }
#pragma unroll
    for (int t = 0; t < 2; t++) {
        const int idx = tid + t * 512;
        const int m = idx >> 4, q = idx & 15;
        const int e = min(e0 + m, NEDGE - 1);
        st[t] = *(const uint4*)(nodes_bf + (size_t)rcv_s[e] * HD + q * 8);
    }
    __syncthreads();

    __builtin_amdgcn_s_setprio(1);
    egemm_seg(W1p, buf1, acc, 4, wm, wn, l15, lg, lane);
    __builtin_amdgcn_s_setprio(0);
#pragma unroll
    for (int t = 0; t < 2; t++) {
        const int idx = tid + t * 512;
        const int m = idx >> 4, q = idx & 15;
        *(uint4*)(buf0 + m * 136 + q * 8) = st[t];
    }
    __syncthreads();

    __builtin_amdgcn_s_setprio(1);
    egemm_seg(W1p, buf0, acc, 8, wm, wn, l15, lg, lane);
    __builtin_amdgcn_s_setprio(0);
    estore_h(buf1, acc, wm, wn, l15, lg);
    __syncthreads();

    __builtin_amdgcn_s_setprio(1);
    egemm_h(W2p, B2, buf1, acc, wm, wn, l15, lg, lane);
    __builtin_amdgcn_s_setprio(0);
    estore_h(buf0, acc, wm, wn, l15, lg);
    __syncthreads();

    __builtin_amdgcn_s_setprio(1);
    egemm_h(W3p, B3, buf0, acc, wm, wn, l15, lg, lane);
    __builtin_amdgcn_s_setprio(0);

    // ---- layernorm reduction ----
    float ps[2], pss[2];
#pragma unroll
    for (int nt = 0; nt < 2; nt++) {
        float s = 0.0f, ss = 0.0f;
#pragma unroll
        for (int mt = 0; mt < 2; mt++) {
#pragma unroll
            for (int r = 0; r < 4; r++) {
                const float v = acc[mt][nt][r];
                s += v; ss += v * v;
            }
        }
        s += __shfl_xor(s, 16); ss += __shfl_xor(ss, 16);
        s += __shfl_xor(s, 32); ss += __shfl_xor(ss, 32);
        ps[nt] = s; pss[nt] = ss;
    }
    if (lane < 16) {
#pragma unroll
        for (int nt = 0; nt < 2; nt++) {
            red[wm][wn][nt][l15][0] = ps[nt];
            red[wm][wn][nt][l15][1] = pss[nt];
        }
    }
    __syncthreads();   // also: all waves past egemm_h3 -> safe to overwrite sb as fout

    // ---- LN apply -> fout (f32, stride 132) ----
#pragma unroll
    for (int nt = 0; nt < 2; nt++) {
        const float S  = red[0][wn][nt][l15][0] + red[1][wn][nt][l15][0]
                       + red[2][wn][nt][l15][0] + red[3][wn][nt][l15][0];
        const float SS = red[0][wn][nt][l15][1] + red[1][wn][nt][l15][1]
                       + red[2][wn][nt][l15][1] + red[3][wn][nt][l15][1];
        const float mu  = S * (1.0f / 128.0f);
        const float var = SS * (1.0f / 128.0f) - mu * mu;
        const float inv = rsqrtf(var + 1e-5f);
        const int row = wn * 32 + nt * 16 + l15;
#pragma unroll
        for (int mt = 0; mt < 2; mt++) {
            const int hid = wm * 32 + mt * 16 + lg * 4;
            const f32x4 gv  = *(const f32x4*)(g + hid);
            const f32x4 bev = *(const f32x4*)(be + hid);
            f32x4 o;
#pragma unroll
            for (int r = 0; r < 4; r++)
                o[r] = (acc[mt][nt][r] - mu) * inv * gv[r] + bev[r];
            *(f32x4*)(fout + row * 132 + hid) = o;
        }
    }
    __syncthreads();

    // ---- writer: new = old + ln; coalesced full-row global write; new -> fout ----
#pragma unroll
    for (int t = 0; t < 2; t++) {
        const int idx = tid + t * 512;
        const int m = idx >> 4, q = idx & 15;
        float4 lo = *(const float4*)(fout + m * 132 + q * 8);
        float4 hi = *(const float4*)(fout + m * 132 + q * 8 + 4);
        lo.x += olda[t].x; lo.y += olda[t].y; lo.z += olda[t].z; lo.w += olda[t].w;
        hi.x += oldb[t].x; hi.y += oldb[t].y; hi.z += oldb[t].z; hi.w += oldb[t].w;
        *(float4*)(fout + m * 132 + q * 8) = lo;
        *(float4*)(fout + m * 132 + q * 8 + 4) = hi;
        if (e0 + m < NEDGE) {
            float* ep = edges + (size_t)(e0 + m) * HD + q * 8;
            *(float4*)(ep) = lo;
            *(float4*)(ep + 4) = hi;
        }
    }
    __syncthreads();

    // ---- fused aggregation: per-receiver run sums from fout -> agg ----
    const int c = tid & 31;          // float4 chunk 0..31
    for (int ms = (tid >> 5); ms < 64; ms += 16) {
        const int rs = rblk[ms];
        if (rs < 0) continue;
        if (ms > 0 && rblk[ms - 1] == rs) continue;   // not a run start
        int me = ms + 1;
        while (me < 64 && rblk[me] == rs) me++;
        float4 s = make_float4(0.0f, 0.0f, 0.0f, 0.0f);
        for (int m = ms; m < me; m++) {
            const float4 v = *(const float4*)(fout + m * 132 + c * 4);
            s.x += v.x; s.y += v.y; s.z += v.z; s.w += v.w;
        }
        float* ap = agg + (size_t)rs * HD + c * 4;
        const bool bnd = (ms == 0 && rblk[64] == rs) || (me == 64 && rblk[65] == rs);
        if (bnd) {
            atomicAdd(ap + 0, s.x); atomicAdd(ap + 1, s.y);
            atomicAdd(ap + 2, s.z); atomicAdd(ap + 3, s.w);
        } else {
            *(float4*)ap = s;
        }
    }
}

// ---------------- per-layer node update (K=256), reads agg directly ----------------
__global__ __launch_bounds__(256)
void k_node_layer_m(float* __restrict__ nodes, u16* __restrict__ nodes_bf,
                    const float* __restrict__ agg,
                    const u16* __restrict__ W1p, const float* __restrict__ B1,
                    const u16* __restrict__ W2p, const float* __restrict__ B2,
                    const u16* __restrict__ W3p, const float* __restrict__ B3,
                    const float* __restrict__ g, const float* __restrict__ be)
{
    __shared__ __align__(16) u16 lds[17408];
    __shared__ float red[2][2][2][16][2];
    const int tid = threadIdx.x;
    const int i0 = blockIdx.x * 64;
    for (int idx = tid; idx < 1024; idx += 256) {
        const int m = idx >> 4, q = idx & 15;
        const int i = min(i0 + m, NPART - 1);
        const float* src = nodes + (size_t)i * HD + q * 8;
        const float4 a = *(const float4*)(src);
        const float4 b = *(const float4*)(src + 4);
        *(uint4*)(lds + m * 264 + q * 8) =
            make_uint4(pack2(a.x, a.y), pack2(a.z, a.w), pack2(b.x, b.y), pack2(b.z, b.w));
    }
    for (int idx = tid; idx < 1024; idx += 256) {
        const int m = idx >> 4, q = idx & 15;
        const int i = min(i0 + m, NPART - 1);
        const float* src = agg + (size_t)i * HD + q * 8;
        const float4 a = *(const float4*)(src);
        const float4 b = *(const float4*)(src + 4);
        *(uint4*)(lds + m * 264 + 128 + q * 8) =
            make_uint4(pack2(a.x, a.y), pack2(a.z, a.w), pack2(b.x, b.y), pack2(b.z, b.w));
    }
    __syncthreads();
    const int lane = tid & 63, wv = tid >> 6;
    const int wm = wv >> 1, wn = wv & 1, l15 = lane & 15, lg = lane >> 4;
    float outv[4][2][4];
    mlp_mfma<8, 264>(lds, lds, lds + 8704, red, W1p, B1, W2p, B2, W3p, B3, g, be,
                     outv, wm, wn, l15, lg, lane);
#pragma unroll
    for (int nt = 0; nt < 2; nt++) {
        const int i = i0 + wn * 32 + nt * 16 + l15;
        if (i < NPART) {
            float* np = nodes + (size_t)i * HD;
#pragma unroll
            for (int mt = 0; mt < 4; mt++) {
                const int hid = wm * 64 + mt * 16 + lg * 4;
                const float4 old = *(const float4*)(np + hid);
                const float4 nv = make_float4(old.x + outv[mt][nt][0],
                                              old.y + outv[mt][nt][1],
                                              old.z + outv[mt][nt][2],
                                              old.w + outv[mt][nt][3]);
                *(float4*)(np + hid) = nv;
                *(uint2*)(nodes_bf + (size_t)i * HD + hid) =
                    make_uint2(pack2(nv.x, nv.y), pack2(nv.z, nv.w));
            }
        }
    }
}

// ---------------- fp32 gemv for decoder ----------------
template<int K, int S>
__device__ __forceinline__ void gemv(const float* __restrict__ in,
                                     const float* __restrict__ W,
                                     const float* __restrict__ B,
                                     float acc[8])
{
    const int j = threadIdx.x;
    const float bb = B[j];
#pragma unroll
    for (int m = 0; m < 8; m++) acc[m] = bb;
    constexpr int K4 = (K / 4) * 4;
    for (int k = 0; k < K4; k += 4) {
        const float w0 = W[(k + 0) * HD + j];
        const float w1 = W[(k + 1) * HD + j];
        const float w2 = W[(k + 2) * HD + j];
        const float w3 = W[(k + 3) * HD + j];
#pragma unroll
        for (int m = 0; m < 8; m++) {
            const float4 x = *(const float4*)(in + m * S + k);
            float a = acc[m];
            a = fmaf(x.x, w0, a);
            a = fmaf(x.y, w1, a);
            a = fmaf(x.z, w2, a);
            a = fmaf(x.w, w3, a);
            acc[m] = a;
        }
    }
#pragma unroll
    for (int k = K4; k < K; k++) {
        const float w = W[k * HD + j];
#pragma unroll
        for (int m = 0; m < 8; m++) acc[m] = fmaf(in[m * S + k], w, acc[m]);
    }
}

// ---------------- decoder + Euler integration (dual output dtype) ----------------
__global__ __launch_bounds__(128)
void k_decoder(const float* __restrict__ nodes,
               const float* W1, const float* B1, const float* W2, const float* B2,
               const float* W3, const float* B3,
               const float* __restrict__ vel, const float* __restrict__ pos,
               const float* __restrict__ tgt, const int* __restrict__ nonk,
               const unsigned short* __restrict__ braw, void* __restrict__ d_out)
{
    __shared__ __align__(16) float xs[8 * HD];
    __shared__ __align__(16) float h1[8 * HD];
    __shared__ __align__(16) float h2[8 * HD];
    const int j = threadIdx.x;
    const int i0 = blockIdx.x * 8;
    float acc[8];
#pragma unroll
    for (int m = 0; m < 8; m++) xs[m * HD + j] = nodes[(i0 + m) * HD + j];
    __syncthreads();
    gemv<HD, HD>(xs, W1, B1, acc);
#pragma unroll
    for (int m = 0; m < 8; m++) h1[m * HD + j] = fmaxf(acc[m], 0.0f);
    __syncthreads();
    gemv<HD, HD>(h1, W2, B2, acc);
#pragma unroll
    for (int m = 0; m < 8; m++) h2[m * HD + j] = fmaxf(acc[m], 0.0f);
    __syncthreads();
    if (j < 16) {
        const int m = j >> 1, d = j & 1, i = i0 + m;
        float a = B3[d];
        for (int k = 0; k < HD; k++) a = fmaf(h2[m * HD + k], W3[k * 2 + d], a);
        float pp = pos[i * 2 + d] + vel[i * 10 + 8 + d] + a;
        if (nonk[i] == 0) pp = tgt[i * 2 + d];
        if (detect_bf16(braw)) {
            bf16* o = (bf16*)d_out;
            o[i * 2 + d] = __float2bfloat16(a);
            o[2 * NPART + i * 2 + d] = __float2bfloat16(pp);
        } else {
            float* o = (float*)d_out;
            o[i * 2 + d] = a;
            o[2 * NPART + i * 2 + d] = pp;
        }
    }
}

extern "C" void kernel_launch(void* const* d_in, const int* in_sizes, int n_in,
                              void* d_out, int out_size, void* d_ws, size_t ws_size,
                              hipStream_t stream)
{
    const int* ptype = (const int*)d_in[4];
    const int* nonk  = (const int*)d_in[5];
    const int* snd   = (const int*)d_in[6];
    const int* rcv   = (const int*)d_in[7];
    const unsigned short* braw = (const unsigned short*)d_in[2];

    int fmap[NFLOAT_ARRAYS];
    {
        int c = 0;
        fmap[c++] = 0; fmap[c++] = 1; fmap[c++] = 2; fmap[c++] = 3; fmap[c++] = 8;
        for (int i = 9; i <= 46; i++) fmap[c++] = i;
    }
    ConvArgs ca;
    const float* fp[47];
    float* cw = (float*)d_ws;
    int off = 0;
    for (int i = 0; i < NFLOAT_ARRAYS; i++) {
        ca.src[i] = d_in[fmap[i]];
        ca.n[i]   = in_sizes[fmap[i]];
        ca.off[i] = off;
        fp[fmap[i]] = cw + off;
        off += in_sizes[fmap[i]];
    }
    // workspace: f32 states + agg + bf16 node mirror + packed weights + sort scratch
    float* nodes = cw + ((off + 3) & ~3);
    float* agg   = nodes + (size_t)NPART * HD;
    float* edges = agg + (size_t)NPART * HD;
    u16* nodes_bf = (u16*)(edges + (size_t)NEDGE * HD);
    u16* wpk = nodes_bf + (size_t)NPART * HD;

    // build pack table (order: ne x3, ee x3, ge x30, gn x30)
    PackArgs pa;
    int dst = 0, c = 0;
    int pk[NMAT];
    auto addm = [&](long srcoff, int K) {
        const int nk = (K + 31) / 32;
        pa.src_off[c] = (int)srcoff;
        pa.K[c] = K;
        pa.nks[c] = nk;
        pa.dst_off[c] = dst;
        pk[c] = dst;
        dst += nk * 4096;
        c++;
    };
    addm(fp[9]  - cw, 30);  addm(fp[11] - cw, 128); addm(fp[13] - cw, 128);
    addm(fp[17] - cw, 3);   addm(fp[19] - cw, 128); addm(fp[21] - cw, 128);
    for (int l = 0; l < NLAYER; l++) {
        addm(fp[25] - cw + (long)l * 384 * HD, 384);
        addm(fp[27] - cw + (long)l * HD * HD, 128);
        addm(fp[29] - cw + (long)l * HD * HD, 128);
    }
    for (int l = 0; l < NLAYER; l++) {
        addm(fp[33] - cw + (long)l * 256 * HD, 256);
        addm(fp[35] - cw + (long)l * HD * HD, 128);
        addm(fp[37] - cw + (long)l * HD * HD, 128);
    }

    int* ip = (int*)(wpk + ((dst + 7) & ~7));
    int* row_ptr = ip;            ip += NPART + 8;
    int* cursor  = ip;            ip += NPART;
    int* counts  = ip;            ip += NPART;
    int* snd_s   = ip;            ip += NEDGE;
    int* rcv_s   = ip;

    const int EBL = (NEDGE + 255) / 256;

    k_convert<<<dim3(64, NFLOAT_ARRAYS), 256, 0, stream>>>(ca, cw, braw);
    hipMemsetAsync(counts, 0, (size_t)NPART * sizeof(int), stream);
    k_hist<<<EBL, 256, 0, stream>>>(rcv, counts);
    k_scan<<<1, 1024, 0, stream>>>(counts, row_ptr, cursor);
    k_scatter<<<EBL, 256, 0, stream>>>(snd, rcv, cursor, snd_s, rcv_s);
    k_pack<<<dim3(192, NMAT), 256, 0, stream>>>(cw, wpk, pa);

    const int NB = (NPART + 63) / 64;   // 469
    const int EB = (NEDGE + 63) / 64;   // 4688

    k_node_enc_m<<<NB, 256, 0, stream>>>(fp[0], fp[1], fp[2], ptype, fp[8],
        wpk + pk[0], fp[10], wpk + pk[1], fp[12], wpk + pk[2], fp[14],
        fp[15], fp[16], nodes, nodes_bf);
    k_edge_enc_m<<<EB, 256, 0, stream>>>(fp[1], snd_s, rcv_s,
        wpk + pk[3], fp[18], wpk + pk[4], fp[20], wpk + pk[5], fp[22],
        fp[23], fp[24], edges);

    for (int l = 0; l < NLAYER; l++) {
        hipMemsetAsync(agg, 0, (size_t)NPART * HD * sizeof(float), stream);
        k_edge_layer_m<<<EB, 512, 0, stream>>>(nodes_bf, edges, agg, snd_s, rcv_s,
            wpk + pk[6 + 3 * l],  fp[26] + (size_t)l * HD,
            wpk + pk[7 + 3 * l],  fp[28] + (size_t)l * HD,
            wpk + pk[8 + 3 * l],  fp[30] + (size_t)l * HD,
            fp[31] + (size_t)l * HD, fp[32] + (size_t)l * HD);
        k_node_layer_m<<<NB, 256, 0, stream>>>(nodes, nodes_bf, agg,
            wpk + pk[36 + 3 * l], fp[34] + (size_t)l * HD,
            wpk + pk[37 + 3 * l], fp[36] + (size_t)l * HD,
            wpk + pk[38 + 3 * l], fp[38] + (size_t)l * HD,
            fp[39] + (size_t)l * HD, fp[40] + (size_t)l * HD);
    }

    k_decoder<<<NPART / 8, 128, 0, stream>>>(nodes,
        fp[41], fp[42], fp[43], fp[44], fp[45], fp[46],
        fp[0], fp[1], fp[3], nonk, braw, d_out);
}

// Round 5
// 2515.165 us; speedup vs baseline: 5.7951x; 1.0125x over previous
//
#include <hip/hip_runtime.h>
#include <hip/hip_bf16.h>

typedef __hip_bfloat16 bf16;
typedef unsigned short u16;
typedef unsigned int u32;
typedef __attribute__((ext_vector_type(8))) short short8;
typedef __attribute__((ext_vector_type(4))) float f32x4;

#define NPART 30000
#define NEDGE 300000
#define HD 128
#define NLAYER 10
#define NFLOAT_ARRAYS 43
#define NMAT 66

// ---------------- dtype detect ----------------
__device__ __forceinline__ bool detect_bf16(const unsigned short* braw) {
    return braw[1] == 0x3F80u;
}

// ---------------- fp32<->bf16 helpers (RNE) ----------------
__device__ __forceinline__ u16 f2b(float f) {
    u32 u = __float_as_uint(f);
    u += 0x7FFFu + ((u >> 16) & 1u);
    return (u16)(u >> 16);
}
__device__ __forceinline__ u32 pack2(float a, float b) {
    return (u32)f2b(a) | ((u32)f2b(b) << 16);
}

// ---------------- convert all float arrays to canonical fp32 ----------------
struct ConvArgs {
    const void* src[NFLOAT_ARRAYS];
    int n[NFLOAT_ARRAYS];
    int off[NFLOAT_ARRAYS];
};

__global__ __launch_bounds__(256)
void k_convert(ConvArgs a, float* __restrict__ dst, const unsigned short* __restrict__ braw)
{
    const bool isb = detect_bf16(braw);
    const int aid = blockIdx.y;
    const int n = a.n[aid];
    float* o = dst + a.off[aid];
    const int stride = gridDim.x * 256;
    int i = blockIdx.x * 256 + threadIdx.x;
    if (isb) {
        const unsigned short* s = (const unsigned short*)a.src[aid];
        for (; i < n; i += stride) {
            const unsigned int u = ((unsigned int)s[i]) << 16;
            o[i] = __uint_as_float(u);
        }
    } else {
        const float* s = (const float*)a.src[aid];
        for (; i < n; i += stride) o[i] = s[i];
    }
}

// ---------------- counting sort of edges by receiver ----------------
__global__ __launch_bounds__(256)
void k_hist(const int* __restrict__ rcv, int* __restrict__ counts)
{
    const int e = blockIdx.x * 256 + threadIdx.x;
    if (e < NEDGE) atomicAdd(&counts[rcv[e]], 1);
}

__global__ __launch_bounds__(1024)
void k_scan(const int* __restrict__ counts, int* __restrict__ row_ptr, int* __restrict__ cursor)
{
    __shared__ int part[1024];
    const int t = threadIdx.x;
    const int base = t * 32;
    int local[32];
    int s = 0;
#pragma unroll
    for (int k = 0; k < 32; k++) {
        const int idx = base + k;
        const int v = (idx < NPART) ? counts[idx] : 0;
        local[k] = s;
        s += v;
    }
    part[t] = s;
    __syncthreads();
    for (int off = 1; off < 1024; off <<= 1) {
        const int v = (t >= off) ? part[t - off] : 0;
        __syncthreads();
        part[t] += v;
        __syncthreads();
    }
    const int excl = (t == 0) ? 0 : part[t - 1];
#pragma unroll
    for (int k = 0; k < 32; k++) {
        const int idx = base + k;
        if (idx < NPART) {
            const int rp = excl + local[k];
            row_ptr[idx] = rp;
            cursor[idx] = rp;
        }
    }
    if (t == 0) row_ptr[NPART] = NEDGE;
}

__global__ __launch_bounds__(256)
void k_scatter(const int* __restrict__ snd, const int* __restrict__ rcv,
               int* __restrict__ cursor, int* __restrict__ snd_s, int* __restrict__ rcv_s)
{
    const int e = blockIdx.x * 256 + threadIdx.x;
    if (e < NEDGE) {
        const int r = rcv[e];
        const int p = atomicAdd(&cursor[r], 1);
        snd_s[p] = snd[e];
        rcv_s[p] = r;
    }
}

// ---------------- weight pre-pack: f32 [K][128] -> bf16 fragment-linear ----------------
struct PackArgs {
    int src_off[NMAT];
    int dst_off[NMAT];
    int K[NMAT];
    int nks[NMAT];
};

__global__ __launch_bounds__(256)
void k_pack(const float* __restrict__ cw, u16* __restrict__ wpk, PackArgs pa)
{
    const int mid = blockIdx.y;
    const int nks = pa.nks[mid];
    const int total = nks * 4096;
    const int d = blockIdx.x * 256 + threadIdx.x;
    if (d >= total) return;
    const int j = d & 7, l = (d >> 3) & 63, t = d >> 9;
    const int ks = t % nks, mt = t / nks;
    const int hid = mt * 16 + (l & 15);
    const int k = ks * 32 + (l >> 4) * 8 + j;
    const float v = (k < pa.K[mid]) ? cw[pa.src_off[mid] + k * HD + hid] : 0.0f;
    wpk[pa.dst_off[mid] + d] = f2b(v);
}

// ================= 4-wave (256-thr) MFMA MLP: encoders + node layer =================
template<int NKS, int XROW>
__device__ __forceinline__ void gemm16(const u16* __restrict__ Wp,
                                       const float* __restrict__ Bias,
                                       const u16* __restrict__ x,
                                       f32x4 acc[4][2],
                                       const int wm, const int wn,
                                       const int l15, const int lg, const int lane)
{
#pragma unroll
    for (int mt = 0; mt < 4; mt++) {
        const f32x4 bv = *(const f32x4*)(Bias + wm * 64 + mt * 16 + lg * 4);
        acc[mt][0] = bv;
        acc[mt][1] = bv;
    }
    const u16* xr0 = x + (wn * 32 + l15) * XROW + lg * 8;
    const u16* xr1 = xr0 + 16 * XROW;
    const u16* wp = Wp + (wm * 4 * NKS) * 512 + lane * 8;
#pragma unroll
    for (int ks = 0; ks < NKS; ks++) {
        const short8 b0 = *(const short8*)(xr0 + ks * 32);
        const short8 b1 = *(const short8*)(xr1 + ks * 32);
#pragma unroll
        for (int mt = 0; mt < 4; mt++) {
            const short8 a = *(const short8*)(wp + (mt * NKS + ks) * 512);
            acc[mt][0] = __builtin_amdgcn_mfma_f32_16x16x32_bf16(a, b0, acc[mt][0], 0, 0, 0);
            acc[mt][1] = __builtin_amdgcn_mfma_f32_16x16x32_bf16(a, b1, acc[mt][1], 0, 0, 0);
        }
    }
}

__device__ __forceinline__ void store_h(u16* __restrict__ h, const f32x4 acc[4][2],
                                        const int wm, const int wn, const int l15, const int lg)
{
#pragma unroll
    for (int nt = 0; nt < 2; nt++) {
        const int e = wn * 32 + nt * 16 + l15;
#pragma unroll
        for (int mt = 0; mt < 4; mt++) {
            const int hid = wm * 64 + mt * 16 + lg * 4;
            const f32x4 v = acc[mt][nt];
            const u32 lo = pack2(fmaxf(v[0], 0.0f), fmaxf(v[1], 0.0f));
            const u32 hi = pack2(fmaxf(v[2], 0.0f), fmaxf(v[3], 0.0f));
            *(uint2*)(h + e * 136 + hid) = make_uint2(lo, hi);
        }
    }
}

template<int NKS1, int XROW>
__device__ __forceinline__ void mlp_mfma(const u16* __restrict__ xs,
    u16* __restrict__ h1, u16* __restrict__ h2,
    float (*red)[2][2][16][2],
    const u16* __restrict__ W1p, const float* __restrict__ B1,
    const u16* __restrict__ W2p, const float* __restrict__ B2,
    const u16* __restrict__ W3p, const float* __restrict__ B3,
    const float* __restrict__ g, const float* __restrict__ be,
    float outv[4][2][4],
    const int wm, const int wn, const int l15, const int lg, const int lane)
{
    f32x4 acc[4][2];
    gemm16<NKS1, XROW>(W1p, B1, xs, acc, wm, wn, l15, lg, lane);
    __syncthreads();
    store_h(h1, acc, wm, wn, l15, lg);
    __syncthreads();
    gemm16<4, 136>(W2p, B2, h1, acc, wm, wn, l15, lg, lane);
    store_h(h2, acc, wm, wn, l15, lg);
    __syncthreads();
    gemm16<4, 136>(W3p, B3, h2, acc, wm, wn, l15, lg, lane);
    float ps[2], pss[2];
#pragma unroll
    for (int nt = 0; nt < 2; nt++) {
        float s = 0.0f, ss = 0.0f;
#pragma unroll
        for (int mt = 0; mt < 4; mt++) {
#pragma unroll
            for (int r = 0; r < 4; r++) {
                const float v = acc[mt][nt][r];
                s += v; ss += v * v;
            }
        }
        s += __shfl_xor(s, 16); ss += __shfl_xor(ss, 16);
        s += __shfl_xor(s, 32); ss += __shfl_xor(ss, 32);
        ps[nt] = s; pss[nt] = ss;
    }
    if (lane < 16) {
#pragma unroll
        for (int nt = 0; nt < 2; nt++) {
            red[wm][wn][nt][l15][0] = ps[nt];
            red[wm][wn][nt][l15][1] = pss[nt];
        }
    }
    __syncthreads();
#pragma unroll
    for (int nt = 0; nt < 2; nt++) {
        const float S  = red[0][wn][nt][l15][0] + red[1][wn][nt][l15][0];
        const float SS = red[0][wn][nt][l15][1] + red[1][wn][nt][l15][1];
        const float mu  = S * (1.0f / 128.0f);
        const float var = SS * (1.0f / 128.0f) - mu * mu;
        const float inv = rsqrtf(var + 1e-5f);
#pragma unroll
        for (int mt = 0; mt < 4; mt++) {
            const int hid = wm * 64 + mt * 16 + lg * 4;
            const f32x4 gv  = *(const f32x4*)(g + hid);
            const f32x4 bev = *(const f32x4*)(be + hid);
#pragma unroll
            for (int r = 0; r < 4; r++)
                outv[mt][nt][r] = (acc[mt][nt][r] - mu) * inv * gv[r] + bev[r];
        }
    }
}

// ---------------- node encoder (K=30 padded to 32) ----------------
__device__ __forceinline__ float nfeat(int i, int k,
    const float* __restrict__ vel, const float* __restrict__ pos,
    const float* __restrict__ bounds, const int* __restrict__ ptype,
    const float* __restrict__ emb)
{
    if (k < 10) return vel[i * 10 + k];
    if (k < 14) {
        const int q = k - 10;
        float sub;
        if (q < 2) sub = pos[i * 2 + q] - bounds[q * 2 + 0];
        else       sub = bounds[(q - 2) * 2 + 1] - pos[i * 2 + (q - 2)];
        const float dv = sub * 20.0f;
        return fminf(fmaxf(dv, -1.0f), 1.0f);
    }
    if (k < 30) return emb[ptype[i] * 16 + (k - 14)];
    return 0.0f;
}

__global__ __launch_bounds__(256)
void k_node_enc_m(const float* __restrict__ vel, const float* __restrict__ pos,
                  const float* __restrict__ bounds, const int* __restrict__ ptype,
                  const float* __restrict__ emb,
                  const u16* __restrict__ W1p, const float* __restrict__ B1,
                  const u16* __restrict__ W2p, const float* __restrict__ B2,
                  const u16* __restrict__ W3p, const float* __restrict__ B3,
                  const float* __restrict__ g, const float* __restrict__ be,
                  float* __restrict__ nodes, u16* __restrict__ nodes_bf)
{
    __shared__ __align__(16) u16 lds[17408];
    __shared__ float red[2][2][2][16][2];
    const int tid = threadIdx.x;
    const int i0 = blockIdx.x * 64;
    for (int idx = tid; idx < 1024; idx += 256) {
        const int m = idx >> 4, kk = idx & 15;
        const int i = i0 + m;
        float f0 = 0.0f, f1 = 0.0f;
        if (i < NPART) {
            f0 = nfeat(i, kk * 2 + 0, vel, pos, bounds, ptype, emb);
            f1 = nfeat(i, kk * 2 + 1, vel, pos, bounds, ptype, emb);
        }
        *(u32*)(lds + m * 40 + kk * 2) = pack2(f0, f1);
    }
    __syncthreads();
    const int lane = tid & 63, wv = tid >> 6;
    const int wm = wv >> 1, wn = wv & 1, l15 = lane & 15, lg = lane >> 4;
    float outv[4][2][4];
    mlp_mfma<1, 40>(lds, lds, lds + 8704, red, W1p, B1, W2p, B2, W3p, B3, g, be,
                    outv, wm, wn, l15, lg, lane);
#pragma unroll
    for (int nt = 0; nt < 2; nt++) {
        const int i = i0 + wn * 32 + nt * 16 + l15;
        if (i < NPART) {
#pragma unroll
            for (int mt = 0; mt < 4; mt++) {
                const int hid = wm * 64 + mt * 16 + lg * 4;
                const float4 v = make_float4(outv[mt][nt][0], outv[mt][nt][1],
                                             outv[mt][nt][2], outv[mt][nt][3]);
                *(float4*)(nodes + (size_t)i * HD + hid) = v;
                *(uint2*)(nodes_bf + (size_t)i * HD + hid) =
                    make_uint2(pack2(v.x, v.y), pack2(v.z, v.w));
            }
        }
    }
}

// ---------------- edge encoder (K=3 padded to 32), sorted edge order ----------------
__global__ __launch_bounds__(256)
void k_edge_enc_m(const float* __restrict__ pos, const int* __restrict__ snd_s,
                  const int* __restrict__ rcv_s,
                  const u16* __restrict__ W1p, const float* __restrict__ B1,
                  const u16* __restrict__ W2p, const float* __restrict__ B2,
                  const u16* __restrict__ W3p, const float* __restrict__ B3,
                  const float* __restrict__ g, const float* __restrict__ be,
                  float* __restrict__ edges)
{
    __shared__ __align__(16) u16 lds[17408];
    __shared__ float red[2][2][2][16][2];
    const int tid = threadIdx.x;
    const int e0 = blockIdx.x * 64;
    for (int idx = tid; idx < 1024; idx += 256) {
        const int m = idx >> 4, kk = idx & 15;
        const int e = min(e0 + m, NEDGE - 1);
        u32 w = 0;
        if (kk < 2) {
            const int s = snd_s[e], r = rcv_s[e];
            const float dx = (pos[s * 2 + 0] - pos[r * 2 + 0]) * 20.0f;
            const float dy = (pos[s * 2 + 1] - pos[r * 2 + 1]) * 20.0f;
            if (kk == 0) w = pack2(dx, dy);
            else         w = pack2(sqrtf(dx * dx + dy * dy), 0.0f);
        }
        *(u32*)(lds + m * 40 + kk * 2) = w;
    }
    __syncthreads();
    const int lane = tid & 63, wv = tid >> 6;
    const int wm = wv >> 1, wn = wv & 1, l15 = lane & 15, lg = lane >> 4;
    float outv[4][2][4];
    mlp_mfma<1, 40>(lds, lds, lds + 8704, red, W1p, B1, W2p, B2, W3p, B3, g, be,
                    outv, wm, wn, l15, lg, lane);
#pragma unroll
    for (int nt = 0; nt < 2; nt++) {
        const int e = e0 + wn * 32 + nt * 16 + l15;
        if (e < NEDGE) {
#pragma unroll
            for (int mt = 0; mt < 4; mt++) {
                const int hid = wm * 64 + mt * 16 + lg * 4;
                *(float4*)(edges + (size_t)e * HD + hid) =
                    make_float4(outv[mt][nt][0], outv[mt][nt][1], outv[mt][nt][2], outv[mt][nt][3]);
            }
        }
    }
}

// ================= 4-wave (256-thr) 32-row pipelined edge layer + fused agg =============
// wave wm = wv in 0..3 (32 hid each); rows = nt*16 + l15 (32 rows per block).
__device__ __forceinline__ void egemm_seg32(const u16* __restrict__ Wp,
                                            const u16* __restrict__ x,
                                            f32x4 acc[2][2], const int ks0,
                                            const int wm,
                                            const int l15, const int lg, const int lane)
{
    const u16* xr0 = x + l15 * 136 + lg * 8;
    const u16* xr1 = xr0 + 16 * 136;
#pragma unroll
    for (int ks = 0; ks < 4; ks++) {
        const short8 b0 = *(const short8*)(xr0 + ks * 32);
        const short8 b1 = *(const short8*)(xr1 + ks * 32);
#pragma unroll
        for (int mt = 0; mt < 2; mt++) {
            const short8 a = *(const short8*)(Wp + (((wm * 2 + mt) * 12 + ks0 + ks) * 64 + lane) * 8);
            acc[mt][0] = __builtin_amdgcn_mfma_f32_16x16x32_bf16(a, b0, acc[mt][0], 0, 0, 0);
            acc[mt][1] = __builtin_amdgcn_mfma_f32_16x16x32_bf16(a, b1, acc[mt][1], 0, 0, 0);
        }
    }
}

__device__ __forceinline__ void egemm_h32(const u16* __restrict__ Wp,
                                          const float* __restrict__ Bias,
                                          const u16* __restrict__ x,
                                          f32x4 acc[2][2],
                                          const int wm,
                                          const int l15, const int lg, const int lane)
{
#pragma unroll
    for (int mt = 0; mt < 2; mt++) {
        const f32x4 bv = *(const f32x4*)(Bias + wm * 32 + mt * 16 + lg * 4);
        acc[mt][0] = bv;
        acc[mt][1] = bv;
    }
    const u16* xr0 = x + l15 * 136 + lg * 8;
    const u16* xr1 = xr0 + 16 * 136;
#pragma unroll
    for (int ks = 0; ks < 4; ks++) {
        const short8 b0 = *(const short8*)(xr0 + ks * 32);
        const short8 b1 = *(const short8*)(xr1 + ks * 32);
#pragma unroll
        for (int mt = 0; mt < 2; mt++) {
            const short8 a = *(const short8*)(Wp + (((wm * 2 + mt) * 4 + ks) * 64 + lane) * 8);
            acc[mt][0] = __builtin_amdgcn_mfma_f32_16x16x32_bf16(a, b0, acc[mt][0], 0, 0, 0);
            acc[mt][1] = __builtin_amdgcn_mfma_f32_16x16x32_bf16(a, b1, acc[mt][1], 0, 0, 0);
        }
    }
}

__device__ __forceinline__ void estore_h32(u16* __restrict__ h, const f32x4 acc[2][2],
                                           const int wm, const int l15, const int lg)
{
#pragma unroll
    for (int nt = 0; nt < 2; nt++) {
        const int row = nt * 16 + l15;
#pragma unroll
        for (int mt = 0; mt < 2; mt++) {
            const int hid = wm * 32 + mt * 16 + lg * 4;
            const f32x4 v = acc[mt][nt];
            const u32 lo = pack2(fmaxf(v[0], 0.0f), fmaxf(v[1], 0.0f));
            const u32 hi = pack2(fmaxf(v[2], 0.0f), fmaxf(v[3], 0.0f));
            *(uint2*)(h + row * 136 + hid) = make_uint2(lo, hi);
        }
    }
}

__global__ __launch_bounds__(256, 8)
void k_edge_layer_m(const u16* __restrict__ nodes_bf, float* __restrict__ edges,
                    float* __restrict__ agg,
                    const int* __restrict__ snd_s, const int* __restrict__ rcv_s,
                    const u16* __restrict__ W1p, const float* __restrict__ B1,
                    const u16* __restrict__ W2p, const float* __restrict__ B2,
                    const u16* __restrict__ W3p, const float* __restrict__ B3,
                    const float* __restrict__ g, const float* __restrict__ be)
{
    __shared__ __align__(16) u16 sb[2 * 4352];   // b0,b1: 32x136 bf16 each; fout overlays
    __shared__ float red[4][2][16][2];
    __shared__ int rblk[34];                     // [0..31] receivers, 32=prev, 33=next
    u16* b0 = sb;
    u16* b1 = sb + 4352;
    float* fout = (float*)sb;                    // 32 rows x stride 132 f32 = 16896B

    const int tid = threadIdx.x;
    const int e0 = blockIdx.x * 32;              // NEDGE/32 = 9375 blocks, exact
    const int lane = tid & 63, wm = tid >> 6;
    const int l15 = lane & 15, lg = lane >> 4;

    if (tid < 32)       rblk[tid] = rcv_s[e0 + tid];
    else if (tid == 32) rblk[32] = (e0 > 0) ? rcv_s[e0 - 1] : -2;
    else if (tid == 33) rblk[33] = (e0 + 32 < NEDGE) ? rcv_s[e0 + 32] : -2;

    // stage seg0 (edge rows, f32 -> bf16) into b0
#pragma unroll
    for (int t = 0; t < 2; t++) {
        const int idx = tid + t * 256;
        const int m = idx >> 4, q = idx & 15;
        const float* src = edges + (size_t)(e0 + m) * HD + q * 8;
        const float4 a = *(const float4*)(src);
        const float4 b = *(const float4*)(src + 4);
        *(uint4*)(b0 + m * 136 + q * 8) =
            make_uint4(pack2(a.x, a.y), pack2(a.z, a.w), pack2(b.x, b.y), pack2(b.z, b.w));
    }
    // issue seg1 (sender rows, bf16) loads -> regs
    uint4 st[2];
#pragma unroll
    for (int t = 0; t < 2; t++) {
        const int idx = tid + t * 256;
        const int m = idx >> 4, q = idx & 15;
        st[t] = *(const uint4*)(nodes_bf + (size_t)snd_s[e0 + m] * HD + q * 8);
    }
    __syncthreads();

    f32x4 acc[2][2];
#pragma unroll
    for (int mt = 0; mt < 2; mt++) {
        const f32x4 bv = *(const f32x4*)(B1 + wm * 32 + mt * 16 + lg * 4);
        acc[mt][0] = bv;
        acc[mt][1] = bv;
    }
    __builtin_amdgcn_s_setprio(1);
    egemm_seg32(W1p, b0, acc, 0, wm, l15, lg, lane);
    __builtin_amdgcn_s_setprio(0);
    // write seg1 -> b1, issue seg2 (receiver rows) loads
#pragma unroll
    for (int t = 0; t < 2; t++) {
        const int idx = tid + t * 256;
        const int m = idx >> 4, q = idx & 15;
        *(uint4*)(b1 + m * 136 + q * 8) = st[t];
    }
#pragma unroll
    for (int t = 0; t < 2; t++) {
        const int idx = tid + t * 256;
        const int m = idx >> 4, q = idx & 15;
        st[t] = *(const uint4*)(nodes_bf + (size_t)rcv_s[e0 + m] * HD + q * 8);
    }
    __syncthreads();

    __builtin_amdgcn_s_setprio(1);
    egemm_seg32(W1p, b1, acc, 4, wm, l15, lg, lane);
    __builtin_amdgcn_s_setprio(0);
#pragma unroll
    for (int t = 0; t < 2; t++) {
        const int idx = tid + t * 256;
        const int m = idx >> 4, q = idx & 15;
        *(uint4*)(b0 + m * 136 + q * 8) = st[t];
    }
    __syncthreads();

    __builtin_amdgcn_s_setprio(1);
    egemm_seg32(W1p, b0, acc, 8, wm, l15, lg, lane);
    __builtin_amdgcn_s_setprio(0);
    estore_h32(b1, acc, wm, l15, lg);      // b1 free: all waves past prev barrier
    __syncthreads();

    __builtin_amdgcn_s_setprio(1);
    egemm_h32(W2p, B2, b1, acc, wm, l15, lg, lane);
    __builtin_amdgcn_s_setprio(0);
    estore_h32(b0, acc, wm, l15, lg);      // b0 free
    __syncthreads();

    __builtin_amdgcn_s_setprio(1);
    egemm_h32(W3p, B3, b0, acc, wm, l15, lg, lane);
    __builtin_amdgcn_s_setprio(0);

    // ---- layernorm reduction ----
    float ps[2], pss[2];
#pragma unroll
    for (int nt = 0; nt < 2; nt++) {
        float s = 0.0f, ss = 0.0f;
#pragma unroll
        for (int mt = 0; mt < 2; mt++) {
#pragma unroll
            for (int r = 0; r < 4; r++) {
                const float v = acc[mt][nt][r];
                s += v; ss += v * v;
            }
        }
        s += __shfl_xor(s, 16); ss += __shfl_xor(ss, 16);
        s += __shfl_xor(s, 32); ss += __shfl_xor(ss, 32);
        ps[nt] = s; pss[nt] = ss;
    }
    if (lane < 16) {
#pragma unroll
        for (int nt = 0; nt < 2; nt++) {
            red[wm][nt][l15][0] = ps[nt];
            red[wm][nt][l15][1] = pss[nt];
        }
    }
    __syncthreads();   // red ready; all waves past GEMM3 -> b0/b1 dead, fout may overlay

    // ---- LN apply -> fout (f32, stride 132) ----
#pragma unroll
    for (int nt = 0; nt < 2; nt++) {
        const float S  = red[0][nt][l15][0] + red[1][nt][l15][0]
                       + red[2][nt][l15][0] + red[3][nt][l15][0];
        const float SS = red[0][nt][l15][1] + red[1][nt][l15][1]
                       + red[2][nt][l15][1] + red[3][nt][l15][1];
        const float mu  = S * (1.0f / 128.0f);
        const float var = SS * (1.0f / 128.0f) - mu * mu;
        const float inv = rsqrtf(var + 1e-5f);
        const int row = nt * 16 + l15;
#pragma unroll
        for (int mt = 0; mt < 2; mt++) {
            const int hid = wm * 32 + mt * 16 + lg * 4;
            const f32x4 gv  = *(const f32x4*)(g + hid);
            const f32x4 bev = *(const f32x4*)(be + hid);
            f32x4 o;
#pragma unroll
            for (int r = 0; r < 4; r++)
                o[r] = (acc[mt][nt][r] - mu) * inv * gv[r] + bev[r];
            *(f32x4*)(fout + row * 132 + hid) = o;
        }
    }
    __syncthreads();

    // ---- writer: new = old(global, L2-hot) + ln; coalesced row write; new -> fout ----
#pragma unroll
    for (int t = 0; t < 2; t++) {
        const int idx = tid + t * 256;
        const int m = idx >> 4, q = idx & 15;
        float* ep = edges + (size_t)(e0 + m) * HD + q * 8;
        const float4 olda = *(const float4*)(ep);
        const float4 oldb = *(const float4*)(ep + 4);
        float4 lo = *(const float4*)(fout + m * 132 + q * 8);
        float4 hi = *(const float4*)(fout + m * 132 + q * 8 + 4);
        lo.x += olda.x; lo.y += olda.y; lo.z += olda.z; lo.w += olda.w;
        hi.x += oldb.x; hi.y += oldb.y; hi.z += oldb.z; hi.w += oldb.w;
        *(float4*)(ep) = lo;
        *(float4*)(ep + 4) = hi;
        *(float4*)(fout + m * 132 + q * 8) = lo;
        *(float4*)(fout + m * 132 + q * 8 + 4) = hi;
    }
    __syncthreads();

    // ---- fused aggregation: per-receiver run sums from fout -> agg ----
    const int c = tid & 31;              // float4 chunk 0..31
    for (int ms = (tid >> 5); ms < 32; ms += 8) {
        const int rs = rblk[ms];
        if (ms > 0 && rblk[ms - 1] == rs) continue;   // not a run start
        int me = ms + 1;
        while (me < 32 && rblk[me] == rs) me++;
        float4 s = make_float4(0.0f, 0.0f, 0.0f, 0.0f);
        for (int m = ms; m < me; m++) {
            const float4 v = *(const float4*)(fout + m * 132 + c * 4);
            s.x += v.x; s.y += v.y; s.z += v.z; s.w += v.w;
        }
        float* ap = agg + (size_t)rs * HD + c * 4;
        const bool bnd = (ms == 0 && rblk[32] == rs) || (me == 32 && rblk[33] == rs);
        if (bnd) {
            atomicAdd(ap + 0, s.x); atomicAdd(ap + 1, s.y);
            atomicAdd(ap + 2, s.z); atomicAdd(ap + 3, s.w);
        } else {
            *(float4*)ap = s;
        }
    }
}

// ------- per-layer node update (K=256); reads agg and re-zeroes it for next layer -------
__global__ __launch_bounds__(256)
void k_node_layer_m(float* __restrict__ nodes, u16* __restrict__ nodes_bf,
                    float* __restrict__ agg,
                    const u16* __restrict__ W1p, const float* __restrict__ B1,
                    const u16* __restrict__ W2p, const float* __restrict__ B2,
                    const u16* __restrict__ W3p, const float* __restrict__ B3,
                    const float* __restrict__ g, const float* __restrict__ be)
{
    __shared__ __align__(16) u16 lds[17408];
    __shared__ float red[2][2][2][16][2];
    const int tid = threadIdx.x;
    const int i0 = blockIdx.x * 64;
    for (int idx = tid; idx < 1024; idx += 256) {
        const int m = idx >> 4, q = idx & 15;
        const int i = min(i0 + m, NPART - 1);
        const float* src = nodes + (size_t)i * HD + q * 8;
        const float4 a = *(const float4*)(src);
        const float4 b = *(const float4*)(src + 4);
        *(uint4*)(lds + m * 264 + q * 8) =
            make_uint4(pack2(a.x, a.y), pack2(a.z, a.w), pack2(b.x, b.y), pack2(b.z, b.w));
    }
    const float4 z4 = make_float4(0.0f, 0.0f, 0.0f, 0.0f);
    for (int idx = tid; idx < 1024; idx += 256) {
        const int m = idx >> 4, q = idx & 15;
        const int i = min(i0 + m, NPART - 1);
        float* src = agg + (size_t)i * HD + q * 8;
        const float4 a = *(const float4*)(src);
        const float4 b = *(const float4*)(src + 4);
        *(uint4*)(lds + m * 264 + 128 + q * 8) =
            make_uint4(pack2(a.x, a.y), pack2(a.z, a.w), pack2(b.x, b.y), pack2(b.z, b.w));
        *(float4*)(src) = z4;                    // zero for next layer (own rows only)
        *(float4*)(src + 4) = z4;
    }
    __syncthreads();
    const int lane = tid & 63, wv = tid >> 6;
    const int wm = wv >> 1, wn = wv & 1, l15 = lane & 15, lg = lane >> 4;
    float outv[4][2][4];
    mlp_mfma<8, 264>(lds, lds, lds + 8704, red, W1p, B1, W2p, B2, W3p, B3, g, be,
                     outv, wm, wn, l15, lg, lane);
#pragma unroll
    for (int nt = 0; nt < 2; nt++) {
        const int i = i0 + wn * 32 + nt * 16 + l15;
        if (i < NPART) {
            float* np = nodes + (size_t)i * HD;
#pragma unroll
            for (int mt = 0; mt < 4; mt++) {
                const int hid = wm * 64 + mt * 16 + lg * 4;
                const float4 old = *(const float4*)(np + hid);
                const float4 nv = make_float4(old.x + outv[mt][nt][0],
                                              old.y + outv[mt][nt][1],
                                              old.z + outv[mt][nt][2],
                                              old.w + outv[mt][nt][3]);
                *(float4*)(np + hid) = nv;
                *(uint2*)(nodes_bf + (size_t)i * HD + hid) =
                    make_uint2(pack2(nv.x, nv.y), pack2(nv.z, nv.w));
            }
        }
    }
}

// ---------------- fp32 gemv for decoder ----------------
template<int K, int S>
__device__ __forceinline__ void gemv(const float* __restrict__ in,
                                     const float* __restrict__ W,
                                     const float* __restrict__ B,
                                     float acc[8])
{
    const int j = threadIdx.x;
    const float bb = B[j];
#pragma unroll
    for (int m = 0; m < 8; m++) acc[m] = bb;
    constexpr int K4 = (K / 4) * 4;
    for (int k = 0; k < K4; k += 4) {
        const float w0 = W[(k + 0) * HD + j];
        const float w1 = W[(k + 1) * HD + j];
        const float w2 = W[(k + 2) * HD + j];
        const float w3 = W[(k + 3) * HD + j];
#pragma unroll
        for (int m = 0; m < 8; m++) {
            const float4 x = *(const float4*)(in + m * S + k);
            float a = acc[m];
            a = fmaf(x.x, w0, a);
            a = fmaf(x.y, w1, a);
            a = fmaf(x.z, w2, a);
            a = fmaf(x.w, w3, a);
            acc[m] = a;
        }
    }
#pragma unroll
    for (int k = K4; k < K; k++) {
        const float w = W[k * HD + j];
#pragma unroll
        for (int m = 0; m < 8; m++) acc[m] = fmaf(in[m * S + k], w, acc[m]);
    }
}

// ---------------- decoder + Euler integration (dual output dtype) ----------------
__global__ __launch_bounds__(128)
void k_decoder(const float* __restrict__ nodes,
               const float* W1, const float* B1, const float* W2, const float* B2,
               const float* W3, const float* B3,
               const float* __restrict__ vel, const float* __restrict__ pos,
               const float* __restrict__ tgt, const int* __restrict__ nonk,
               const unsigned short* __restrict__ braw, void* __restrict__ d_out)
{
    __shared__ __align__(16) float xs[8 * HD];
    __shared__ __align__(16) float h1[8 * HD];
    __shared__ __align__(16) float h2[8 * HD];
    const int j = threadIdx.x;
    const int i0 = blockIdx.x * 8;
    float acc[8];
#pragma unroll
    for (int m = 0; m < 8; m++) xs[m * HD + j] = nodes[(i0 + m) * HD + j];
    __syncthreads();
    gemv<HD, HD>(xs, W1, B1, acc);
#pragma unroll
    for (int m = 0; m < 8; m++) h1[m * HD + j] = fmaxf(acc[m], 0.0f);
    __syncthreads();
    gemv<HD, HD>(h1, W2, B2, acc);
#pragma unroll
    for (int m = 0; m < 8; m++) h2[m * HD + j] = fmaxf(acc[m], 0.0f);
    __syncthreads();
    if (j < 16) {
        const int m = j >> 1, d = j & 1, i = i0 + m;
        float a = B3[d];
        for (int k = 0; k < HD; k++) a = fmaf(h2[m * HD + k], W3[k * 2 + d], a);
        float pp = pos[i * 2 + d] + vel[i * 10 + 8 + d] + a;
        if (nonk[i] == 0) pp = tgt[i * 2 + d];
        if (detect_bf16(braw)) {
            bf16* o = (bf16*)d_out;
            o[i * 2 + d] = __float2bfloat16(a);
            o[2 * NPART + i * 2 + d] = __float2bfloat16(pp);
        } else {
            float* o = (float*)d_out;
            o[i * 2 + d] = a;
            o[2 * NPART + i * 2 + d] = pp;
        }
    }
}

extern "C" void kernel_launch(void* const* d_in, const int* in_sizes, int n_in,
                              void* d_out, int out_size, void* d_ws, size_t ws_size,
                              hipStream_t stream)
{
    const int* ptype = (const int*)d_in[4];
    const int* nonk  = (const int*)d_in[5];
    const int* snd   = (const int*)d_in[6];
    const int* rcv   = (const int*)d_in[7];
    const unsigned short* braw = (const unsigned short*)d_in[2];

    int fmap[NFLOAT_ARRAYS];
    {
        int c = 0;
        fmap[c++] = 0; fmap[c++] = 1; fmap[c++] = 2; fmap[c++] = 3; fmap[c++] = 8;
        for (int i = 9; i <= 46; i++) fmap[c++] = i;
    }
    ConvArgs ca;
    const float* fp[47];
    float* cw = (float*)d_ws;
    int off = 0;
    for (int i = 0; i < NFLOAT_ARRAYS; i++) {
        ca.src[i] = d_in[fmap[i]];
        ca.n[i]   = in_sizes[fmap[i]];
        ca.off[i] = off;
        fp[fmap[i]] = cw + off;
        off += in_sizes[fmap[i]];
    }
    // workspace: f32 states + agg + bf16 node mirror + packed weights + sort scratch
    float* nodes = cw + ((off + 3) & ~3);
    float* agg   = nodes + (size_t)NPART * HD;
    float* edges = agg + (size_t)NPART * HD;
    u16* nodes_bf = (u16*)(edges + (size_t)NEDGE * HD);
    u16* wpk = nodes_bf + (size_t)NPART * HD;

    // build pack table (order: ne x3, ee x3, ge x30, gn x30)
    PackArgs pa;
    int dst = 0, c = 0;
    int pk[NMAT];
    auto addm = [&](long srcoff, int K) {
        const int nk = (K + 31) / 32;
        pa.src_off[c] = (int)srcoff;
        pa.K[c] = K;
        pa.nks[c] = nk;
        pa.dst_off[c] = dst;
        pk[c] = dst;
        dst += nk * 4096;
        c++;
    };
    addm(fp[9]  - cw, 30);  addm(fp[11] - cw, 128); addm(fp[13] - cw, 128);
    addm(fp[17] - cw, 3);   addm(fp[19] - cw, 128); addm(fp[21] - cw, 128);
    for (int l = 0; l < NLAYER; l++) {
        addm(fp[25] - cw + (long)l * 384 * HD, 384);
        addm(fp[27] - cw + (long)l * HD * HD, 128);
        addm(fp[29] - cw + (long)l * HD * HD, 128);
    }
    for (int l = 0; l < NLAYER; l++) {
        addm(fp[33] - cw + (long)l * 256 * HD, 256);
        addm(fp[35] - cw + (long)l * HD * HD, 128);
        addm(fp[37] - cw + (long)l * HD * HD, 128);
    }

    int* ip = (int*)(wpk + ((dst + 7) & ~7));
    int* row_ptr = ip;            ip += NPART + 8;
    int* cursor  = ip;            ip += NPART;
    int* counts  = ip;            ip += NPART;
    int* snd_s   = ip;            ip += NEDGE;
    int* rcv_s   = ip;

    const int EBL = (NEDGE + 255) / 256;

    k_convert<<<dim3(64, NFLOAT_ARRAYS), 256, 0, stream>>>(ca, cw, braw);
    hipMemsetAsync(counts, 0, (size_t)NPART * sizeof(int), stream);
    hipMemsetAsync(agg, 0, (size_t)NPART * HD * sizeof(float), stream);
    k_hist<<<EBL, 256, 0, stream>>>(rcv, counts);
    k_scan<<<1, 1024, 0, stream>>>(counts, row_ptr, cursor);
    k_scatter<<<EBL, 256, 0, stream>>>(snd, rcv, cursor, snd_s, rcv_s);
    k_pack<<<dim3(192, NMAT), 256, 0, stream>>>(cw, wpk, pa);

    const int NB = (NPART + 63) / 64;   // 469
    const int EB = (NEDGE + 63) / 64;   // 4688 (encoder)
    const int EB32 = NEDGE / 32;        // 9375 (edge layer, exact)

    k_node_enc_m<<<NB, 256, 0, stream>>>(fp[0], fp[1], fp[2], ptype, fp[8],
        wpk + pk[0], fp[10], wpk + pk[1], fp[12], wpk + pk[2], fp[14],
        fp[15], fp[16], nodes, nodes_bf);
    k_edge_enc_m<<<EB, 256, 0, stream>>>(fp[1], snd_s, rcv_s,
        wpk + pk[3], fp[18], wpk + pk[4], fp[20], wpk + pk[5], fp[22],
        fp[23], fp[24], edges);

    for (int l = 0; l < NLAYER; l++) {
        k_edge_layer_m<<<EB32, 256, 0, stream>>>(nodes_bf, edges, agg, snd_s, rcv_s,
            wpk + pk[6 + 3 * l],  fp[26] + (size_t)l * HD,
            wpk + pk[7 + 3 * l],  fp[28] + (size_t)l * HD,
            wpk + pk[8 + 3 * l],  fp[30] + (size_t)l * HD,
            fp[31] + (size_t)l * HD, fp[32] + (size_t)l * HD);
        k_node_layer_m<<<NB, 256, 0, stream>>>(nodes, nodes_bf, agg,
            wpk + pk[36 + 3 * l], fp[34] + (size_t)l * HD,
            wpk + pk[37 + 3 * l], fp[36] + (size_t)l * HD,
            wpk + pk[38 + 3 * l], fp[38] + (size_t)l * HD,
            fp[39] + (size_t)l * HD, fp[40] + (size_t)l * HD);
    }

    k_decoder<<<NPART / 8, 128, 0, stream>>>(nodes,
        fp[41], fp[42], fp[43], fp[44], fp[45], fp[46],
        fp[0], fp[1], fp[3], nonk, braw, d_out);
}

// Round 6
// 2219.409 us; speedup vs baseline: 6.5674x; 1.1333x over previous
//
#include <hip/hip_runtime.h>
#include <hip/hip_bf16.h>

typedef __hip_bfloat16 bf16;
typedef unsigned short u16;
typedef unsigned int u32;
typedef __attribute__((ext_vector_type(8))) short short8;
typedef __attribute__((ext_vector_type(4))) float f32x4;

#define NPART 30000
#define NEDGE 300000
#define HD 128
#define NLAYER 10
#define NFLOAT_ARRAYS 43
#define NMAT 66

// ---------------- dtype detect ----------------
__device__ __forceinline__ bool detect_bf16(const unsigned short* braw) {
    return braw[1] == 0x3F80u;
}

// ---------------- fp32<->bf16 helpers (RNE) ----------------
__device__ __forceinline__ u16 f2b(float f) {
    u32 u = __float_as_uint(f);
    u += 0x7FFFu + ((u >> 16) & 1u);
    return (u16)(u >> 16);
}
__device__ __forceinline__ u32 pack2(float a, float b) {
    return (u32)f2b(a) | ((u32)f2b(b) << 16);
}
__device__ __forceinline__ float b2flo(u32 u) { return __uint_as_float(u << 16); }
__device__ __forceinline__ float b2fhi(u32 u) { return __uint_as_float(u & 0xFFFF0000u); }

// ---------------- convert all float arrays to canonical fp32 ----------------
struct ConvArgs {
    const void* src[NFLOAT_ARRAYS];
    int n[NFLOAT_ARRAYS];
    int off[NFLOAT_ARRAYS];
};

__global__ __launch_bounds__(256)
void k_convert(ConvArgs a, float* __restrict__ dst, const unsigned short* __restrict__ braw)
{
    const bool isb = detect_bf16(braw);
    const int aid = blockIdx.y;
    const int n = a.n[aid];
    float* o = dst + a.off[aid];
    const int stride = gridDim.x * 256;
    int i = blockIdx.x * 256 + threadIdx.x;
    if (isb) {
        const unsigned short* s = (const unsigned short*)a.src[aid];
        for (; i < n; i += stride) {
            const unsigned int u = ((unsigned int)s[i]) << 16;
            o[i] = __uint_as_float(u);
        }
    } else {
        const float* s = (const float*)a.src[aid];
        for (; i < n; i += stride) o[i] = s[i];
    }
}

// ---------------- counting sort of edges by receiver ----------------
__global__ __launch_bounds__(256)
void k_hist(const int* __restrict__ rcv, int* __restrict__ counts)
{
    const int e = blockIdx.x * 256 + threadIdx.x;
    if (e < NEDGE) atomicAdd(&counts[rcv[e]], 1);
}

__global__ __launch_bounds__(1024)
void k_scan(const int* __restrict__ counts, int* __restrict__ row_ptr, int* __restrict__ cursor)
{
    __shared__ int part[1024];
    const int t = threadIdx.x;
    const int base = t * 32;
    int local[32];
    int s = 0;
#pragma unroll
    for (int k = 0; k < 32; k++) {
        const int idx = base + k;
        const int v = (idx < NPART) ? counts[idx] : 0;
        local[k] = s;
        s += v;
    }
    part[t] = s;
    __syncthreads();
    for (int off = 1; off < 1024; off <<= 1) {
        const int v = (t >= off) ? part[t - off] : 0;
        __syncthreads();
        part[t] += v;
        __syncthreads();
    }
    const int excl = (t == 0) ? 0 : part[t - 1];
#pragma unroll
    for (int k = 0; k < 32; k++) {
        const int idx = base + k;
        if (idx < NPART) {
            const int rp = excl + local[k];
            row_ptr[idx] = rp;
            cursor[idx] = rp;
        }
    }
    if (t == 0) row_ptr[NPART] = NEDGE;
}

__global__ __launch_bounds__(256)
void k_scatter(const int* __restrict__ snd, const int* __restrict__ rcv,
               int* __restrict__ cursor, int* __restrict__ snd_s, int* __restrict__ rcv_s)
{
    const int e = blockIdx.x * 256 + threadIdx.x;
    if (e < NEDGE) {
        const int r = rcv[e];
        const int p = atomicAdd(&cursor[r], 1);
        snd_s[p] = snd[e];
        rcv_s[p] = r;
    }
}

// ---------------- weight pre-pack: f32 [K][128] -> bf16 fragment-linear ----------------
struct PackArgs {
    int src_off[NMAT];
    int dst_off[NMAT];
    int K[NMAT];
    int nks[NMAT];
};

__global__ __launch_bounds__(256)
void k_pack(const float* __restrict__ cw, u16* __restrict__ wpk, PackArgs pa)
{
    const int mid = blockIdx.y;
    const int nks = pa.nks[mid];
    const int total = nks * 4096;
    const int d = blockIdx.x * 256 + threadIdx.x;
    if (d >= total) return;
    const int j = d & 7, l = (d >> 3) & 63, t = d >> 9;
    const int ks = t % nks, mt = t / nks;
    const int hid = mt * 16 + (l & 15);
    const int k = ks * 32 + (l >> 4) * 8 + j;
    const float v = (k < pa.K[mid]) ? cw[pa.src_off[mid] + k * HD + hid] : 0.0f;
    wpk[pa.dst_off[mid] + d] = f2b(v);
}

// ================= 4-wave (256-thr) MFMA MLP: encoders + node layer =================
template<int NKS, int XROW>
__device__ __forceinline__ void gemm16(const u16* __restrict__ Wp,
                                       const float* __restrict__ Bias,
                                       const u16* __restrict__ x,
                                       f32x4 acc[4][2],
                                       const int wm, const int wn,
                                       const int l15, const int lg, const int lane)
{
#pragma unroll
    for (int mt = 0; mt < 4; mt++) {
        const f32x4 bv = *(const f32x4*)(Bias + wm * 64 + mt * 16 + lg * 4);
        acc[mt][0] = bv;
        acc[mt][1] = bv;
    }
    const u16* xr0 = x + (wn * 32 + l15) * XROW + lg * 8;
    const u16* xr1 = xr0 + 16 * XROW;
    const u16* wp = Wp + (wm * 4 * NKS) * 512 + lane * 8;
#pragma unroll
    for (int ks = 0; ks < NKS; ks++) {
        const short8 b0 = *(const short8*)(xr0 + ks * 32);
        const short8 b1 = *(const short8*)(xr1 + ks * 32);
#pragma unroll
        for (int mt = 0; mt < 4; mt++) {
            const short8 a = *(const short8*)(wp + (mt * NKS + ks) * 512);
            acc[mt][0] = __builtin_amdgcn_mfma_f32_16x16x32_bf16(a, b0, acc[mt][0], 0, 0, 0);
            acc[mt][1] = __builtin_amdgcn_mfma_f32_16x16x32_bf16(a, b1, acc[mt][1], 0, 0, 0);
        }
    }
}

__device__ __forceinline__ void store_h(u16* __restrict__ h, const f32x4 acc[4][2],
                                        const int wm, const int wn, const int l15, const int lg)
{
#pragma unroll
    for (int nt = 0; nt < 2; nt++) {
        const int e = wn * 32 + nt * 16 + l15;
#pragma unroll
        for (int mt = 0; mt < 4; mt++) {
            const int hid = wm * 64 + mt * 16 + lg * 4;
            const f32x4 v = acc[mt][nt];
            const u32 lo = pack2(fmaxf(v[0], 0.0f), fmaxf(v[1], 0.0f));
            const u32 hi = pack2(fmaxf(v[2], 0.0f), fmaxf(v[3], 0.0f));
            *(uint2*)(h + e * 136 + hid) = make_uint2(lo, hi);
        }
    }
}

template<int NKS1, int XROW>
__device__ __forceinline__ void mlp_mfma(const u16* __restrict__ xs,
    u16* __restrict__ h1, u16* __restrict__ h2,
    float (*red)[2][2][16][2],
    const u16* __restrict__ W1p, const float* __restrict__ B1,
    const u16* __restrict__ W2p, const float* __restrict__ B2,
    const u16* __restrict__ W3p, const float* __restrict__ B3,
    const float* __restrict__ g, const float* __restrict__ be,
    float outv[4][2][4],
    const int wm, const int wn, const int l15, const int lg, const int lane)
{
    f32x4 acc[4][2];
    gemm16<NKS1, XROW>(W1p, B1, xs, acc, wm, wn, l15, lg, lane);
    __syncthreads();
    store_h(h1, acc, wm, wn, l15, lg);
    __syncthreads();
    gemm16<4, 136>(W2p, B2, h1, acc, wm, wn, l15, lg, lane);
    store_h(h2, acc, wm, wn, l15, lg);
    __syncthreads();
    gemm16<4, 136>(W3p, B3, h2, acc, wm, wn, l15, lg, lane);
    float ps[2], pss[2];
#pragma unroll
    for (int nt = 0; nt < 2; nt++) {
        float s = 0.0f, ss = 0.0f;
#pragma unroll
        for (int mt = 0; mt < 4; mt++) {
#pragma unroll
            for (int r = 0; r < 4; r++) {
                const float v = acc[mt][nt][r];
                s += v; ss += v * v;
            }
        }
        s += __shfl_xor(s, 16); ss += __shfl_xor(ss, 16);
        s += __shfl_xor(s, 32); ss += __shfl_xor(ss, 32);
        ps[nt] = s; pss[nt] = ss;
    }
    if (lane < 16) {
#pragma unroll
        for (int nt = 0; nt < 2; nt++) {
            red[wm][wn][nt][l15][0] = ps[nt];
            red[wm][wn][nt][l15][1] = pss[nt];
        }
    }
    __syncthreads();
#pragma unroll
    for (int nt = 0; nt < 2; nt++) {
        const float S  = red[0][wn][nt][l15][0] + red[1][wn][nt][l15][0];
        const float SS = red[0][wn][nt][l15][1] + red[1][wn][nt][l15][1];
        const float mu  = S * (1.0f / 128.0f);
        const float var = SS * (1.0f / 128.0f) - mu * mu;
        const float inv = rsqrtf(var + 1e-5f);
#pragma unroll
        for (int mt = 0; mt < 4; mt++) {
            const int hid = wm * 64 + mt * 16 + lg * 4;
            const f32x4 gv  = *(const f32x4*)(g + hid);
            const f32x4 bev = *(const f32x4*)(be + hid);
#pragma unroll
            for (int r = 0; r < 4; r++)
                outv[mt][nt][r] = (acc[mt][nt][r] - mu) * inv * gv[r] + bev[r];
        }
    }
}

// ---------------- node encoder (K=30 padded to 32) ----------------
__device__ __forceinline__ float nfeat(int i, int k,
    const float* __restrict__ vel, const float* __restrict__ pos,
    const float* __restrict__ bounds, const int* __restrict__ ptype,
    const float* __restrict__ emb)
{
    if (k < 10) return vel[i * 10 + k];
    if (k < 14) {
        const int q = k - 10;
        float sub;
        if (q < 2) sub = pos[i * 2 + q] - bounds[q * 2 + 0];
        else       sub = bounds[(q - 2) * 2 + 1] - pos[i * 2 + (q - 2)];
        const float dv = sub * 20.0f;
        return fminf(fmaxf(dv, -1.0f), 1.0f);
    }
    if (k < 30) return emb[ptype[i] * 16 + (k - 14)];
    return 0.0f;
}

__global__ __launch_bounds__(256)
void k_node_enc_m(const float* __restrict__ vel, const float* __restrict__ pos,
                  const float* __restrict__ bounds, const int* __restrict__ ptype,
                  const float* __restrict__ emb,
                  const u16* __restrict__ W1p, const float* __restrict__ B1,
                  const u16* __restrict__ W2p, const float* __restrict__ B2,
                  const u16* __restrict__ W3p, const float* __restrict__ B3,
                  const float* __restrict__ g, const float* __restrict__ be,
                  float* __restrict__ nodes, u16* __restrict__ nodes_bf)
{
    __shared__ __align__(16) u16 lds[17408];
    __shared__ float red[2][2][2][16][2];
    const int tid = threadIdx.x;
    const int i0 = blockIdx.x * 64;
    for (int idx = tid; idx < 1024; idx += 256) {
        const int m = idx >> 4, kk = idx & 15;
        const int i = i0 + m;
        float f0 = 0.0f, f1 = 0.0f;
        if (i < NPART) {
            f0 = nfeat(i, kk * 2 + 0, vel, pos, bounds, ptype, emb);
            f1 = nfeat(i, kk * 2 + 1, vel, pos, bounds, ptype, emb);
        }
        *(u32*)(lds + m * 40 + kk * 2) = pack2(f0, f1);
    }
    __syncthreads();
    const int lane = tid & 63, wv = tid >> 6;
    const int wm = wv >> 1, wn = wv & 1, l15 = lane & 15, lg = lane >> 4;
    float outv[4][2][4];
    mlp_mfma<1, 40>(lds, lds, lds + 8704, red, W1p, B1, W2p, B2, W3p, B3, g, be,
                    outv, wm, wn, l15, lg, lane);
#pragma unroll
    for (int nt = 0; nt < 2; nt++) {
        const int i = i0 + wn * 32 + nt * 16 + l15;
        if (i < NPART) {
#pragma unroll
            for (int mt = 0; mt < 4; mt++) {
                const int hid = wm * 64 + mt * 16 + lg * 4;
                const float4 v = make_float4(outv[mt][nt][0], outv[mt][nt][1],
                                             outv[mt][nt][2], outv[mt][nt][3]);
                *(float4*)(nodes + (size_t)i * HD + hid) = v;
                *(uint2*)(nodes_bf + (size_t)i * HD + hid) =
                    make_uint2(pack2(v.x, v.y), pack2(v.z, v.w));
            }
        }
    }
}

// ------------- edge encoder (K=3 padded to 32), sorted order, bf16 output -------------
__global__ __launch_bounds__(256)
void k_edge_enc_m(const float* __restrict__ pos, const int* __restrict__ snd_s,
                  const int* __restrict__ rcv_s,
                  const u16* __restrict__ W1p, const float* __restrict__ B1,
                  const u16* __restrict__ W2p, const float* __restrict__ B2,
                  const u16* __restrict__ W3p, const float* __restrict__ B3,
                  const float* __restrict__ g, const float* __restrict__ be,
                  u16* __restrict__ edges_bf)
{
    __shared__ __align__(16) u16 lds[17408];
    __shared__ float red[2][2][2][16][2];
    const int tid = threadIdx.x;
    const int e0 = blockIdx.x * 64;
    for (int idx = tid; idx < 1024; idx += 256) {
        const int m = idx >> 4, kk = idx & 15;
        const int e = min(e0 + m, NEDGE - 1);
        u32 w = 0;
        if (kk < 2) {
            const int s = snd_s[e], r = rcv_s[e];
            const float dx = (pos[s * 2 + 0] - pos[r * 2 + 0]) * 20.0f;
            const float dy = (pos[s * 2 + 1] - pos[r * 2 + 1]) * 20.0f;
            if (kk == 0) w = pack2(dx, dy);
            else         w = pack2(sqrtf(dx * dx + dy * dy), 0.0f);
        }
        *(u32*)(lds + m * 40 + kk * 2) = w;
    }
    __syncthreads();
    const int lane = tid & 63, wv = tid >> 6;
    const int wm = wv >> 1, wn = wv & 1, l15 = lane & 15, lg = lane >> 4;
    float outv[4][2][4];
    mlp_mfma<1, 40>(lds, lds, lds + 8704, red, W1p, B1, W2p, B2, W3p, B3, g, be,
                    outv, wm, wn, l15, lg, lane);
#pragma unroll
    for (int nt = 0; nt < 2; nt++) {
        const int e = e0 + wn * 32 + nt * 16 + l15;
        if (e < NEDGE) {
#pragma unroll
            for (int mt = 0; mt < 4; mt++) {
                const int hid = wm * 64 + mt * 16 + lg * 4;
                *(uint2*)(edges_bf + (size_t)e * HD + hid) =
                    make_uint2(pack2(outv[mt][nt][0], outv[mt][nt][1]),
                               pack2(outv[mt][nt][2], outv[mt][nt][3]));
            }
        }
    }
}

// ======= 4-wave (256-thr) 32-row pipelined edge layer, bf16 state, fused agg =======
__device__ __forceinline__ void egemm_seg32(const u16* __restrict__ Wp,
                                            const u16* __restrict__ x,
                                            f32x4 acc[2][2], const int ks0,
                                            const int wm,
                                            const int l15, const int lg, const int lane)
{
    const u16* xr0 = x + l15 * 136 + lg * 8;
    const u16* xr1 = xr0 + 16 * 136;
#pragma unroll
    for (int ks = 0; ks < 4; ks++) {
        const short8 b0 = *(const short8*)(xr0 + ks * 32);
        const short8 b1 = *(const short8*)(xr1 + ks * 32);
#pragma unroll
        for (int mt = 0; mt < 2; mt++) {
            const short8 a = *(const short8*)(Wp + (((wm * 2 + mt) * 12 + ks0 + ks) * 64 + lane) * 8);
            acc[mt][0] = __builtin_amdgcn_mfma_f32_16x16x32_bf16(a, b0, acc[mt][0], 0, 0, 0);
            acc[mt][1] = __builtin_amdgcn_mfma_f32_16x16x32_bf16(a, b1, acc[mt][1], 0, 0, 0);
        }
    }
}

__device__ __forceinline__ void egemm_h32(const u16* __restrict__ Wp,
                                          const float* __restrict__ Bias,
                                          const u16* __restrict__ x,
                                          f32x4 acc[2][2],
                                          const int wm,
                                          const int l15, const int lg, const int lane)
{
#pragma unroll
    for (int mt = 0; mt < 2; mt++) {
        const f32x4 bv = *(const f32x4*)(Bias + wm * 32 + mt * 16 + lg * 4);
        acc[mt][0] = bv;
        acc[mt][1] = bv;
    }
    const u16* xr0 = x + l15 * 136 + lg * 8;
    const u16* xr1 = xr0 + 16 * 136;
#pragma unroll
    for (int ks = 0; ks < 4; ks++) {
        const short8 b0 = *(const short8*)(xr0 + ks * 32);
        const short8 b1 = *(const short8*)(xr1 + ks * 32);
#pragma unroll
        for (int mt = 0; mt < 2; mt++) {
            const short8 a = *(const short8*)(Wp + (((wm * 2 + mt) * 4 + ks) * 64 + lane) * 8);
            acc[mt][0] = __builtin_amdgcn_mfma_f32_16x16x32_bf16(a, b0, acc[mt][0], 0, 0, 0);
            acc[mt][1] = __builtin_amdgcn_mfma_f32_16x16x32_bf16(a, b1, acc[mt][1], 0, 0, 0);
        }
    }
}

__device__ __forceinline__ void estore_h32(u16* __restrict__ h, const f32x4 acc[2][2],
                                           const int wm, const int l15, const int lg)
{
#pragma unroll
    for (int nt = 0; nt < 2; nt++) {
        const int row = nt * 16 + l15;
#pragma unroll
        for (int mt = 0; mt < 2; mt++) {
            const int hid = wm * 32 + mt * 16 + lg * 4;
            const f32x4 v = acc[mt][nt];
            const u32 lo = pack2(fmaxf(v[0], 0.0f), fmaxf(v[1], 0.0f));
            const u32 hi = pack2(fmaxf(v[2], 0.0f), fmaxf(v[3], 0.0f));
            *(uint2*)(h + row * 136 + hid) = make_uint2(lo, hi);
        }
    }
}

__global__ __launch_bounds__(256, 8)
void k_edge_layer_m(const u16* __restrict__ nodes_bf, u16* __restrict__ edges_bf,
                    float* __restrict__ agg,
                    const int* __restrict__ snd_s, const int* __restrict__ rcv_s,
                    const u16* __restrict__ W1p, const float* __restrict__ B1,
                    const u16* __restrict__ W2p, const float* __restrict__ B2,
                    const u16* __restrict__ W3p, const float* __restrict__ B3,
                    const float* __restrict__ g, const float* __restrict__ be)
{
    __shared__ __align__(16) u16 sb[2 * 4352];   // b0,b1: 32x136 bf16; fout overlays
    __shared__ float red[4][2][16][2];
    __shared__ int rblk[34];                     // [0..31] receivers, 32=prev, 33=next
    u16* b0 = sb;
    u16* b1 = sb + 4352;
    float* fout = (float*)sb;                    // 32 rows x stride 132 f32 = 16896B

    const int tid = threadIdx.x;
    const int e0 = blockIdx.x * 32;              // NEDGE/32 = 9375 blocks, exact
    const int lane = tid & 63, wm = tid >> 6;
    const int l15 = lane & 15, lg = lane >> 4;

    if (tid < 32)       rblk[tid] = rcv_s[e0 + tid];
    else if (tid == 32) rblk[32] = (e0 > 0) ? rcv_s[e0 - 1] : -2;
    else if (tid == 33) rblk[33] = (e0 + 32 < NEDGE) ? rcv_s[e0 + 32] : -2;

    // stage seg0 (edge rows, bf16 -> straight copy) into b0; keep old in regs
    uint4 e_old[2];
#pragma unroll
    for (int t = 0; t < 2; t++) {
        const int idx = tid + t * 256;
        const int m = idx >> 4, q = idx & 15;
        e_old[t] = *(const uint4*)(edges_bf + (size_t)(e0 + m) * HD + q * 8);
        *(uint4*)(b0 + m * 136 + q * 8) = e_old[t];
    }
    // issue seg1 (sender rows, bf16) loads -> regs
    uint4 st[2];
#pragma unroll
    for (int t = 0; t < 2; t++) {
        const int idx = tid + t * 256;
        const int m = idx >> 4, q = idx & 15;
        st[t] = *(const uint4*)(nodes_bf + (size_t)snd_s[e0 + m] * HD + q * 8);
    }
    __syncthreads();

    f32x4 acc[2][2];
#pragma unroll
    for (int mt = 0; mt < 2; mt++) {
        const f32x4 bv = *(const f32x4*)(B1 + wm * 32 + mt * 16 + lg * 4);
        acc[mt][0] = bv;
        acc[mt][1] = bv;
    }
    __builtin_amdgcn_s_setprio(1);
    egemm_seg32(W1p, b0, acc, 0, wm, l15, lg, lane);
    __builtin_amdgcn_s_setprio(0);
    // write seg1 -> b1, issue seg2 (receiver rows) loads
#pragma unroll
    for (int t = 0; t < 2; t++) {
        const int idx = tid + t * 256;
        const int m = idx >> 4, q = idx & 15;
        *(uint4*)(b1 + m * 136 + q * 8) = st[t];
    }
#pragma unroll
    for (int t = 0; t < 2; t++) {
        const int idx = tid + t * 256;
        const int m = idx >> 4, q = idx & 15;
        st[t] = *(const uint4*)(nodes_bf + (size_t)rcv_s[e0 + m] * HD + q * 8);
    }
    __syncthreads();

    __builtin_amdgcn_s_setprio(1);
    egemm_seg32(W1p, b1, acc, 4, wm, l15, lg, lane);
    __builtin_amdgcn_s_setprio(0);
#pragma unroll
    for (int t = 0; t < 2; t++) {
        const int idx = tid + t * 256;
        const int m = idx >> 4, q = idx & 15;
        *(uint4*)(b0 + m * 136 + q * 8) = st[t];
    }
    __syncthreads();

    __builtin_amdgcn_s_setprio(1);
    egemm_seg32(W1p, b0, acc, 8, wm, l15, lg, lane);
    __builtin_amdgcn_s_setprio(0);
    estore_h32(b1, acc, wm, l15, lg);      // b1 free: all waves past prev barrier
    __syncthreads();

    __builtin_amdgcn_s_setprio(1);
    egemm_h32(W2p, B2, b1, acc, wm, l15, lg, lane);
    __builtin_amdgcn_s_setprio(0);
    estore_h32(b0, acc, wm, l15, lg);      // b0 free
    __syncthreads();

    __builtin_amdgcn_s_setprio(1);
    egemm_h32(W3p, B3, b0, acc, wm, l15, lg, lane);
    __builtin_amdgcn_s_setprio(0);

    // ---- layernorm reduction ----
    float ps[2], pss[2];
#pragma unroll
    for (int nt = 0; nt < 2; nt++) {
        float s = 0.0f, ss = 0.0f;
#pragma unroll
        for (int mt = 0; mt < 2; mt++) {
#pragma unroll
            for (int r = 0; r < 4; r++) {
                const float v = acc[mt][nt][r];
                s += v; ss += v * v;
            }
        }
        s += __shfl_xor(s, 16); ss += __shfl_xor(ss, 16);
        s += __shfl_xor(s, 32); ss += __shfl_xor(ss, 32);
        ps[nt] = s; pss[nt] = ss;
    }
    if (lane < 16) {
#pragma unroll
        for (int nt = 0; nt < 2; nt++) {
            red[wm][nt][l15][0] = ps[nt];
            red[wm][nt][l15][1] = pss[nt];
        }
    }
    __syncthreads();   // red ready; all waves past GEMM3 -> b0/b1 dead, fout may overlay

    // ---- LN apply -> fout (f32, stride 132) ----
#pragma unroll
    for (int nt = 0; nt < 2; nt++) {
        const float S  = red[0][nt][l15][0] + red[1][nt][l15][0]
                       + red[2][nt][l15][0] + red[3][nt][l15][0];
        const float SS = red[0][nt][l15][1] + red[1][nt][l15][1]
                       + red[2][nt][l15][1] + red[3][nt][l15][1];
        const float mu  = S * (1.0f / 128.0f);
        const float var = SS * (1.0f / 128.0f) - mu * mu;
        const float inv = rsqrtf(var + 1e-5f);
        const int row = nt * 16 + l15;
#pragma unroll
        for (int mt = 0; mt < 2; mt++) {
            const int hid = wm * 32 + mt * 16 + lg * 4;
            const f32x4 gv  = *(const f32x4*)(g + hid);
            const f32x4 bev = *(const f32x4*)(be + hid);
            f32x4 o;
#pragma unroll
            for (int r = 0; r < 4; r++)
                o[r] = (acc[mt][nt][r] - mu) * inv * gv[r] + bev[r];
            *(f32x4*)(fout + row * 132 + hid) = o;
        }
    }
    __syncthreads();

    // ---- writer: new = b2f(old regs) + ln; bf16 row write; new(f32) -> fout ----
#pragma unroll
    for (int t = 0; t < 2; t++) {
        const int idx = tid + t * 256;
        const int m = idx >> 4, q = idx & 15;
        float4 lo = *(const float4*)(fout + m * 132 + q * 8);
        float4 hi = *(const float4*)(fout + m * 132 + q * 8 + 4);
        const uint4 o = e_old[t];
        lo.x += b2flo(o.x); lo.y += b2fhi(o.x);
        lo.z += b2flo(o.y); lo.w += b2fhi(o.y);
        hi.x += b2flo(o.z); hi.y += b2fhi(o.z);
        hi.z += b2flo(o.w); hi.w += b2fhi(o.w);
        *(float4*)(fout + m * 132 + q * 8) = lo;
        *(float4*)(fout + m * 132 + q * 8 + 4) = hi;
        *(uint4*)(edges_bf + (size_t)(e0 + m) * HD + q * 8) =
            make_uint4(pack2(lo.x, lo.y), pack2(lo.z, lo.w),
                       pack2(hi.x, hi.y), pack2(hi.z, hi.w));
    }
    __syncthreads();

    // ---- fused aggregation: per-receiver run sums from fout -> agg (f32) ----
    const int c = tid & 31;              // float4 chunk 0..31
    for (int ms = (tid >> 5); ms < 32; ms += 8) {
        const int rs = rblk[ms];
        if (ms > 0 && rblk[ms - 1] == rs) continue;   // not a run start
        int me = ms + 1;
        while (me < 32 && rblk[me] == rs) me++;
        float4 s = make_float4(0.0f, 0.0f, 0.0f, 0.0f);
        for (int m = ms; m < me; m++) {
            const float4 v = *(const float4*)(fout + m * 132 + c * 4);
            s.x += v.x; s.y += v.y; s.z += v.z; s.w += v.w;
        }
        float* ap = agg + (size_t)rs * HD + c * 4;
        const bool bnd = (ms == 0 && rblk[32] == rs) || (me == 32 && rblk[33] == rs);
        if (bnd) {
            atomicAdd(ap + 0, s.x); atomicAdd(ap + 1, s.y);
            atomicAdd(ap + 2, s.z); atomicAdd(ap + 3, s.w);
        } else {
            *(float4*)ap = s;
        }
    }
}

// ------- per-layer node update (K=256); reads agg and re-zeroes it for next layer -------
__global__ __launch_bounds__(256)
void k_node_layer_m(float* __restrict__ nodes, u16* __restrict__ nodes_bf,
                    float* __restrict__ agg,
                    const u16* __restrict__ W1p, const float* __restrict__ B1,
                    const u16* __restrict__ W2p, const float* __restrict__ B2,
                    const u16* __restrict__ W3p, const float* __restrict__ B3,
                    const float* __restrict__ g, const float* __restrict__ be)
{
    __shared__ __align__(16) u16 lds[17408];
    __shared__ float red[2][2][2][16][2];
    const int tid = threadIdx.x;
    const int i0 = blockIdx.x * 64;
    for (int idx = tid; idx < 1024; idx += 256) {
        const int m = idx >> 4, q = idx & 15;
        const int i = min(i0 + m, NPART - 1);
        const float* src = nodes + (size_t)i * HD + q * 8;
        const float4 a = *(const float4*)(src);
        const float4 b = *(const float4*)(src + 4);
        *(uint4*)(lds + m * 264 + q * 8) =
            make_uint4(pack2(a.x, a.y), pack2(a.z, a.w), pack2(b.x, b.y), pack2(b.z, b.w));
    }
    const float4 z4 = make_float4(0.0f, 0.0f, 0.0f, 0.0f);
    for (int idx = tid; idx < 1024; idx += 256) {
        const int m = idx >> 4, q = idx & 15;
        const int i = min(i0 + m, NPART - 1);
        float* src = agg + (size_t)i * HD + q * 8;
        const float4 a = *(const float4*)(src);
        const float4 b = *(const float4*)(src + 4);
        *(uint4*)(lds + m * 264 + 128 + q * 8) =
            make_uint4(pack2(a.x, a.y), pack2(a.z, a.w), pack2(b.x, b.y), pack2(b.z, b.w));
        *(float4*)(src) = z4;                    // zero for next layer (own rows only)
        *(float4*)(src + 4) = z4;
    }
    __syncthreads();
    const int lane = tid & 63, wv = tid >> 6;
    const int wm = wv >> 1, wn = wv & 1, l15 = lane & 15, lg = lane >> 4;
    float outv[4][2][4];
    mlp_mfma<8, 264>(lds, lds, lds + 8704, red, W1p, B1, W2p, B2, W3p, B3, g, be,
                     outv, wm, wn, l15, lg, lane);
#pragma unroll
    for (int nt = 0; nt < 2; nt++) {
        const int i = i0 + wn * 32 + nt * 16 + l15;
        if (i < NPART) {
            float* np = nodes + (size_t)i * HD;
#pragma unroll
            for (int mt = 0; mt < 4; mt++) {
                const int hid = wm * 64 + mt * 16 + lg * 4;
                const float4 old = *(const float4*)(np + hid);
                const float4 nv = make_float4(old.x + outv[mt][nt][0],
                                              old.y + outv[mt][nt][1],
                                              old.z + outv[mt][nt][2],
                                              old.w + outv[mt][nt][3]);
                *(float4*)(np + hid) = nv;
                *(uint2*)(nodes_bf + (size_t)i * HD + hid) =
                    make_uint2(pack2(nv.x, nv.y), pack2(nv.z, nv.w));
            }
        }
    }
}

// ---------------- fp32 gemv for decoder ----------------
template<int K, int S>
__device__ __forceinline__ void gemv(const float* __restrict__ in,
                                     const float* __restrict__ W,
                                     const float* __restrict__ B,
                                     float acc[8])
{
    const int j = threadIdx.x;
    const float bb = B[j];
#pragma unroll
    for (int m = 0; m < 8; m++) acc[m] = bb;
    constexpr int K4 = (K / 4) * 4;
    for (int k = 0; k < K4; k += 4) {
        const float w0 = W[(k + 0) * HD + j];
        const float w1 = W[(k + 1) * HD + j];
        const float w2 = W[(k + 2) * HD + j];
        const float w3 = W[(k + 3) * HD + j];
#pragma unroll
        for (int m = 0; m < 8; m++) {
            const float4 x = *(const float4*)(in + m * S + k);
            float a = acc[m];
            a = fmaf(x.x, w0, a);
            a = fmaf(x.y, w1, a);
            a = fmaf(x.z, w2, a);
            a = fmaf(x.w, w3, a);
            acc[m] = a;
        }
    }
#pragma unroll
    for (int k = K4; k < K; k++) {
        const float w = W[k * HD + j];
#pragma unroll
        for (int m = 0; m < 8; m++) acc[m] = fmaf(in[m * S + k], w, acc[m]);
    }
}

// ---------------- decoder + Euler integration (dual output dtype) ----------------
__global__ __launch_bounds__(128)
void k_decoder(const float* __restrict__ nodes,
               const float* W1, const float* B1, const float* W2, const float* B2,
               const float* W3, const float* B3,
               const float* __restrict__ vel, const float* __restrict__ pos,
               const float* __restrict__ tgt, const int* __restrict__ nonk,
               const unsigned short* __restrict__ braw, void* __restrict__ d_out)
{
    __shared__ __align__(16) float xs[8 * HD];
    __shared__ __align__(16) float h1[8 * HD];
    __shared__ __align__(16) float h2[8 * HD];
    const int j = threadIdx.x;
    const int i0 = blockIdx.x * 8;
    float acc[8];
#pragma unroll
    for (int m = 0; m < 8; m++) xs[m * HD + j] = nodes[(i0 + m) * HD + j];
    __syncthreads();
    gemv<HD, HD>(xs, W1, B1, acc);
#pragma unroll
    for (int m = 0; m < 8; m++) h1[m * HD + j] = fmaxf(acc[m], 0.0f);
    __syncthreads();
    gemv<HD, HD>(h1, W2, B2, acc);
#pragma unroll
    for (int m = 0; m < 8; m++) h2[m * HD + j] = fmaxf(acc[m], 0.0f);
    __syncthreads();
    if (j < 16) {
        const int m = j >> 1, d = j & 1, i = i0 + m;
        float a = B3[d];
        for (int k = 0; k < HD; k++) a = fmaf(h2[m * HD + k], W3[k * 2 + d], a);
        float pp = pos[i * 2 + d] + vel[i * 10 + 8 + d] + a;
        if (nonk[i] == 0) pp = tgt[i * 2 + d];
        if (detect_bf16(braw)) {
            bf16* o = (bf16*)d_out;
            o[i * 2 + d] = __float2bfloat16(a);
            o[2 * NPART + i * 2 + d] = __float2bfloat16(pp);
        } else {
            float* o = (float*)d_out;
            o[i * 2 + d] = a;
            o[2 * NPART + i * 2 + d] = pp;
        }
    }
}

extern "C" void kernel_launch(void* const* d_in, const int* in_sizes, int n_in,
                              void* d_out, int out_size, void* d_ws, size_t ws_size,
                              hipStream_t stream)
{
    const int* ptype = (const int*)d_in[4];
    const int* nonk  = (const int*)d_in[5];
    const int* snd   = (const int*)d_in[6];
    const int* rcv   = (const int*)d_in[7];
    const unsigned short* braw = (const unsigned short*)d_in[2];

    int fmap[NFLOAT_ARRAYS];
    {
        int c = 0;
        fmap[c++] = 0; fmap[c++] = 1; fmap[c++] = 2; fmap[c++] = 3; fmap[c++] = 8;
        for (int i = 9; i <= 46; i++) fmap[c++] = i;
    }
    ConvArgs ca;
    const float* fp[47];
    float* cw = (float*)d_ws;
    int off = 0;
    for (int i = 0; i < NFLOAT_ARRAYS; i++) {
        ca.src[i] = d_in[fmap[i]];
        ca.n[i]   = in_sizes[fmap[i]];
        ca.off[i] = off;
        fp[fmap[i]] = cw + off;
        off += in_sizes[fmap[i]];
    }
    // workspace: f32 node state + agg + bf16 edge state + bf16 node mirror + weights
    float* nodes = cw + ((off + 3) & ~3);
    float* agg   = nodes + (size_t)NPART * HD;
    u16* edges_bf = (u16*)(agg + (size_t)NPART * HD);
    u16* nodes_bf = edges_bf + (size_t)NEDGE * HD;
    u16* wpk = nodes_bf + (size_t)NPART * HD;

    // build pack table (order: ne x3, ee x3, ge x30, gn x30)
    PackArgs pa;
    int dst = 0, c = 0;
    int pk[NMAT];
    auto addm = [&](long srcoff, int K) {
        const int nk = (K + 31) / 32;
        pa.src_off[c] = (int)srcoff;
        pa.K[c] = K;
        pa.nks[c] = nk;
        pa.dst_off[c] = dst;
        pk[c] = dst;
        dst += nk * 4096;
        c++;
    };
    addm(fp[9]  - cw, 30);  addm(fp[11] - cw, 128); addm(fp[13] - cw, 128);
    addm(fp[17] - cw, 3);   addm(fp[19] - cw, 128); addm(fp[21] - cw, 128);
    for (int l = 0; l < NLAYER; l++) {
        addm(fp[25] - cw + (long)l * 384 * HD, 384);
        addm(fp[27] - cw + (long)l * HD * HD, 128);
        addm(fp[29] - cw + (long)l * HD * HD, 128);
    }
    for (int l = 0; l < NLAYER; l++) {
        addm(fp[33] - cw + (long)l * 256 * HD, 256);
        addm(fp[35] - cw + (long)l * HD * HD, 128);
        addm(fp[37] - cw + (long)l * HD * HD, 128);
    }

    int* ip = (int*)(wpk + ((dst + 7) & ~7));
    int* row_ptr = ip;            ip += NPART + 8;
    int* cursor  = ip;            ip += NPART;
    int* counts  = ip;            ip += NPART;
    int* snd_s   = ip;            ip += NEDGE;
    int* rcv_s   = ip;

    const int EBL = (NEDGE + 255) / 256;

    k_convert<<<dim3(64, NFLOAT_ARRAYS), 256, 0, stream>>>(ca, cw, braw);
    hipMemsetAsync(counts, 0, (size_t)NPART * sizeof(int), stream);
    hipMemsetAsync(agg, 0, (size_t)NPART * HD * sizeof(float), stream);
    k_hist<<<EBL, 256, 0, stream>>>(rcv, counts);
    k_scan<<<1, 1024, 0, stream>>>(counts, row_ptr, cursor);
    k_scatter<<<EBL, 256, 0, stream>>>(snd, rcv, cursor, snd_s, rcv_s);
    k_pack<<<dim3(192, NMAT), 256, 0, stream>>>(cw, wpk, pa);

    const int NB = (NPART + 63) / 64;   // 469
    const int EB = (NEDGE + 63) / 64;   // 4688 (encoder)
    const int EB32 = NEDGE / 32;        // 9375 (edge layer, exact)

    k_node_enc_m<<<NB, 256, 0, stream>>>(fp[0], fp[1], fp[2], ptype, fp[8],
        wpk + pk[0], fp[10], wpk + pk[1], fp[12], wpk + pk[2], fp[14],
        fp[15], fp[16], nodes, nodes_bf);
    k_edge_enc_m<<<EB, 256, 0, stream>>>(fp[1], snd_s, rcv_s,
        wpk + pk[3], fp[18], wpk + pk[4], fp[20], wpk + pk[5], fp[22],
        fp[23], fp[24], edges_bf);

    for (int l = 0; l < NLAYER; l++) {
        k_edge_layer_m<<<EB32, 256, 0, stream>>>(nodes_bf, edges_bf, agg, snd_s, rcv_s,
            wpk + pk[6 + 3 * l],  fp[26] + (size_t)l * HD,
            wpk + pk[7 + 3 * l],  fp[28] + (size_t)l * HD,
            wpk + pk[8 + 3 * l],  fp[30] + (size_t)l * HD,
            fp[31] + (size_t)l * HD, fp[32] + (size_t)l * HD);
        k_node_layer_m<<<NB, 256, 0, stream>>>(nodes, nodes_bf, agg,
            wpk + pk[36 + 3 * l], fp[34] + (size_t)l * HD,
            wpk + pk[37 + 3 * l], fp[36] + (size_t)l * HD,
            wpk + pk[38 + 3 * l], fp[38] + (size_t)l * HD,
            fp[39] + (size_t)l * HD, fp[40] + (size_t)l * HD);
    }

    k_decoder<<<NPART / 8, 128, 0, stream>>>(nodes,
        fp[41], fp[42], fp[43], fp[44], fp[45], fp[46],
        fp[0], fp[1], fp[3], nonk, braw, d_out);
}

// Round 7
// 2206.661 us; speedup vs baseline: 6.6053x; 1.0058x over previous
//
#include <hip/hip_runtime.h>
#include <hip/hip_bf16.h>

typedef __hip_bfloat16 bf16;
typedef unsigned short u16;
typedef unsigned int u32;
typedef __attribute__((ext_vector_type(8))) short short8;
typedef __attribute__((ext_vector_type(4))) float f32x4;

#define NPART 30000
#define NEDGE 300000
#define HD 128
#define NLAYER 10
#define NFLOAT_ARRAYS 43
#define NMAT 66

// ---------------- dtype detect ----------------
__device__ __forceinline__ bool detect_bf16(const unsigned short* braw) {
    return braw[1] == 0x3F80u;
}

// ---------------- fp32<->bf16 helpers (RNE) ----------------
__device__ __forceinline__ u16 f2b(float f) {
    u32 u = __float_as_uint(f);
    u += 0x7FFFu + ((u >> 16) & 1u);
    return (u16)(u >> 16);
}
__device__ __forceinline__ u32 pack2(float a, float b) {
    return (u32)f2b(a) | ((u32)f2b(b) << 16);
}
__device__ __forceinline__ float b2flo(u32 u) { return __uint_as_float(u << 16); }
__device__ __forceinline__ float b2fhi(u32 u) { return __uint_as_float(u & 0xFFFF0000u); }

// ---------------- convert all float arrays to canonical fp32 ----------------
struct ConvArgs {
    const void* src[NFLOAT_ARRAYS];
    int n[NFLOAT_ARRAYS];
    int off[NFLOAT_ARRAYS];
};

__global__ __launch_bounds__(256)
void k_convert(ConvArgs a, float* __restrict__ dst, const unsigned short* __restrict__ braw)
{
    const bool isb = detect_bf16(braw);
    const int aid = blockIdx.y;
    const int n = a.n[aid];
    float* o = dst + a.off[aid];
    const int stride = gridDim.x * 256;
    int i = blockIdx.x * 256 + threadIdx.x;
    if (isb) {
        const unsigned short* s = (const unsigned short*)a.src[aid];
        for (; i < n; i += stride) {
            const unsigned int u = ((unsigned int)s[i]) << 16;
            o[i] = __uint_as_float(u);
        }
    } else {
        const float* s = (const float*)a.src[aid];
        for (; i < n; i += stride) o[i] = s[i];
    }
}

// ---------------- counting sort of edges by receiver ----------------
__global__ __launch_bounds__(256)
void k_hist(const int* __restrict__ rcv, int* __restrict__ counts)
{
    const int e = blockIdx.x * 256 + threadIdx.x;
    if (e < NEDGE) atomicAdd(&counts[rcv[e]], 1);
}

__global__ __launch_bounds__(1024)
void k_scan(const int* __restrict__ counts, int* __restrict__ row_ptr, int* __restrict__ cursor)
{
    __shared__ int part[1024];
    const int t = threadIdx.x;
    const int base = t * 32;
    int local[32];
    int s = 0;
#pragma unroll
    for (int k = 0; k < 32; k++) {
        const int idx = base + k;
        const int v = (idx < NPART) ? counts[idx] : 0;
        local[k] = s;
        s += v;
    }
    part[t] = s;
    __syncthreads();
    for (int off = 1; off < 1024; off <<= 1) {
        const int v = (t >= off) ? part[t - off] : 0;
        __syncthreads();
        part[t] += v;
        __syncthreads();
    }
    const int excl = (t == 0) ? 0 : part[t - 1];
#pragma unroll
    for (int k = 0; k < 32; k++) {
        const int idx = base + k;
        if (idx < NPART) {
            const int rp = excl + local[k];
            row_ptr[idx] = rp;
            cursor[idx] = rp;
        }
    }
    if (t == 0) row_ptr[NPART] = NEDGE;
}

__global__ __launch_bounds__(256)
void k_scatter(const int* __restrict__ snd, const int* __restrict__ rcv,
               int* __restrict__ cursor, int* __restrict__ snd_s, int* __restrict__ rcv_s)
{
    const int e = blockIdx.x * 256 + threadIdx.x;
    if (e < NEDGE) {
        const int r = rcv[e];
        const int p = atomicAdd(&cursor[r], 1);
        snd_s[p] = snd[e];
        rcv_s[p] = r;
    }
}

// ---------------- weight pre-pack: f32 [K][128] -> bf16 fragment-linear ----------------
struct PackArgs {
    int src_off[NMAT];
    int dst_off[NMAT];
    int K[NMAT];
    int nks[NMAT];
};

__global__ __launch_bounds__(256)
void k_pack(const float* __restrict__ cw, u16* __restrict__ wpk, PackArgs pa)
{
    const int mid = blockIdx.y;
    const int nks = pa.nks[mid];
    const int total = nks * 4096;
    const int d = blockIdx.x * 256 + threadIdx.x;
    if (d >= total) return;
    const int j = d & 7, l = (d >> 3) & 63, t = d >> 9;
    const int ks = t % nks, mt = t / nks;
    const int hid = mt * 16 + (l & 15);
    const int k = ks * 32 + (l >> 4) * 8 + j;
    const float v = (k < pa.K[mid]) ? cw[pa.src_off[mid] + k * HD + hid] : 0.0f;
    wpk[pa.dst_off[mid] + d] = f2b(v);
}

// ================= 4-wave (256-thr) MFMA MLP: encoders + node layer =================
template<int NKS, int XROW>
__device__ __forceinline__ void gemm16(const u16* __restrict__ Wp,
                                       const float* __restrict__ Bias,
                                       const u16* __restrict__ x,
                                       f32x4 acc[4][2],
                                       const int wm, const int wn,
                                       const int l15, const int lg, const int lane)
{
#pragma unroll
    for (int mt = 0; mt < 4; mt++) {
        const f32x4 bv = *(const f32x4*)(Bias + wm * 64 + mt * 16 + lg * 4);
        acc[mt][0] = bv;
        acc[mt][1] = bv;
    }
    const u16* xr0 = x + (wn * 32 + l15) * XROW + lg * 8;
    const u16* xr1 = xr0 + 16 * XROW;
    const u16* wp = Wp + (wm * 4 * NKS) * 512 + lane * 8;
#pragma unroll
    for (int ks = 0; ks < NKS; ks++) {
        const short8 b0 = *(const short8*)(xr0 + ks * 32);
        const short8 b1 = *(const short8*)(xr1 + ks * 32);
#pragma unroll
        for (int mt = 0; mt < 4; mt++) {
            const short8 a = *(const short8*)(wp + (mt * NKS + ks) * 512);
            acc[mt][0] = __builtin_amdgcn_mfma_f32_16x16x32_bf16(a, b0, acc[mt][0], 0, 0, 0);
            acc[mt][1] = __builtin_amdgcn_mfma_f32_16x16x32_bf16(a, b1, acc[mt][1], 0, 0, 0);
        }
    }
}

__device__ __forceinline__ void store_h(u16* __restrict__ h, const f32x4 acc[4][2],
                                        const int wm, const int wn, const int l15, const int lg)
{
#pragma unroll
    for (int nt = 0; nt < 2; nt++) {
        const int e = wn * 32 + nt * 16 + l15;
#pragma unroll
        for (int mt = 0; mt < 4; mt++) {
            const int hid = wm * 64 + mt * 16 + lg * 4;
            const f32x4 v = acc[mt][nt];
            const u32 lo = pack2(fmaxf(v[0], 0.0f), fmaxf(v[1], 0.0f));
            const u32 hi = pack2(fmaxf(v[2], 0.0f), fmaxf(v[3], 0.0f));
            *(uint2*)(h + e * 136 + hid) = make_uint2(lo, hi);
        }
    }
}

template<int NKS1, int XROW>
__device__ __forceinline__ void mlp_mfma(const u16* __restrict__ xs,
    u16* __restrict__ h1, u16* __restrict__ h2,
    float (*red)[2][2][16][2],
    const u16* __restrict__ W1p, const float* __restrict__ B1,
    const u16* __restrict__ W2p, const float* __restrict__ B2,
    const u16* __restrict__ W3p, const float* __restrict__ B3,
    const float* __restrict__ g, const float* __restrict__ be,
    float outv[4][2][4],
    const int wm, const int wn, const int l15, const int lg, const int lane)
{
    f32x4 acc[4][2];
    gemm16<NKS1, XROW>(W1p, B1, xs, acc, wm, wn, l15, lg, lane);
    __syncthreads();
    store_h(h1, acc, wm, wn, l15, lg);
    __syncthreads();
    gemm16<4, 136>(W2p, B2, h1, acc, wm, wn, l15, lg, lane);
    store_h(h2, acc, wm, wn, l15, lg);
    __syncthreads();
    gemm16<4, 136>(W3p, B3, h2, acc, wm, wn, l15, lg, lane);
    float ps[2], pss[2];
#pragma unroll
    for (int nt = 0; nt < 2; nt++) {
        float s = 0.0f, ss = 0.0f;
#pragma unroll
        for (int mt = 0; mt < 4; mt++) {
#pragma unroll
            for (int r = 0; r < 4; r++) {
                const float v = acc[mt][nt][r];
                s += v; ss += v * v;
            }
        }
        s += __shfl_xor(s, 16); ss += __shfl_xor(ss, 16);
        s += __shfl_xor(s, 32); ss += __shfl_xor(ss, 32);
        ps[nt] = s; pss[nt] = ss;
    }
    if (lane < 16) {
#pragma unroll
        for (int nt = 0; nt < 2; nt++) {
            red[wm][wn][nt][l15][0] = ps[nt];
            red[wm][wn][nt][l15][1] = pss[nt];
        }
    }
    __syncthreads();
#pragma unroll
    for (int nt = 0; nt < 2; nt++) {
        const float S  = red[0][wn][nt][l15][0] + red[1][wn][nt][l15][0];
        const float SS = red[0][wn][nt][l15][1] + red[1][wn][nt][l15][1];
        const float mu  = S * (1.0f / 128.0f);
        const float var = SS * (1.0f / 128.0f) - mu * mu;
        const float inv = rsqrtf(var + 1e-5f);
#pragma unroll
        for (int mt = 0; mt < 4; mt++) {
            const int hid = wm * 64 + mt * 16 + lg * 4;
            const f32x4 gv  = *(const f32x4*)(g + hid);
            const f32x4 bev = *(const f32x4*)(be + hid);
#pragma unroll
            for (int r = 0; r < 4; r++)
                outv[mt][nt][r] = (acc[mt][nt][r] - mu) * inv * gv[r] + bev[r];
        }
    }
}

// ---------------- node encoder (K=30 padded to 32) ----------------
__device__ __forceinline__ float nfeat(int i, int k,
    const float* __restrict__ vel, const float* __restrict__ pos,
    const float* __restrict__ bounds, const int* __restrict__ ptype,
    const float* __restrict__ emb)
{
    if (k < 10) return vel[i * 10 + k];
    if (k < 14) {
        const int q = k - 10;
        float sub;
        if (q < 2) sub = pos[i * 2 + q] - bounds[q * 2 + 0];
        else       sub = bounds[(q - 2) * 2 + 1] - pos[i * 2 + (q - 2)];
        const float dv = sub * 20.0f;
        return fminf(fmaxf(dv, -1.0f), 1.0f);
    }
    if (k < 30) return emb[ptype[i] * 16 + (k - 14)];
    return 0.0f;
}

__global__ __launch_bounds__(256)
void k_node_enc_m(const float* __restrict__ vel, const float* __restrict__ pos,
                  const float* __restrict__ bounds, const int* __restrict__ ptype,
                  const float* __restrict__ emb,
                  const u16* __restrict__ W1p, const float* __restrict__ B1,
                  const u16* __restrict__ W2p, const float* __restrict__ B2,
                  const u16* __restrict__ W3p, const float* __restrict__ B3,
                  const float* __restrict__ g, const float* __restrict__ be,
                  float* __restrict__ nodes, u16* __restrict__ nodes_bf)
{
    __shared__ __align__(16) u16 lds[17408];
    __shared__ float red[2][2][2][16][2];
    const int tid = threadIdx.x;
    const int i0 = blockIdx.x * 64;
    for (int idx = tid; idx < 1024; idx += 256) {
        const int m = idx >> 4, kk = idx & 15;
        const int i = i0 + m;
        float f0 = 0.0f, f1 = 0.0f;
        if (i < NPART) {
            f0 = nfeat(i, kk * 2 + 0, vel, pos, bounds, ptype, emb);
            f1 = nfeat(i, kk * 2 + 1, vel, pos, bounds, ptype, emb);
        }
        *(u32*)(lds + m * 40 + kk * 2) = pack2(f0, f1);
    }
    __syncthreads();
    const int lane = tid & 63, wv = tid >> 6;
    const int wm = wv >> 1, wn = wv & 1, l15 = lane & 15, lg = lane >> 4;
    float outv[4][2][4];
    mlp_mfma<1, 40>(lds, lds, lds + 8704, red, W1p, B1, W2p, B2, W3p, B3, g, be,
                    outv, wm, wn, l15, lg, lane);
#pragma unroll
    for (int nt = 0; nt < 2; nt++) {
        const int i = i0 + wn * 32 + nt * 16 + l15;
        if (i < NPART) {
#pragma unroll
            for (int mt = 0; mt < 4; mt++) {
                const int hid = wm * 64 + mt * 16 + lg * 4;
                const float4 v = make_float4(outv[mt][nt][0], outv[mt][nt][1],
                                             outv[mt][nt][2], outv[mt][nt][3]);
                *(float4*)(nodes + (size_t)i * HD + hid) = v;
                *(uint2*)(nodes_bf + (size_t)i * HD + hid) =
                    make_uint2(pack2(v.x, v.y), pack2(v.z, v.w));
            }
        }
    }
}

// ------------- edge encoder (K=3 padded to 32), sorted order, bf16 output -------------
__global__ __launch_bounds__(256)
void k_edge_enc_m(const float* __restrict__ pos, const int* __restrict__ snd_s,
                  const int* __restrict__ rcv_s,
                  const u16* __restrict__ W1p, const float* __restrict__ B1,
                  const u16* __restrict__ W2p, const float* __restrict__ B2,
                  const u16* __restrict__ W3p, const float* __restrict__ B3,
                  const float* __restrict__ g, const float* __restrict__ be,
                  u16* __restrict__ edges_bf)
{
    __shared__ __align__(16) u16 lds[17408];
    __shared__ float red[2][2][2][16][2];
    const int tid = threadIdx.x;
    const int e0 = blockIdx.x * 64;
    for (int idx = tid; idx < 1024; idx += 256) {
        const int m = idx >> 4, kk = idx & 15;
        const int e = min(e0 + m, NEDGE - 1);
        u32 w = 0;
        if (kk < 2) {
            const int s = snd_s[e], r = rcv_s[e];
            const float dx = (pos[s * 2 + 0] - pos[r * 2 + 0]) * 20.0f;
            const float dy = (pos[s * 2 + 1] - pos[r * 2 + 1]) * 20.0f;
            if (kk == 0) w = pack2(dx, dy);
            else         w = pack2(sqrtf(dx * dx + dy * dy), 0.0f);
        }
        *(u32*)(lds + m * 40 + kk * 2) = w;
    }
    __syncthreads();
    const int lane = tid & 63, wv = tid >> 6;
    const int wm = wv >> 1, wn = wv & 1, l15 = lane & 15, lg = lane >> 4;
    float outv[4][2][4];
    mlp_mfma<1, 40>(lds, lds, lds + 8704, red, W1p, B1, W2p, B2, W3p, B3, g, be,
                    outv, wm, wn, l15, lg, lane);
#pragma unroll
    for (int nt = 0; nt < 2; nt++) {
        const int e = e0 + wn * 32 + nt * 16 + l15;
        if (e < NEDGE) {
#pragma unroll
            for (int mt = 0; mt < 4; mt++) {
                const int hid = wm * 64 + mt * 16 + lg * 4;
                *(uint2*)(edges_bf + (size_t)e * HD + hid) =
                    make_uint2(pack2(outv[mt][nt][0], outv[mt][nt][1]),
                               pack2(outv[mt][nt][2], outv[mt][nt][3]));
            }
        }
    }
}

// ======= 4-wave (256-thr) 32-row pipelined edge layer, bf16 state, private agg =======
__device__ __forceinline__ void egemm_seg32(const u16* __restrict__ Wp,
                                            const u16* __restrict__ x,
                                            f32x4 acc[2][2], const int ks0,
                                            const int wm,
                                            const int l15, const int lg, const int lane)
{
    const u16* xr0 = x + l15 * 136 + lg * 8;
    const u16* xr1 = xr0 + 16 * 136;
#pragma unroll
    for (int ks = 0; ks < 4; ks++) {
        const short8 b0 = *(const short8*)(xr0 + ks * 32);
        const short8 b1 = *(const short8*)(xr1 + ks * 32);
#pragma unroll
        for (int mt = 0; mt < 2; mt++) {
            const short8 a = *(const short8*)(Wp + (((wm * 2 + mt) * 12 + ks0 + ks) * 64 + lane) * 8);
            acc[mt][0] = __builtin_amdgcn_mfma_f32_16x16x32_bf16(a, b0, acc[mt][0], 0, 0, 0);
            acc[mt][1] = __builtin_amdgcn_mfma_f32_16x16x32_bf16(a, b1, acc[mt][1], 0, 0, 0);
        }
    }
}

__device__ __forceinline__ void egemm_h32(const u16* __restrict__ Wp,
                                          const float* __restrict__ Bias,
                                          const u16* __restrict__ x,
                                          f32x4 acc[2][2],
                                          const int wm,
                                          const int l15, const int lg, const int lane)
{
#pragma unroll
    for (int mt = 0; mt < 2; mt++) {
        const f32x4 bv = *(const f32x4*)(Bias + wm * 32 + mt * 16 + lg * 4);
        acc[mt][0] = bv;
        acc[mt][1] = bv;
    }
    const u16* xr0 = x + l15 * 136 + lg * 8;
    const u16* xr1 = xr0 + 16 * 136;
#pragma unroll
    for (int ks = 0; ks < 4; ks++) {
        const short8 b0 = *(const short8*)(xr0 + ks * 32);
        const short8 b1 = *(const short8*)(xr1 + ks * 32);
#pragma unroll
        for (int mt = 0; mt < 2; mt++) {
            const short8 a = *(const short8*)(Wp + (((wm * 2 + mt) * 4 + ks) * 64 + lane) * 8);
            acc[mt][0] = __builtin_amdgcn_mfma_f32_16x16x32_bf16(a, b0, acc[mt][0], 0, 0, 0);
            acc[mt][1] = __builtin_amdgcn_mfma_f32_16x16x32_bf16(a, b1, acc[mt][1], 0, 0, 0);
        }
    }
}

__device__ __forceinline__ void estore_h32(u16* __restrict__ h, const f32x4 acc[2][2],
                                           const int wm, const int l15, const int lg)
{
#pragma unroll
    for (int nt = 0; nt < 2; nt++) {
        const int row = nt * 16 + l15;
#pragma unroll
        for (int mt = 0; mt < 2; mt++) {
            const int hid = wm * 32 + mt * 16 + lg * 4;
            const f32x4 v = acc[mt][nt];
            const u32 lo = pack2(fmaxf(v[0], 0.0f), fmaxf(v[1], 0.0f));
            const u32 hi = pack2(fmaxf(v[2], 0.0f), fmaxf(v[3], 0.0f));
            *(uint2*)(h + row * 136 + hid) = make_uint2(lo, hi);
        }
    }
}

__global__ __launch_bounds__(256, 8)
void k_edge_layer_m(const u16* __restrict__ nodes_bf, u16* __restrict__ edges_bf,
                    float* __restrict__ agg, float* __restrict__ bnd,
                    const int* __restrict__ snd_s, const int* __restrict__ rcv_s,
                    const u16* __restrict__ W1p, const float* __restrict__ B1,
                    const u16* __restrict__ W2p, const float* __restrict__ B2,
                    const u16* __restrict__ W3p, const float* __restrict__ B3,
                    const float* __restrict__ g, const float* __restrict__ be)
{
    __shared__ __align__(16) u16 sb[2 * 4352];   // b0,b1: 32x136 bf16; fout overlays
    __shared__ float red[4][2][16][2];
    __shared__ int rblk[34];                     // [0..31] receivers, 32=prev, 33=next
    u16* b0 = sb;
    u16* b1 = sb + 4352;
    float* fout = (float*)sb;                    // 32 rows x stride 132 f32 = 16896B

    const int tid = threadIdx.x;
    const int e0 = blockIdx.x * 32;              // NEDGE/32 = 9375 blocks, exact
    const int lane = tid & 63, wm = tid >> 6;
    const int l15 = lane & 15, lg = lane >> 4;

    if (tid < 32)       rblk[tid] = rcv_s[e0 + tid];
    else if (tid == 32) rblk[32] = (e0 > 0) ? rcv_s[e0 - 1] : -2;
    else if (tid == 33) rblk[33] = (e0 + 32 < NEDGE) ? rcv_s[e0 + 32] : -2;

    // stage seg0 (edge rows, bf16 -> straight copy) into b0; keep old in regs
    uint4 e_old[2];
#pragma unroll
    for (int t = 0; t < 2; t++) {
        const int idx = tid + t * 256;
        const int m = idx >> 4, q = idx & 15;
        e_old[t] = *(const uint4*)(edges_bf + (size_t)(e0 + m) * HD + q * 8);
        *(uint4*)(b0 + m * 136 + q * 8) = e_old[t];
    }
    // issue seg1 (sender rows, bf16) loads -> regs
    uint4 st[2];
#pragma unroll
    for (int t = 0; t < 2; t++) {
        const int idx = tid + t * 256;
        const int m = idx >> 4, q = idx & 15;
        st[t] = *(const uint4*)(nodes_bf + (size_t)snd_s[e0 + m] * HD + q * 8);
    }
    __syncthreads();

    f32x4 acc[2][2];
#pragma unroll
    for (int mt = 0; mt < 2; mt++) {
        const f32x4 bv = *(const f32x4*)(B1 + wm * 32 + mt * 16 + lg * 4);
        acc[mt][0] = bv;
        acc[mt][1] = bv;
    }
    __builtin_amdgcn_s_setprio(1);
    egemm_seg32(W1p, b0, acc, 0, wm, l15, lg, lane);
    __builtin_amdgcn_s_setprio(0);
    // write seg1 -> b1, issue seg2 (receiver rows) loads
#pragma unroll
    for (int t = 0; t < 2; t++) {
        const int idx = tid + t * 256;
        const int m = idx >> 4, q = idx & 15;
        *(uint4*)(b1 + m * 136 + q * 8) = st[t];
    }
#pragma unroll
    for (int t = 0; t < 2; t++) {
        const int idx = tid + t * 256;
        const int m = idx >> 4, q = idx & 15;
        st[t] = *(const uint4*)(nodes_bf + (size_t)rcv_s[e0 + m] * HD + q * 8);
    }
    __syncthreads();

    __builtin_amdgcn_s_setprio(1);
    egemm_seg32(W1p, b1, acc, 4, wm, l15, lg, lane);
    __builtin_amdgcn_s_setprio(0);
#pragma unroll
    for (int t = 0; t < 2; t++) {
        const int idx = tid + t * 256;
        const int m = idx >> 4, q = idx & 15;
        *(uint4*)(b0 + m * 136 + q * 8) = st[t];
    }
    __syncthreads();

    __builtin_amdgcn_s_setprio(1);
    egemm_seg32(W1p, b0, acc, 8, wm, l15, lg, lane);
    __builtin_amdgcn_s_setprio(0);
    estore_h32(b1, acc, wm, l15, lg);      // b1 free: all waves past prev barrier
    __syncthreads();

    __builtin_amdgcn_s_setprio(1);
    egemm_h32(W2p, B2, b1, acc, wm, l15, lg, lane);
    __builtin_amdgcn_s_setprio(0);
    estore_h32(b0, acc, wm, l15, lg);      // b0 free
    __syncthreads();

    __builtin_amdgcn_s_setprio(1);
    egemm_h32(W3p, B3, b0, acc, wm, l15, lg, lane);
    __builtin_amdgcn_s_setprio(0);

    // ---- layernorm reduction ----
    float ps[2], pss[2];
#pragma unroll
    for (int nt = 0; nt < 2; nt++) {
        float s = 0.0f, ss = 0.0f;
#pragma unroll
        for (int mt = 0; mt < 2; mt++) {
#pragma unroll
            for (int r = 0; r < 4; r++) {
                const float v = acc[mt][nt][r];
                s += v; ss += v * v;
            }
        }
        s += __shfl_xor(s, 16); ss += __shfl_xor(ss, 16);
        s += __shfl_xor(s, 32); ss += __shfl_xor(ss, 32);
        ps[nt] = s; pss[nt] = ss;
    }
    if (lane < 16) {
#pragma unroll
        for (int nt = 0; nt < 2; nt++) {
            red[wm][nt][l15][0] = ps[nt];
            red[wm][nt][l15][1] = pss[nt];
        }
    }
    __syncthreads();   // red ready; all waves past GEMM3 -> b0/b1 dead, fout may overlay

    // ---- LN apply -> fout (f32, stride 132) ----
#pragma unroll
    for (int nt = 0; nt < 2; nt++) {
        const float S  = red[0][nt][l15][0] + red[1][nt][l15][0]
                       + red[2][nt][l15][0] + red[3][nt][l15][0];
        const float SS = red[0][nt][l15][1] + red[1][nt][l15][1]
                       + red[2][nt][l15][1] + red[3][nt][l15][1];
        const float mu  = S * (1.0f / 128.0f);
        const float var = SS * (1.0f / 128.0f) - mu * mu;
        const float inv = rsqrtf(var + 1e-5f);
        const int row = nt * 16 + l15;
#pragma unroll
        for (int mt = 0; mt < 2; mt++) {
            const int hid = wm * 32 + mt * 16 + lg * 4;
            const f32x4 gv  = *(const f32x4*)(g + hid);
            const f32x4 bev = *(const f32x4*)(be + hid);
            f32x4 o;
#pragma unroll
            for (int r = 0; r < 4; r++)
                o[r] = (acc[mt][nt][r] - mu) * inv * gv[r] + bev[r];
            *(f32x4*)(fout + row * 132 + hid) = o;
        }
    }
    __syncthreads();

    // ---- writer: new = b2f(old regs) + ln; bf16 row write; new(f32) -> fout ----
#pragma unroll
    for (int t = 0; t < 2; t++) {
        const int idx = tid + t * 256;
        const int m = idx >> 4, q = idx & 15;
        float4 lo = *(const float4*)(fout + m * 132 + q * 8);
        float4 hi = *(const float4*)(fout + m * 132 + q * 8 + 4);
        const uint4 o = e_old[t];
        lo.x += b2flo(o.x); lo.y += b2fhi(o.x);
        lo.z += b2flo(o.y); lo.w += b2fhi(o.y);
        hi.x += b2flo(o.z); hi.y += b2fhi(o.z);
        hi.z += b2flo(o.w); hi.w += b2fhi(o.w);
        *(float4*)(fout + m * 132 + q * 8) = lo;
        *(float4*)(fout + m * 132 + q * 8 + 4) = hi;
        *(uint4*)(edges_bf + (size_t)(e0 + m) * HD + q * 8) =
            make_uint4(pack2(lo.x, lo.y), pack2(lo.z, lo.w),
                       pack2(hi.x, hi.y), pack2(hi.z, hi.w));
    }
    __syncthreads();

    // ---- aggregation: run sums -> agg (interior, sole writer) or bnd (boundary,
    //      block-private slots, no atomics). Slot 0: run extends backward;
    //      slot 1: run extends forward only. ----
    const int c = tid & 31;              // float4 chunk 0..31
    for (int ms = (tid >> 5); ms < 32; ms += 8) {
        const int rs = rblk[ms];
        if (ms > 0 && rblk[ms - 1] == rs) continue;   // not a run start
        int me = ms + 1;
        while (me < 32 && rblk[me] == rs) me++;
        float4 s = make_float4(0.0f, 0.0f, 0.0f, 0.0f);
        for (int m = ms; m < me; m++) {
            const float4 v = *(const float4*)(fout + m * 132 + c * 4);
            s.x += v.x; s.y += v.y; s.z += v.z; s.w += v.w;
        }
        const bool extb = (ms == 0 && rblk[32] == rs);
        const bool extf = (me == 32 && rblk[33] == rs);
        float* ap;
        if (!extb && !extf) ap = agg + (size_t)rs * HD + c * 4;
        else ap = bnd + ((size_t)blockIdx.x * 2 + (extb ? 0 : 1)) * HD + c * 4;
        *(float4*)ap = s;
    }
}

// ------- per-layer node update (K=256); CSR-aware agg/bnd reassembly, no zeroing -------
__global__ __launch_bounds__(256)
void k_node_layer_m(float* __restrict__ nodes, u16* __restrict__ nodes_bf,
                    const float* __restrict__ agg, const float* __restrict__ bnd,
                    const int* __restrict__ row_ptr,
                    const u16* __restrict__ W1p, const float* __restrict__ B1,
                    const u16* __restrict__ W2p, const float* __restrict__ B2,
                    const u16* __restrict__ W3p, const float* __restrict__ B3,
                    const float* __restrict__ g, const float* __restrict__ be)
{
    __shared__ __align__(16) u16 lds[17408];
    __shared__ float red[2][2][2][16][2];
    __shared__ int rp[65];
    const int tid = threadIdx.x;
    const int i0 = blockIdx.x * 64;
    if (tid < 65) rp[tid] = row_ptr[min(i0 + tid, NPART)];
    __syncthreads();
    for (int idx = tid; idx < 1024; idx += 256) {
        const int m = idx >> 4, q = idx & 15;
        const int i = min(i0 + m, NPART - 1);
        const float* src = nodes + (size_t)i * HD + q * 8;
        const float4 a = *(const float4*)(src);
        const float4 b = *(const float4*)(src + 4);
        *(uint4*)(lds + m * 264 + q * 8) =
            make_uint4(pack2(a.x, a.y), pack2(a.z, a.w), pack2(b.x, b.y), pack2(b.z, b.w));
    }
    for (int idx = tid; idx < 1024; idx += 256) {
        const int m = idx >> 4, q = idx & 15;
        const int i = i0 + m;
        float4 a = make_float4(0.0f, 0.0f, 0.0f, 0.0f);
        float4 b = make_float4(0.0f, 0.0f, 0.0f, 0.0f);
        if (i < NPART) {
            const int p0 = rp[m], p1 = rp[m + 1];
            if (p1 > p0) {
                const int b0 = p0 >> 5, b1 = (p1 - 1) >> 5;
                if (b0 == b1) {
                    const float* src = agg + (size_t)i * HD + q * 8;
                    a = *(const float4*)(src);
                    b = *(const float4*)(src + 4);
                } else {
                    const float* s1 = bnd + ((size_t)b0 * 2 + 1) * HD + q * 8;
                    a = *(const float4*)(s1);
                    b = *(const float4*)(s1 + 4);
                    for (int bb = b0 + 1; bb <= b1; bb++) {
                        const float* s0 = bnd + ((size_t)bb * 2 + 0) * HD + q * 8;
                        const float4 xa = *(const float4*)(s0);
                        const float4 xb = *(const float4*)(s0 + 4);
                        a.x += xa.x; a.y += xa.y; a.z += xa.z; a.w += xa.w;
                        b.x += xb.x; b.y += xb.y; b.z += xb.z; b.w += xb.w;
                    }
                }
            }
        }
        *(uint4*)(lds + m * 264 + 128 + q * 8) =
            make_uint4(pack2(a.x, a.y), pack2(a.z, a.w), pack2(b.x, b.y), pack2(b.z, b.w));
    }
    __syncthreads();
    const int lane = tid & 63, wv = tid >> 6;
    const int wm = wv >> 1, wn = wv & 1, l15 = lane & 15, lg = lane >> 4;
    float outv[4][2][4];
    mlp_mfma<8, 264>(lds, lds, lds + 8704, red, W1p, B1, W2p, B2, W3p, B3, g, be,
                     outv, wm, wn, l15, lg, lane);
#pragma unroll
    for (int nt = 0; nt < 2; nt++) {
        const int i = i0 + wn * 32 + nt * 16 + l15;
        if (i < NPART) {
            float* np = nodes + (size_t)i * HD;
#pragma unroll
            for (int mt = 0; mt < 4; mt++) {
                const int hid = wm * 64 + mt * 16 + lg * 4;
                const float4 old = *(const float4*)(np + hid);
                const float4 nv = make_float4(old.x + outv[mt][nt][0],
                                              old.y + outv[mt][nt][1],
                                              old.z + outv[mt][nt][2],
                                              old.w + outv[mt][nt][3]);
                *(float4*)(np + hid) = nv;
                *(uint2*)(nodes_bf + (size_t)i * HD + hid) =
                    make_uint2(pack2(nv.x, nv.y), pack2(nv.z, nv.w));
            }
        }
    }
}

// ---------------- fp32 gemv for decoder ----------------
template<int K, int S>
__device__ __forceinline__ void gemv(const float* __restrict__ in,
                                     const float* __restrict__ W,
                                     const float* __restrict__ B,
                                     float acc[8])
{
    const int j = threadIdx.x;
    const float bb = B[j];
#pragma unroll
    for (int m = 0; m < 8; m++) acc[m] = bb;
    constexpr int K4 = (K / 4) * 4;
    for (int k = 0; k < K4; k += 4) {
        const float w0 = W[(k + 0) * HD + j];
        const float w1 = W[(k + 1) * HD + j];
        const float w2 = W[(k + 2) * HD + j];
        const float w3 = W[(k + 3) * HD + j];
#pragma unroll
        for (int m = 0; m < 8; m++) {
            const float4 x = *(const float4*)(in + m * S + k);
            float a = acc[m];
            a = fmaf(x.x, w0, a);
            a = fmaf(x.y, w1, a);
            a = fmaf(x.z, w2, a);
            a = fmaf(x.w, w3, a);
            acc[m] = a;
        }
    }
#pragma unroll
    for (int k = K4; k < K; k++) {
        const float w = W[k * HD + j];
#pragma unroll
        for (int m = 0; m < 8; m++) acc[m] = fmaf(in[m * S + k], w, acc[m]);
    }
}

// ---------------- decoder + Euler integration (dual output dtype) ----------------
__global__ __launch_bounds__(128)
void k_decoder(const float* __restrict__ nodes,
               const float* W1, const float* B1, const float* W2, const float* B2,
               const float* W3, const float* B3,
               const float* __restrict__ vel, const float* __restrict__ pos,
               const float* __restrict__ tgt, const int* __restrict__ nonk,
               const unsigned short* __restrict__ braw, void* __restrict__ d_out)
{
    __shared__ __align__(16) float xs[8 * HD];
    __shared__ __align__(16) float h1[8 * HD];
    __shared__ __align__(16) float h2[8 * HD];
    const int j = threadIdx.x;
    const int i0 = blockIdx.x * 8;
    float acc[8];
#pragma unroll
    for (int m = 0; m < 8; m++) xs[m * HD + j] = nodes[(i0 + m) * HD + j];
    __syncthreads();
    gemv<HD, HD>(xs, W1, B1, acc);
#pragma unroll
    for (int m = 0; m < 8; m++) h1[m * HD + j] = fmaxf(acc[m], 0.0f);
    __syncthreads();
    gemv<HD, HD>(h1, W2, B2, acc);
#pragma unroll
    for (int m = 0; m < 8; m++) h2[m * HD + j] = fmaxf(acc[m], 0.0f);
    __syncthreads();
    if (j < 16) {
        const int m = j >> 1, d = j & 1, i = i0 + m;
        float a = B3[d];
        for (int k = 0; k < HD; k++) a = fmaf(h2[m * HD + k], W3[k * 2 + d], a);
        float pp = pos[i * 2 + d] + vel[i * 10 + 8 + d] + a;
        if (nonk[i] == 0) pp = tgt[i * 2 + d];
        if (detect_bf16(braw)) {
            bf16* o = (bf16*)d_out;
            o[i * 2 + d] = __float2bfloat16(a);
            o[2 * NPART + i * 2 + d] = __float2bfloat16(pp);
        } else {
            float* o = (float*)d_out;
            o[i * 2 + d] = a;
            o[2 * NPART + i * 2 + d] = pp;
        }
    }
}

extern "C" void kernel_launch(void* const* d_in, const int* in_sizes, int n_in,
                              void* d_out, int out_size, void* d_ws, size_t ws_size,
                              hipStream_t stream)
{
    const int* ptype = (const int*)d_in[4];
    const int* nonk  = (const int*)d_in[5];
    const int* snd   = (const int*)d_in[6];
    const int* rcv   = (const int*)d_in[7];
    const unsigned short* braw = (const unsigned short*)d_in[2];

    int fmap[NFLOAT_ARRAYS];
    {
        int c = 0;
        fmap[c++] = 0; fmap[c++] = 1; fmap[c++] = 2; fmap[c++] = 3; fmap[c++] = 8;
        for (int i = 9; i <= 46; i++) fmap[c++] = i;
    }
    ConvArgs ca;
    const float* fp[47];
    float* cw = (float*)d_ws;
    int off = 0;
    for (int i = 0; i < NFLOAT_ARRAYS; i++) {
        ca.src[i] = d_in[fmap[i]];
        ca.n[i]   = in_sizes[fmap[i]];
        ca.off[i] = off;
        fp[fmap[i]] = cw + off;
        off += in_sizes[fmap[i]];
    }
    const int EB32 = NEDGE / 32;        // 9375 (edge layer, exact)
    // workspace: f32 node state + agg + bnd + bf16 edge state + bf16 node mirror + weights
    float* nodes = cw + ((off + 3) & ~3);
    float* agg   = nodes + (size_t)NPART * HD;
    float* bnd   = agg + (size_t)NPART * HD;
    u16* edges_bf = (u16*)(bnd + (size_t)EB32 * 2 * HD);
    u16* nodes_bf = edges_bf + (size_t)NEDGE * HD;
    u16* wpk = nodes_bf + (size_t)NPART * HD;

    // build pack table (order: ne x3, ee x3, ge x30, gn x30)
    PackArgs pa;
    int dst = 0, c = 0;
    int pk[NMAT];
    auto addm = [&](long srcoff, int K) {
        const int nk = (K + 31) / 32;
        pa.src_off[c] = (int)srcoff;
        pa.K[c] = K;
        pa.nks[c] = nk;
        pa.dst_off[c] = dst;
        pk[c] = dst;
        dst += nk * 4096;
        c++;
    };
    addm(fp[9]  - cw, 30);  addm(fp[11] - cw, 128); addm(fp[13] - cw, 128);
    addm(fp[17] - cw, 3);   addm(fp[19] - cw, 128); addm(fp[21] - cw, 128);
    for (int l = 0; l < NLAYER; l++) {
        addm(fp[25] - cw + (long)l * 384 * HD, 384);
        addm(fp[27] - cw + (long)l * HD * HD, 128);
        addm(fp[29] - cw + (long)l * HD * HD, 128);
    }
    for (int l = 0; l < NLAYER; l++) {
        addm(fp[33] - cw + (long)l * 256 * HD, 256);
        addm(fp[35] - cw + (long)l * HD * HD, 128);
        addm(fp[37] - cw + (long)l * HD * HD, 128);
    }

    int* ip = (int*)(wpk + ((dst + 7) & ~7));
    int* row_ptr = ip;            ip += NPART + 8;
    int* cursor  = ip;            ip += NPART;
    int* counts  = ip;            ip += NPART;
    int* snd_s   = ip;            ip += NEDGE;
    int* rcv_s   = ip;

    const int EBL = (NEDGE + 255) / 256;

    k_convert<<<dim3(64, NFLOAT_ARRAYS), 256, 0, stream>>>(ca, cw, braw);
    hipMemsetAsync(counts, 0, (size_t)NPART * sizeof(int), stream);
    k_hist<<<EBL, 256, 0, stream>>>(rcv, counts);
    k_scan<<<1, 1024, 0, stream>>>(counts, row_ptr, cursor);
    k_scatter<<<EBL, 256, 0, stream>>>(snd, rcv, cursor, snd_s, rcv_s);
    k_pack<<<dim3(192, NMAT), 256, 0, stream>>>(cw, wpk, pa);

    const int NB = (NPART + 63) / 64;   // 469
    const int EB = (NEDGE + 63) / 64;   // 4688 (encoder)

    k_node_enc_m<<<NB, 256, 0, stream>>>(fp[0], fp[1], fp[2], ptype, fp[8],
        wpk + pk[0], fp[10], wpk + pk[1], fp[12], wpk + pk[2], fp[14],
        fp[15], fp[16], nodes, nodes_bf);
    k_edge_enc_m<<<EB, 256, 0, stream>>>(fp[1], snd_s, rcv_s,
        wpk + pk[3], fp[18], wpk + pk[4], fp[20], wpk + pk[5], fp[22],
        fp[23], fp[24], edges_bf);

    for (int l = 0; l < NLAYER; l++) {
        k_edge_layer_m<<<EB32, 256, 0, stream>>>(nodes_bf, edges_bf, agg, bnd, snd_s, rcv_s,
            wpk + pk[6 + 3 * l],  fp[26] + (size_t)l * HD,
            wpk + pk[7 + 3 * l],  fp[28] + (size_t)l * HD,
            wpk + pk[8 + 3 * l],  fp[30] + (size_t)l * HD,
            fp[31] + (size_t)l * HD, fp[32] + (size_t)l * HD);
        k_node_layer_m<<<NB, 256, 0, stream>>>(nodes, nodes_bf, agg, bnd, row_ptr,
            wpk + pk[36 + 3 * l], fp[34] + (size_t)l * HD,
            wpk + pk[37 + 3 * l], fp[36] + (size_t)l * HD,
            wpk + pk[38 + 3 * l], fp[38] + (size_t)l * HD,
            fp[39] + (size_t)l * HD, fp[40] + (size_t)l * HD);
    }

    k_decoder<<<NPART / 8, 128, 0, stream>>>(nodes,
        fp[41], fp[42], fp[43], fp[44], fp[45], fp[46],
        fp[0], fp[1], fp[3], nonk, braw, d_out);
}

// Round 8
// 1834.888 us; speedup vs baseline: 7.9437x; 1.2026x over previous
//
#include <hip/hip_runtime.h>
#include <hip/hip_bf16.h>

typedef __hip_bfloat16 bf16;
typedef unsigned short u16;
typedef unsigned int u32;
typedef __attribute__((ext_vector_type(8))) short short8;
typedef __attribute__((ext_vector_type(4))) float f32x4;
typedef __attribute__((ext_vector_type(4))) unsigned int u32x4;

#define NPART 30000
#define NEDGE 300000
#define HD 128
#define NLAYER 10
#define NFLOAT_ARRAYS 43
#define NMAT 66

// ---------------- dtype detect ----------------
__device__ __forceinline__ bool detect_bf16(const unsigned short* braw) {
    return braw[1] == 0x3F80u;
}

// ---------------- fp32<->bf16 helpers (RNE) ----------------
__device__ __forceinline__ u16 f2b(float f) {
    u32 u = __float_as_uint(f);
    u += 0x7FFFu + ((u >> 16) & 1u);
    return (u16)(u >> 16);
}
__device__ __forceinline__ u32 pack2(float a, float b) {
    return (u32)f2b(a) | ((u32)f2b(b) << 16);
}
__device__ __forceinline__ float b2flo(u32 u) { return __uint_as_float(u << 16); }
__device__ __forceinline__ float b2fhi(u32 u) { return __uint_as_float(u & 0xFFFF0000u); }

// ---------------- non-temporal 16B accessors ----------------
__device__ __forceinline__ u32x4 ntl4(const u16* p) {
    return __builtin_nontemporal_load((const u32x4*)p);
}
__device__ __forceinline__ void nts4(const u32x4 v, u16* p) {
    __builtin_nontemporal_store(v, (u32x4*)p);
}
__device__ __forceinline__ f32x4 ntlf4(const float* p) {
    return __builtin_nontemporal_load((const f32x4*)p);
}
__device__ __forceinline__ void ntsf4(const f32x4 v, float* p) {
    __builtin_nontemporal_store(v, (f32x4*)p);
}

// ---------------- convert all float arrays to canonical fp32 ----------------
struct ConvArgs {
    const void* src[NFLOAT_ARRAYS];
    int n[NFLOAT_ARRAYS];
    int off[NFLOAT_ARRAYS];
};

__global__ __launch_bounds__(256)
void k_convert(ConvArgs a, float* __restrict__ dst, const unsigned short* __restrict__ braw)
{
    const bool isb = detect_bf16(braw);
    const int aid = blockIdx.y;
    const int n = a.n[aid];
    float* o = dst + a.off[aid];
    const int stride = gridDim.x * 256;
    int i = blockIdx.x * 256 + threadIdx.x;
    if (isb) {
        const unsigned short* s = (const unsigned short*)a.src[aid];
        for (; i < n; i += stride) {
            const unsigned int u = ((unsigned int)s[i]) << 16;
            o[i] = __uint_as_float(u);
        }
    } else {
        const float* s = (const float*)a.src[aid];
        for (; i < n; i += stride) o[i] = s[i];
    }
}

// ---------------- counting sort of edges by receiver ----------------
__global__ __launch_bounds__(256)
void k_hist(const int* __restrict__ rcv, int* __restrict__ counts)
{
    const int e = blockIdx.x * 256 + threadIdx.x;
    if (e < NEDGE) atomicAdd(&counts[rcv[e]], 1);
}

__global__ __launch_bounds__(1024)
void k_scan(const int* __restrict__ counts, int* __restrict__ row_ptr, int* __restrict__ cursor)
{
    __shared__ int part[1024];
    const int t = threadIdx.x;
    const int base = t * 32;
    int local[32];
    int s = 0;
#pragma unroll
    for (int k = 0; k < 32; k++) {
        const int idx = base + k;
        const int v = (idx < NPART) ? counts[idx] : 0;
        local[k] = s;
        s += v;
    }
    part[t] = s;
    __syncthreads();
    for (int off = 1; off < 1024; off <<= 1) {
        const int v = (t >= off) ? part[t - off] : 0;
        __syncthreads();
        part[t] += v;
        __syncthreads();
    }
    const int excl = (t == 0) ? 0 : part[t - 1];
#pragma unroll
    for (int k = 0; k < 32; k++) {
        const int idx = base + k;
        if (idx < NPART) {
            const int rp = excl + local[k];
            row_ptr[idx] = rp;
            cursor[idx] = rp;
        }
    }
    if (t == 0) row_ptr[NPART] = NEDGE;
}

__global__ __launch_bounds__(256)
void k_scatter(const int* __restrict__ snd, const int* __restrict__ rcv,
               int* __restrict__ cursor, int* __restrict__ snd_s, int* __restrict__ rcv_s)
{
    const int e = blockIdx.x * 256 + threadIdx.x;
    if (e < NEDGE) {
        const int r = rcv[e];
        const int p = atomicAdd(&cursor[r], 1);
        snd_s[p] = snd[e];
        rcv_s[p] = r;
    }
}

// ---------------- weight pre-pack: f32 [K][128] -> bf16 fragment-linear ----------------
struct PackArgs {
    int src_off[NMAT];
    int dst_off[NMAT];
    int K[NMAT];
    int nks[NMAT];
};

__global__ __launch_bounds__(256)
void k_pack(const float* __restrict__ cw, u16* __restrict__ wpk, PackArgs pa)
{
    const int mid = blockIdx.y;
    const int nks = pa.nks[mid];
    const int total = nks * 4096;
    const int d = blockIdx.x * 256 + threadIdx.x;
    if (d >= total) return;
    const int j = d & 7, l = (d >> 3) & 63, t = d >> 9;
    const int ks = t % nks, mt = t / nks;
    const int hid = mt * 16 + (l & 15);
    const int k = ks * 32 + (l >> 4) * 8 + j;
    const float v = (k < pa.K[mid]) ? cw[pa.src_off[mid] + k * HD + hid] : 0.0f;
    wpk[pa.dst_off[mid] + d] = f2b(v);
}

// ================= 4-wave (256-thr) MFMA MLP: encoders + node layer =================
template<int NKS, int XROW>
__device__ __forceinline__ void gemm16(const u16* __restrict__ Wp,
                                       const float* __restrict__ Bias,
                                       const u16* __restrict__ x,
                                       f32x4 acc[4][2],
                                       const int wm, const int wn,
                                       const int l15, const int lg, const int lane)
{
#pragma unroll
    for (int mt = 0; mt < 4; mt++) {
        const f32x4 bv = *(const f32x4*)(Bias + wm * 64 + mt * 16 + lg * 4);
        acc[mt][0] = bv;
        acc[mt][1] = bv;
    }
    const u16* xr0 = x + (wn * 32 + l15) * XROW + lg * 8;
    const u16* xr1 = xr0 + 16 * XROW;
    const u16* wp = Wp + (wm * 4 * NKS) * 512 + lane * 8;
#pragma unroll
    for (int ks = 0; ks < NKS; ks++) {
        const short8 b0 = *(const short8*)(xr0 + ks * 32);
        const short8 b1 = *(const short8*)(xr1 + ks * 32);
#pragma unroll
        for (int mt = 0; mt < 4; mt++) {
            const short8 a = *(const short8*)(wp + (mt * NKS + ks) * 512);
            acc[mt][0] = __builtin_amdgcn_mfma_f32_16x16x32_bf16(a, b0, acc[mt][0], 0, 0, 0);
            acc[mt][1] = __builtin_amdgcn_mfma_f32_16x16x32_bf16(a, b1, acc[mt][1], 0, 0, 0);
        }
    }
}

__device__ __forceinline__ void store_h(u16* __restrict__ h, const f32x4 acc[4][2],
                                        const int wm, const int wn, const int l15, const int lg)
{
#pragma unroll
    for (int nt = 0; nt < 2; nt++) {
        const int e = wn * 32 + nt * 16 + l15;
#pragma unroll
        for (int mt = 0; mt < 4; mt++) {
            const int hid = wm * 64 + mt * 16 + lg * 4;
            const f32x4 v = acc[mt][nt];
            const u32 lo = pack2(fmaxf(v[0], 0.0f), fmaxf(v[1], 0.0f));
            const u32 hi = pack2(fmaxf(v[2], 0.0f), fmaxf(v[3], 0.0f));
            *(uint2*)(h + e * 136 + hid) = make_uint2(lo, hi);
        }
    }
}

template<int NKS1, int XROW>
__device__ __forceinline__ void mlp_mfma(const u16* __restrict__ xs,
    u16* __restrict__ h1, u16* __restrict__ h2,
    float (*red)[2][2][16][2],
    const u16* __restrict__ W1p, const float* __restrict__ B1,
    const u16* __restrict__ W2p, const float* __restrict__ B2,
    const u16* __restrict__ W3p, const float* __restrict__ B3,
    const float* __restrict__ g, const float* __restrict__ be,
    float outv[4][2][4],
    const int wm, const int wn, const int l15, const int lg, const int lane)
{
    f32x4 acc[4][2];
    gemm16<NKS1, XROW>(W1p, B1, xs, acc, wm, wn, l15, lg, lane);
    __syncthreads();
    store_h(h1, acc, wm, wn, l15, lg);
    __syncthreads();
    gemm16<4, 136>(W2p, B2, h1, acc, wm, wn, l15, lg, lane);
    store_h(h2, acc, wm, wn, l15, lg);
    __syncthreads();
    gemm16<4, 136>(W3p, B3, h2, acc, wm, wn, l15, lg, lane);
    float ps[2], pss[2];
#pragma unroll
    for (int nt = 0; nt < 2; nt++) {
        float s = 0.0f, ss = 0.0f;
#pragma unroll
        for (int mt = 0; mt < 4; mt++) {
#pragma unroll
            for (int r = 0; r < 4; r++) {
                const float v = acc[mt][nt][r];
                s += v; ss += v * v;
            }
        }
        s += __shfl_xor(s, 16); ss += __shfl_xor(ss, 16);
        s += __shfl_xor(s, 32); ss += __shfl_xor(ss, 32);
        ps[nt] = s; pss[nt] = ss;
    }
    if (lane < 16) {
#pragma unroll
        for (int nt = 0; nt < 2; nt++) {
            red[wm][wn][nt][l15][0] = ps[nt];
            red[wm][wn][nt][l15][1] = pss[nt];
        }
    }
    __syncthreads();
#pragma unroll
    for (int nt = 0; nt < 2; nt++) {
        const float S  = red[0][wn][nt][l15][0] + red[1][wn][nt][l15][0];
        const float SS = red[0][wn][nt][l15][1] + red[1][wn][nt][l15][1];
        const float mu  = S * (1.0f / 128.0f);
        const float var = SS * (1.0f / 128.0f) - mu * mu;
        const float inv = rsqrtf(var + 1e-5f);
#pragma unroll
        for (int mt = 0; mt < 4; mt++) {
            const int hid = wm * 64 + mt * 16 + lg * 4;
            const f32x4 gv  = *(const f32x4*)(g + hid);
            const f32x4 bev = *(const f32x4*)(be + hid);
#pragma unroll
            for (int r = 0; r < 4; r++)
                outv[mt][nt][r] = (acc[mt][nt][r] - mu) * inv * gv[r] + bev[r];
        }
    }
}

// ---------------- node encoder (K=30 padded to 32), bf16 node state ----------------
__device__ __forceinline__ float nfeat(int i, int k,
    const float* __restrict__ vel, const float* __restrict__ pos,
    const float* __restrict__ bounds, const int* __restrict__ ptype,
    const float* __restrict__ emb)
{
    if (k < 10) return vel[i * 10 + k];
    if (k < 14) {
        const int q = k - 10;
        float sub;
        if (q < 2) sub = pos[i * 2 + q] - bounds[q * 2 + 0];
        else       sub = bounds[(q - 2) * 2 + 1] - pos[i * 2 + (q - 2)];
        const float dv = sub * 20.0f;
        return fminf(fmaxf(dv, -1.0f), 1.0f);
    }
    if (k < 30) return emb[ptype[i] * 16 + (k - 14)];
    return 0.0f;
}

__global__ __launch_bounds__(256)
void k_node_enc_m(const float* __restrict__ vel, const float* __restrict__ pos,
                  const float* __restrict__ bounds, const int* __restrict__ ptype,
                  const float* __restrict__ emb,
                  const u16* __restrict__ W1p, const float* __restrict__ B1,
                  const u16* __restrict__ W2p, const float* __restrict__ B2,
                  const u16* __restrict__ W3p, const float* __restrict__ B3,
                  const float* __restrict__ g, const float* __restrict__ be,
                  u16* __restrict__ nodes_bf)
{
    __shared__ __align__(16) u16 lds[17408];
    __shared__ float red[2][2][2][16][2];
    const int tid = threadIdx.x;
    const int i0 = blockIdx.x * 64;
    for (int idx = tid; idx < 1024; idx += 256) {
        const int m = idx >> 4, kk = idx & 15;
        const int i = i0 + m;
        float f0 = 0.0f, f1 = 0.0f;
        if (i < NPART) {
            f0 = nfeat(i, kk * 2 + 0, vel, pos, bounds, ptype, emb);
            f1 = nfeat(i, kk * 2 + 1, vel, pos, bounds, ptype, emb);
        }
        *(u32*)(lds + m * 40 + kk * 2) = pack2(f0, f1);
    }
    __syncthreads();
    const int lane = tid & 63, wv = tid >> 6;
    const int wm = wv >> 1, wn = wv & 1, l15 = lane & 15, lg = lane >> 4;
    float outv[4][2][4];
    mlp_mfma<1, 40>(lds, lds, lds + 8704, red, W1p, B1, W2p, B2, W3p, B3, g, be,
                    outv, wm, wn, l15, lg, lane);
#pragma unroll
    for (int nt = 0; nt < 2; nt++) {
        const int i = i0 + wn * 32 + nt * 16 + l15;
        if (i < NPART) {
#pragma unroll
            for (int mt = 0; mt < 4; mt++) {
                const int hid = wm * 64 + mt * 16 + lg * 4;
                *(uint2*)(nodes_bf + (size_t)i * HD + hid) =
                    make_uint2(pack2(outv[mt][nt][0], outv[mt][nt][1]),
                               pack2(outv[mt][nt][2], outv[mt][nt][3]));
            }
        }
    }
}

// ------------- edge encoder (K=3 padded to 32), sorted order, bf16 output -------------
__global__ __launch_bounds__(256)
void k_edge_enc_m(const float* __restrict__ pos, const int* __restrict__ snd_s,
                  const int* __restrict__ rcv_s,
                  const u16* __restrict__ W1p, const float* __restrict__ B1,
                  const u16* __restrict__ W2p, const float* __restrict__ B2,
                  const u16* __restrict__ W3p, const float* __restrict__ B3,
                  const float* __restrict__ g, const float* __restrict__ be,
                  u16* __restrict__ edges_bf)
{
    __shared__ __align__(16) u16 lds[17408];
    __shared__ float red[2][2][2][16][2];
    const int tid = threadIdx.x;
    const int e0 = blockIdx.x * 64;
    for (int idx = tid; idx < 1024; idx += 256) {
        const int m = idx >> 4, kk = idx & 15;
        const int e = min(e0 + m, NEDGE - 1);
        u32 w = 0;
        if (kk < 2) {
            const int s = snd_s[e], r = rcv_s[e];
            const float dx = (pos[s * 2 + 0] - pos[r * 2 + 0]) * 20.0f;
            const float dy = (pos[s * 2 + 1] - pos[r * 2 + 1]) * 20.0f;
            if (kk == 0) w = pack2(dx, dy);
            else         w = pack2(sqrtf(dx * dx + dy * dy), 0.0f);
        }
        *(u32*)(lds + m * 40 + kk * 2) = w;
    }
    __syncthreads();
    const int lane = tid & 63, wv = tid >> 6;
    const int wm = wv >> 1, wn = wv & 1, l15 = lane & 15, lg = lane >> 4;
    float outv[4][2][4];
    mlp_mfma<1, 40>(lds, lds, lds + 8704, red, W1p, B1, W2p, B2, W3p, B3, g, be,
                    outv, wm, wn, l15, lg, lane);
#pragma unroll
    for (int nt = 0; nt < 2; nt++) {
        const int e = e0 + wn * 32 + nt * 16 + l15;
        if (e < NEDGE) {
#pragma unroll
            for (int mt = 0; mt < 4; mt++) {
                const int hid = wm * 64 + mt * 16 + lg * 4;
                *(uint2*)(edges_bf + (size_t)e * HD + hid) =
                    make_uint2(pack2(outv[mt][nt][0], outv[mt][nt][1]),
                               pack2(outv[mt][nt][2], outv[mt][nt][3]));
            }
        }
    }
}

// ======= 4-wave (256-thr) 32-row pipelined edge layer, bf16 state, NT streams =======
__device__ __forceinline__ void egemm_seg32(const u16* __restrict__ Wp,
                                            const u16* __restrict__ x,
                                            f32x4 acc[2][2], const int ks0,
                                            const int wm,
                                            const int l15, const int lg, const int lane)
{
    const u16* xr0 = x + l15 * 136 + lg * 8;
    const u16* xr1 = xr0 + 16 * 136;
#pragma unroll
    for (int ks = 0; ks < 4; ks++) {
        const short8 b0 = *(const short8*)(xr0 + ks * 32);
        const short8 b1 = *(const short8*)(xr1 + ks * 32);
#pragma unroll
        for (int mt = 0; mt < 2; mt++) {
            const short8 a = *(const short8*)(Wp + (((wm * 2 + mt) * 12 + ks0 + ks) * 64 + lane) * 8);
            acc[mt][0] = __builtin_amdgcn_mfma_f32_16x16x32_bf16(a, b0, acc[mt][0], 0, 0, 0);
            acc[mt][1] = __builtin_amdgcn_mfma_f32_16x16x32_bf16(a, b1, acc[mt][1], 0, 0, 0);
        }
    }
}

__device__ __forceinline__ void egemm_h32(const u16* __restrict__ Wp,
                                          const float* __restrict__ Bias,
                                          const u16* __restrict__ x,
                                          f32x4 acc[2][2],
                                          const int wm,
                                          const int l15, const int lg, const int lane)
{
#pragma unroll
    for (int mt = 0; mt < 2; mt++) {
        const f32x4 bv = *(const f32x4*)(Bias + wm * 32 + mt * 16 + lg * 4);
        acc[mt][0] = bv;
        acc[mt][1] = bv;
    }
    const u16* xr0 = x + l15 * 136 + lg * 8;
    const u16* xr1 = xr0 + 16 * 136;
#pragma unroll
    for (int ks = 0; ks < 4; ks++) {
        const short8 b0 = *(const short8*)(xr0 + ks * 32);
        const short8 b1 = *(const short8*)(xr1 + ks * 32);
#pragma unroll
        for (int mt = 0; mt < 2; mt++) {
            const short8 a = *(const short8*)(Wp + (((wm * 2 + mt) * 4 + ks) * 64 + lane) * 8);
            acc[mt][0] = __builtin_amdgcn_mfma_f32_16x16x32_bf16(a, b0, acc[mt][0], 0, 0, 0);
            acc[mt][1] = __builtin_amdgcn_mfma_f32_16x16x32_bf16(a, b1, acc[mt][1], 0, 0, 0);
        }
    }
}

__device__ __forceinline__ void estore_h32(u16* __restrict__ h, const f32x4 acc[2][2],
                                           const int wm, const int l15, const int lg)
{
#pragma unroll
    for (int nt = 0; nt < 2; nt++) {
        const int row = nt * 16 + l15;
#pragma unroll
        for (int mt = 0; mt < 2; mt++) {
            const int hid = wm * 32 + mt * 16 + lg * 4;
            const f32x4 v = acc[mt][nt];
            const u32 lo = pack2(fmaxf(v[0], 0.0f), fmaxf(v[1], 0.0f));
            const u32 hi = pack2(fmaxf(v[2], 0.0f), fmaxf(v[3], 0.0f));
            *(uint2*)(h + row * 136 + hid) = make_uint2(lo, hi);
        }
    }
}

__global__ __launch_bounds__(256, 8)
void k_edge_layer_m(const u16* __restrict__ nodes_bf, u16* __restrict__ edges_bf,
                    float* __restrict__ agg, float* __restrict__ bnd,
                    const int* __restrict__ snd_s, const int* __restrict__ rcv_s,
                    const u16* __restrict__ W1p, const float* __restrict__ B1,
                    const u16* __restrict__ W2p, const float* __restrict__ B2,
                    const u16* __restrict__ W3p, const float* __restrict__ B3,
                    const float* __restrict__ g, const float* __restrict__ be)
{
    __shared__ __align__(16) u16 sb[2 * 4352];   // b0,b1: 32x136 bf16; fout overlays
    __shared__ float red[4][2][16][2];
    __shared__ int rblk[34];                     // [0..31] receivers, 32=prev, 33=next
    u16* b0 = sb;
    u16* b1 = sb + 4352;
    float* fout = (float*)sb;                    // 32 rows x stride 132 f32 = 16896B

    const int tid = threadIdx.x;
    const int e0 = blockIdx.x * 32;              // NEDGE/32 = 9375 blocks, exact
    const int lane = tid & 63, wm = tid >> 6;
    const int l15 = lane & 15, lg = lane >> 4;

    if (tid < 32)       rblk[tid] = rcv_s[e0 + tid];
    else if (tid == 32) rblk[32] = (e0 > 0) ? rcv_s[e0 - 1] : -2;
    else if (tid == 33) rblk[33] = (e0 + 32 < NEDGE) ? rcv_s[e0 + 32] : -2;

    // stage seg0 (edge rows, bf16, non-temporal) into b0; keep old in regs
    u32x4 e_old[2];
#pragma unroll
    for (int t = 0; t < 2; t++) {
        const int idx = tid + t * 256;
        const int m = idx >> 4, q = idx & 15;
        e_old[t] = ntl4(edges_bf + (size_t)(e0 + m) * HD + q * 8);
        *(u32x4*)(b0 + m * 136 + q * 8) = e_old[t];
    }
    // issue seg1 (sender rows, bf16, cached) loads -> regs
    u32x4 st[2];
#pragma unroll
    for (int t = 0; t < 2; t++) {
        const int idx = tid + t * 256;
        const int m = idx >> 4, q = idx & 15;
        st[t] = *(const u32x4*)(nodes_bf + (size_t)snd_s[e0 + m] * HD + q * 8);
    }
    __syncthreads();

    f32x4 acc[2][2];
#pragma unroll
    for (int mt = 0; mt < 2; mt++) {
        const f32x4 bv = *(const f32x4*)(B1 + wm * 32 + mt * 16 + lg * 4);
        acc[mt][0] = bv;
        acc[mt][1] = bv;
    }
    __builtin_amdgcn_s_setprio(1);
    egemm_seg32(W1p, b0, acc, 0, wm, l15, lg, lane);
    __builtin_amdgcn_s_setprio(0);
    // write seg1 -> b1, issue seg2 (receiver rows) loads
#pragma unroll
    for (int t = 0; t < 2; t++) {
        const int idx = tid + t * 256;
        const int m = idx >> 4, q = idx & 15;
        *(u32x4*)(b1 + m * 136 + q * 8) = st[t];
    }
#pragma unroll
    for (int t = 0; t < 2; t++) {
        const int idx = tid + t * 256;
        const int m = idx >> 4, q = idx & 15;
        st[t] = *(const u32x4*)(nodes_bf + (size_t)rcv_s[e0 + m] * HD + q * 8);
    }
    __syncthreads();

    __builtin_amdgcn_s_setprio(1);
    egemm_seg32(W1p, b1, acc, 4, wm, l15, lg, lane);
    __builtin_amdgcn_s_setprio(0);
#pragma unroll
    for (int t = 0; t < 2; t++) {
        const int idx = tid + t * 256;
        const int m = idx >> 4, q = idx & 15;
        *(u32x4*)(b0 + m * 136 + q * 8) = st[t];
    }
    __syncthreads();

    __builtin_amdgcn_s_setprio(1);
    egemm_seg32(W1p, b0, acc, 8, wm, l15, lg, lane);
    __builtin_amdgcn_s_setprio(0);
    estore_h32(b1, acc, wm, l15, lg);      // b1 free: all waves past prev barrier
    __syncthreads();

    __builtin_amdgcn_s_setprio(1);
    egemm_h32(W2p, B2, b1, acc, wm, l15, lg, lane);
    __builtin_amdgcn_s_setprio(0);
    estore_h32(b0, acc, wm, l15, lg);      // b0 free
    __syncthreads();

    __builtin_amdgcn_s_setprio(1);
    egemm_h32(W3p, B3, b0, acc, wm, l15, lg, lane);
    __builtin_amdgcn_s_setprio(0);

    // ---- layernorm reduction ----
    float ps[2], pss[2];
#pragma unroll
    for (int nt = 0; nt < 2; nt++) {
        float s = 0.0f, ss = 0.0f;
#pragma unroll
        for (int mt = 0; mt < 2; mt++) {
#pragma unroll
            for (int r = 0; r < 4; r++) {
                const float v = acc[mt][nt][r];
                s += v; ss += v * v;
            }
        }
        s += __shfl_xor(s, 16); ss += __shfl_xor(ss, 16);
        s += __shfl_xor(s, 32); ss += __shfl_xor(ss, 32);
        ps[nt] = s; pss[nt] = ss;
    }
    if (lane < 16) {
#pragma unroll
        for (int nt = 0; nt < 2; nt++) {
            red[wm][nt][l15][0] = ps[nt];
            red[wm][nt][l15][1] = pss[nt];
        }
    }
    __syncthreads();   // red ready; all waves past GEMM3 -> b0/b1 dead, fout may overlay

    // ---- LN apply -> fout (f32, stride 132) ----
#pragma unroll
    for (int nt = 0; nt < 2; nt++) {
        const float S  = red[0][nt][l15][0] + red[1][nt][l15][0]
                       + red[2][nt][l15][0] + red[3][nt][l15][0];
        const float SS = red[0][nt][l15][1] + red[1][nt][l15][1]
                       + red[2][nt][l15][1] + red[3][nt][l15][1];
        const float mu  = S * (1.0f / 128.0f);
        const float var = SS * (1.0f / 128.0f) - mu * mu;
        const float inv = rsqrtf(var + 1e-5f);
        const int row = nt * 16 + l15;
#pragma unroll
        for (int mt = 0; mt < 2; mt++) {
            const int hid = wm * 32 + mt * 16 + lg * 4;
            const f32x4 gv  = *(const f32x4*)(g + hid);
            const f32x4 bev = *(const f32x4*)(be + hid);
            f32x4 o;
#pragma unroll
            for (int r = 0; r < 4; r++)
                o[r] = (acc[mt][nt][r] - mu) * inv * gv[r] + bev[r];
            *(f32x4*)(fout + row * 132 + hid) = o;
        }
    }
    __syncthreads();

    // ---- writer: new = b2f(old regs) + ln; NT bf16 row write; new(f32) -> fout ----
#pragma unroll
    for (int t = 0; t < 2; t++) {
        const int idx = tid + t * 256;
        const int m = idx >> 4, q = idx & 15;
        float4 lo = *(const float4*)(fout + m * 132 + q * 8);
        float4 hi = *(const float4*)(fout + m * 132 + q * 8 + 4);
        const u32x4 o = e_old[t];
        lo.x += b2flo(o.x); lo.y += b2fhi(o.x);
        lo.z += b2flo(o.y); lo.w += b2fhi(o.y);
        hi.x += b2flo(o.z); hi.y += b2fhi(o.z);
        hi.z += b2flo(o.w); hi.w += b2fhi(o.w);
        *(float4*)(fout + m * 132 + q * 8) = lo;
        *(float4*)(fout + m * 132 + q * 8 + 4) = hi;
        u32x4 nv;
        nv.x = pack2(lo.x, lo.y); nv.y = pack2(lo.z, lo.w);
        nv.z = pack2(hi.x, hi.y); nv.w = pack2(hi.z, hi.w);
        nts4(nv, edges_bf + (size_t)(e0 + m) * HD + q * 8);
    }
    __syncthreads();

    // ---- aggregation: run sums -> agg (interior) or bnd (boundary), NT stores ----
    const int c = tid & 31;              // float4 chunk 0..31
    for (int ms = (tid >> 5); ms < 32; ms += 8) {
        const int rs = rblk[ms];
        if (ms > 0 && rblk[ms - 1] == rs) continue;   // not a run start
        int me = ms + 1;
        while (me < 32 && rblk[me] == rs) me++;
        f32x4 s = {0.0f, 0.0f, 0.0f, 0.0f};
        for (int m = ms; m < me; m++) {
            const float4 v = *(const float4*)(fout + m * 132 + c * 4);
            s.x += v.x; s.y += v.y; s.z += v.z; s.w += v.w;
        }
        const bool extb = (ms == 0 && rblk[32] == rs);
        const bool extf = (me == 32 && rblk[33] == rs);
        float* ap;
        if (!extb && !extf) ap = agg + (size_t)rs * HD + c * 4;
        else ap = bnd + ((size_t)blockIdx.x * 2 + (extb ? 0 : 1)) * HD + c * 4;
        ntsf4(s, ap);
    }
}

// ------- per-layer node update (K=256); bf16 state, agg/bnd reassembly, NT reads -------
__global__ __launch_bounds__(256)
void k_node_layer_m(u16* __restrict__ nodes_bf,
                    const float* __restrict__ agg, const float* __restrict__ bnd,
                    const int* __restrict__ row_ptr,
                    const u16* __restrict__ W1p, const float* __restrict__ B1,
                    const u16* __restrict__ W2p, const float* __restrict__ B2,
                    const u16* __restrict__ W3p, const float* __restrict__ B3,
                    const float* __restrict__ g, const float* __restrict__ be)
{
    __shared__ __align__(16) u16 lds[17408];
    __shared__ float red[2][2][2][16][2];
    __shared__ int rp[65];
    const int tid = threadIdx.x;
    const int i0 = blockIdx.x * 64;
    if (tid < 65) rp[tid] = row_ptr[min(i0 + tid, NPART)];
    __syncthreads();
    // seg A: bf16 node rows, straight copy
    for (int idx = tid; idx < 1024; idx += 256) {
        const int m = idx >> 4, q = idx & 15;
        const int i = min(i0 + m, NPART - 1);
        *(u32x4*)(lds + m * 264 + q * 8) =
            *(const u32x4*)(nodes_bf + (size_t)i * HD + q * 8);
    }
    // seg B: agg/bnd reassembly (NT loads)
    for (int idx = tid; idx < 1024; idx += 256) {
        const int m = idx >> 4, q = idx & 15;
        const int i = i0 + m;
        f32x4 a = {0.0f, 0.0f, 0.0f, 0.0f};
        f32x4 b = {0.0f, 0.0f, 0.0f, 0.0f};
        if (i < NPART) {
            const int p0 = rp[m], p1 = rp[m + 1];
            if (p1 > p0) {
                const int b0 = p0 >> 5, b1 = (p1 - 1) >> 5;
                if (b0 == b1) {
                    const float* src = agg + (size_t)i * HD + q * 8;
                    a = ntlf4(src);
                    b = ntlf4(src + 4);
                } else {
                    const float* s1 = bnd + ((size_t)b0 * 2 + 1) * HD + q * 8;
                    a = ntlf4(s1);
                    b = ntlf4(s1 + 4);
                    for (int bb = b0 + 1; bb <= b1; bb++) {
                        const float* s0 = bnd + ((size_t)bb * 2 + 0) * HD + q * 8;
                        const f32x4 xa = ntlf4(s0);
                        const f32x4 xb = ntlf4(s0 + 4);
                        a += xa;
                        b += xb;
                    }
                }
            }
        }
        *(u32x4*)(lds + m * 264 + 128 + q * 8) = (u32x4){
            pack2(a.x, a.y), pack2(a.z, a.w), pack2(b.x, b.y), pack2(b.z, b.w)};
    }
    __syncthreads();
    const int lane = tid & 63, wv = tid >> 6;
    const int wm = wv >> 1, wn = wv & 1, l15 = lane & 15, lg = lane >> 4;
    float outv[4][2][4];
    mlp_mfma<8, 264>(lds, lds, lds + 8704, red, W1p, B1, W2p, B2, W3p, B3, g, be,
                     outv, wm, wn, l15, lg, lane);
#pragma unroll
    for (int nt = 0; nt < 2; nt++) {
        const int i = i0 + wn * 32 + nt * 16 + l15;
        if (i < NPART) {
            u16* np = nodes_bf + (size_t)i * HD;
#pragma unroll
            for (int mt = 0; mt < 4; mt++) {
                const int hid = wm * 64 + mt * 16 + lg * 4;
                const uint2 ob = *(const uint2*)(np + hid);   // L2-hot (staged above)
                float4 nv;
                nv.x = b2flo(ob.x) + outv[mt][nt][0];
                nv.y = b2fhi(ob.x) + outv[mt][nt][1];
                nv.z = b2flo(ob.y) + outv[mt][nt][2];
                nv.w = b2fhi(ob.y) + outv[mt][nt][3];
                *(uint2*)(np + hid) = make_uint2(pack2(nv.x, nv.y), pack2(nv.z, nv.w));
            }
        }
    }
}

// ---------------- fp32 gemv for decoder ----------------
template<int K, int S>
__device__ __forceinline__ void gemv(const float* __restrict__ in,
                                     const float* __restrict__ W,
                                     const float* __restrict__ B,
                                     float acc[8])
{
    const int j = threadIdx.x;
    const float bb = B[j];
#pragma unroll
    for (int m = 0; m < 8; m++) acc[m] = bb;
    constexpr int K4 = (K / 4) * 4;
    for (int k = 0; k < K4; k += 4) {
        const float w0 = W[(k + 0) * HD + j];
        const float w1 = W[(k + 1) * HD + j];
        const float w2 = W[(k + 2) * HD + j];
        const float w3 = W[(k + 3) * HD + j];
#pragma unroll
        for (int m = 0; m < 8; m++) {
            const float4 x = *(const float4*)(in + m * S + k);
            float a = acc[m];
            a = fmaf(x.x, w0, a);
            a = fmaf(x.y, w1, a);
            a = fmaf(x.z, w2, a);
            a = fmaf(x.w, w3, a);
            acc[m] = a;
        }
    }
#pragma unroll
    for (int k = K4; k < K; k++) {
        const float w = W[k * HD + j];
#pragma unroll
        for (int m = 0; m < 8; m++) acc[m] = fmaf(in[m * S + k], w, acc[m]);
    }
}

// ---------------- decoder + Euler integration (dual output dtype) ----------------
__global__ __launch_bounds__(128)
void k_decoder(const u16* __restrict__ nodes_bf,
               const float* W1, const float* B1, const float* W2, const float* B2,
               const float* W3, const float* B3,
               const float* __restrict__ vel, const float* __restrict__ pos,
               const float* __restrict__ tgt, const int* __restrict__ nonk,
               const unsigned short* __restrict__ braw, void* __restrict__ d_out)
{
    __shared__ __align__(16) float xs[8 * HD];
    __shared__ __align__(16) float h1[8 * HD];
    __shared__ __align__(16) float h2[8 * HD];
    const int j = threadIdx.x;
    const int i0 = blockIdx.x * 8;
    float acc[8];
    for (int idx = j; idx < 512; idx += 128) {
        const int m = idx >> 6, q = idx & 63;
        const u32 w = *(const u32*)(nodes_bf + (size_t)(i0 + m) * HD + q * 2);
        xs[m * HD + q * 2]     = b2flo(w);
        xs[m * HD + q * 2 + 1] = b2fhi(w);
    }
    __syncthreads();
    gemv<HD, HD>(xs, W1, B1, acc);
#pragma unroll
    for (int m = 0; m < 8; m++) h1[m * HD + j] = fmaxf(acc[m], 0.0f);
    __syncthreads();
    gemv<HD, HD>(h1, W2, B2, acc);
#pragma unroll
    for (int m = 0; m < 8; m++) h2[m * HD + j] = fmaxf(acc[m], 0.0f);
    __syncthreads();
    if (j < 16) {
        const int m = j >> 1, d = j & 1, i = i0 + m;
        float a = B3[d];
        for (int k = 0; k < HD; k++) a = fmaf(h2[m * HD + k], W3[k * 2 + d], a);
        float pp = pos[i * 2 + d] + vel[i * 10 + 8 + d] + a;
        if (nonk[i] == 0) pp = tgt[i * 2 + d];
        if (detect_bf16(braw)) {
            bf16* o = (bf16*)d_out;
            o[i * 2 + d] = __float2bfloat16(a);
            o[2 * NPART + i * 2 + d] = __float2bfloat16(pp);
        } else {
            float* o = (float*)d_out;
            o[i * 2 + d] = a;
            o[2 * NPART + i * 2 + d] = pp;
        }
    }
}

extern "C" void kernel_launch(void* const* d_in, const int* in_sizes, int n_in,
                              void* d_out, int out_size, void* d_ws, size_t ws_size,
                              hipStream_t stream)
{
    const int* ptype = (const int*)d_in[4];
    const int* nonk  = (const int*)d_in[5];
    const int* snd   = (const int*)d_in[6];
    const int* rcv   = (const int*)d_in[7];
    const unsigned short* braw = (const unsigned short*)d_in[2];

    int fmap[NFLOAT_ARRAYS];
    {
        int c = 0;
        fmap[c++] = 0; fmap[c++] = 1; fmap[c++] = 2; fmap[c++] = 3; fmap[c++] = 8;
        for (int i = 9; i <= 46; i++) fmap[c++] = i;
    }
    ConvArgs ca;
    const float* fp[47];
    float* cw = (float*)d_ws;
    int off = 0;
    for (int i = 0; i < NFLOAT_ARRAYS; i++) {
        ca.src[i] = d_in[fmap[i]];
        ca.n[i]   = in_sizes[fmap[i]];
        ca.off[i] = off;
        fp[fmap[i]] = cw + off;
        off += in_sizes[fmap[i]];
    }
    const int EB32 = NEDGE / 32;        // 9375 (edge layer, exact)
    // workspace: agg + bnd + bf16 edge state + bf16 node state + weights + sort scratch
    float* agg   = cw + ((off + 3) & ~3);
    float* bnd   = agg + (size_t)NPART * HD;
    u16* edges_bf = (u16*)(bnd + (size_t)EB32 * 2 * HD);
    u16* nodes_bf = edges_bf + (size_t)NEDGE * HD;
    u16* wpk = nodes_bf + (size_t)NPART * HD;

    // build pack table (order: ne x3, ee x3, ge x30, gn x30)
    PackArgs pa;
    int dst = 0, c = 0;
    int pk[NMAT];
    auto addm = [&](long srcoff, int K) {
        const int nk = (K + 31) / 32;
        pa.src_off[c] = (int)srcoff;
        pa.K[c] = K;
        pa.nks[c] = nk;
        pa.dst_off[c] = dst;
        pk[c] = dst;
        dst += nk * 4096;
        c++;
    };
    addm(fp[9]  - cw, 30);  addm(fp[11] - cw, 128); addm(fp[13] - cw, 128);
    addm(fp[17] - cw, 3);   addm(fp[19] - cw, 128); addm(fp[21] - cw, 128);
    for (int l = 0; l < NLAYER; l++) {
        addm(fp[25] - cw + (long)l * 384 * HD, 384);
        addm(fp[27] - cw + (long)l * HD * HD, 128);
        addm(fp[29] - cw + (long)l * HD * HD, 128);
    }
    for (int l = 0; l < NLAYER; l++) {
        addm(fp[33] - cw + (long)l * 256 * HD, 256);
        addm(fp[35] - cw + (long)l * HD * HD, 128);
        addm(fp[37] - cw + (long)l * HD * HD, 128);
    }

    int* ip = (int*)(wpk + ((dst + 7) & ~7));
    int* row_ptr = ip;            ip += NPART + 8;
    int* cursor  = ip;            ip += NPART;
    int* counts  = ip;            ip += NPART;
    int* snd_s   = ip;            ip += NEDGE;
    int* rcv_s   = ip;

    const int EBL = (NEDGE + 255) / 256;

    k_convert<<<dim3(64, NFLOAT_ARRAYS), 256, 0, stream>>>(ca, cw, braw);
    hipMemsetAsync(counts, 0, (size_t)NPART * sizeof(int), stream);
    k_hist<<<EBL, 256, 0, stream>>>(rcv, counts);
    k_scan<<<1, 1024, 0, stream>>>(counts, row_ptr, cursor);
    k_scatter<<<EBL, 256, 0, stream>>>(snd, rcv, cursor, snd_s, rcv_s);
    k_pack<<<dim3(192, NMAT), 256, 0, stream>>>(cw, wpk, pa);

    const int NB = (NPART + 63) / 64;   // 469
    const int EB = (NEDGE + 63) / 64;   // 4688 (encoder)

    k_node_enc_m<<<NB, 256, 0, stream>>>(fp[0], fp[1], fp[2], ptype, fp[8],
        wpk + pk[0], fp[10], wpk + pk[1], fp[12], wpk + pk[2], fp[14],
        fp[15], fp[16], nodes_bf);
    k_edge_enc_m<<<EB, 256, 0, stream>>>(fp[1], snd_s, rcv_s,
        wpk + pk[3], fp[18], wpk + pk[4], fp[20], wpk + pk[5], fp[22],
        fp[23], fp[24], edges_bf);

    for (int l = 0; l < NLAYER; l++) {
        k_edge_layer_m<<<EB32, 256, 0, stream>>>(nodes_bf, edges_bf, agg, bnd, snd_s, rcv_s,
            wpk + pk[6 + 3 * l],  fp[26] + (size_t)l * HD,
            wpk + pk[7 + 3 * l],  fp[28] + (size_t)l * HD,
            wpk + pk[8 + 3 * l],  fp[30] + (size_t)l * HD,
            fp[31] + (size_t)l * HD, fp[32] + (size_t)l * HD);
        k_node_layer_m<<<NB, 256, 0, stream>>>(nodes_bf, agg, bnd, row_ptr,
            wpk + pk[36 + 3 * l], fp[34] + (size_t)l * HD,
            wpk + pk[37 + 3 * l], fp[36] + (size_t)l * HD,
            wpk + pk[38 + 3 * l], fp[38] + (size_t)l * HD,
            fp[39] + (size_t)l * HD, fp[40] + (size_t)l * HD);
    }

    k_decoder<<<NPART / 8, 128, 0, stream>>>(nodes_bf,
        fp[41], fp[42], fp[43], fp[44], fp[45], fp[46],
        fp[0], fp[1], fp[3], nonk, braw, d_out);
}